// Round 6
// baseline (223.965 us; speedup 1.0000x reference)
//
#include <hip/hip_runtime.h>
#include <cmath>

#define TPB 256
typedef float floatx4 __attribute__((ext_vector_type(4)));
typedef __bf16 bf16x8 __attribute__((ext_vector_type(8)));
typedef unsigned short ushort8 __attribute__((ext_vector_type(8)));
typedef unsigned short ushort_t;

// ---------- workspace layout ----------
// float units: [0]=sc2 (S_N1*s_w2), [1]=sc3 (S_N2*s_w3), [2]=K1 (S_X1*s_w1/S_N1)
// uint units 4..15: enc min/max (6 pairs)
#define OFF_B1 520       // 20  f32  (pre-divided by S_N1)
#define OFF_B2 544       // 50  f32
#define OFF_B3 600       // 500 f32
#define W1BF_BYTE 6144       // [32][32] u16 int weights (conv1)
#define W2BF_BYTE 8192       // [20 chunks][64 co][32 k] u16 int weights (conv2), 81920 B
#define W3BF_BYTE 131072     // [512][800]  u16 int weights (fc1)
#define Q1_BYTE  1048576ULL  // [B][pixel(144)][ci24] bf16 channels-last PADDED (28.3 MB)
#define Q2_BYTE  29360128ULL // [B][800] bf16 (6.6 MB)
#define Q3_BYTE  1048576ULL  // [B][500] u8 — overlays q1cl (dead after conv2)

#define S_X1 (3.5f/255.0f)
#define ZP_X1 36.0f
#define S_N1 (6.0f/255.0f)
#define S_N2 (8.0f/255.0f)
#define S_N3 (10.0f/255.0f)

__device__ inline unsigned int enc_f(float f){
    unsigned int u = __float_as_uint(f);
    return (u & 0x80000000u) ? ~u : (u | 0x80000000u);
}
__device__ inline float dec_f(unsigned int e){
    unsigned int u = (e & 0x80000000u) ? (e & 0x7fffffffu) : ~e;
    return __uint_as_float(u);
}
__device__ inline void sczp(float mn, float mx, float& s, float& zp){
    s = (mx - mn) / 255.0f;
    zp = truncf(fminf(fmaxf(0.0f - mn / s, 0.0f), 255.0f));
}
__device__ inline float qclip(float x, float s, float zp){
    return rintf(fminf(fmaxf(zp + x / s, 0.0f), 255.0f));
}
// exact bf16 bits for integer-valued floats |v| < 256
__device__ inline ushort_t bfbits(float v){
    return (ushort_t)(__float_as_uint(v) >> 16);
}

__global__ void k_init(unsigned int* enc){
    int i = threadIdx.x;
    if (i < 6){ enc[2*i] = 0xFFFFFFFFu; enc[2*i+1] = 0u; }
}

__global__ __launch_bounds__(TPB) void k_minmax(
        const float* c1w, const float* c1b, const float* c2w, const float* c2b,
        const float* f1w, const float* f1b, unsigned int* enc){
    __shared__ float smn[TPB], smx[TPB];
    int bb = blockIdx.x, tid = threadIdx.x;
    const float* src; int n, t, sub, nsub;
    if      (bb == 0){ src=c1w; n=500;    t=0; sub=0;     nsub=1;  }
    else if (bb == 1){ src=c1b; n=20;     t=1; sub=0;     nsub=1;  }
    else if (bb <  6){ src=c2w; n=25000;  t=2; sub=bb-2;  nsub=4;  }
    else if (bb == 6){ src=c2b; n=50;     t=3; sub=0;     nsub=1;  }
    else if (bb < 71){ src=f1w; n=400000; t=4; sub=bb-7;  nsub=64; }
    else             { src=f1b; n=500;    t=5; sub=0;     nsub=1;  }
    float mn = INFINITY, mx = -INFINITY;
    for (int i = sub*TPB + tid; i < n; i += nsub*TPB){
        float v = src[i]; mn = fminf(mn, v); mx = fmaxf(mx, v);
    }
    smn[tid] = mn; smx[tid] = mx; __syncthreads();
    for (int s = TPB/2; s > 0; s >>= 1){
        if (tid < s){
            smn[tid] = fminf(smn[tid], smn[tid+s]);
            smx[tid] = fmaxf(smx[tid], smx[tid+s]);
        }
        __syncthreads();
    }
    if (tid == 0){
        atomicMin(&enc[2*t],   enc_f(smn[0]));
        atomicMax(&enc[2*t+1], enc_f(smx[0]));
    }
}

// w2bt chunk packing (20 chunks of K=32):
//   main c in 0..12:   oct q -> tap = 2c + (q>>1), ci = (q&1)*8 + jj   (tap 25 -> zero)
//   residue c in 13..19: oct q -> tap = 4(c-13) + q, ci = 16 + jj (jj<4; jj>=4 -> zero)
#define N_EFF 452157
__global__ __launch_bounds__(TPB) void k_make_eff(
        const float* c1w, const float* c1b, const float* c2w, const float* c2b,
        const float* f1w, const float* f1b, const unsigned int* enc,
        float* ws, ushort_t* w1bf, ushort_t* w2bf, ushort_t* w3bf){
    int i = blockIdx.x * TPB + threadIdx.x;
    if (i >= N_EFF) return;
    if (i < 1024){                   // w1bf: [n(32)][k(32)] integer weights
        int n = i >> 5, k = i & 31;
        float v = 0.0f;
        if (n < 20 && k < 25){
            float s, zp; sczp(dec_f(enc[0]), dec_f(enc[1]), s, zp);
            v = qclip(c1w[n*25 + k], s, zp) - zp;
        }
        w1bf[i] = bfbits(v);
    } else if (i < 1044){            // b1 pre-divided by S_N1
        int j = i - 1024;
        float s, zp; sczp(dec_f(enc[2]), dec_f(enc[3]), s, zp);
        ws[OFF_B1 + j] = (s * (qclip(c1b[j], s, zp) + zp)) / S_N1;
    } else if (i < 42004){           // w2bt chunk-packed
        int j = i - 1044;
        int c = j >> 11, r = j & 2047, co = r >> 5, k = r & 31;
        int q = k >> 3, jj = k & 7;
        int tap, ci; bool valid;
        if (c < 13){ tap = 2*c + (q>>1); ci = (q&1)*8 + jj; valid = (tap < 25); }
        else       { tap = 4*(c-13) + q; ci = 16 + jj;      valid = (tap < 25) && (jj < 4); }
        valid = valid && (co < 50);
        float v = 0.0f;
        if (valid){
            float s, zp; sczp(dec_f(enc[4]), dec_f(enc[5]), s, zp);
            v = qclip(c2w[(co*20 + ci)*25 + tap], s, zp) - zp;
        }
        w2bf[j] = bfbits(v);
    } else if (i < 42054){
        int j = i - 42004;
        float s, zp; sczp(dec_f(enc[6]), dec_f(enc[7]), s, zp);
        ws[OFF_B2 + j] = s * (qclip(c2b[j], s, zp) + zp);
    } else if (i < 451654){          // w3bf: [n(512)][k(800)]
        int j = i - 42054;
        int n = j / 800, k = j - 800*n;
        float v = 0.0f;
        if (n < 500){
            float s, zp; sczp(dec_f(enc[8]), dec_f(enc[9]), s, zp);
            v = qclip(f1w[n*800 + k], s, zp) - zp;
        }
        w3bf[j] = bfbits(v);
    } else if (i < 452154){
        int j = i - 451654;
        float s, zp; sczp(dec_f(enc[10]), dec_f(enc[11]), s, zp);
        ws[OFF_B3 + j] = s * (qclip(f1b[j], s, zp) + zp);
    } else if (i == 452154){
        float s, zp; sczp(dec_f(enc[4]), dec_f(enc[5]), s, zp);
        ws[0] = S_N1 * s;            // conv2 combined scale
    } else if (i == 452155){
        float s, zp; sczp(dec_f(enc[8]), dec_f(enc[9]), s, zp);
        ws[1] = S_N2 * s;            // fc1 combined scale
    } else {
        float s, zp; sczp(dec_f(enc[0]), dec_f(enc[1]), s, zp);
        ws[2] = (S_X1 * s) / S_N1;   // conv1 combined scale, pre-divided
    }
}

// conv1 via bf16 MFMA implicit GEMM -> channels-last PADDED q1cl[B][144][24] bf16 ints
__global__ __launch_bounds__(TPB) void k_conv1(const float* x, const ushort_t* w1bf,
                                               const float* ws, ushort_t* q1cl){
    __shared__ ushort_t xs[784];
    __shared__ unsigned char hb[5760];   // [oh(24)*12+pw][ch(20)] horizontal pool maxes
    int b = blockIdx.x, tid = threadIdx.x;
    int lane = tid & 63, wv = tid >> 6;
    int ln = lane & 15, quad = lane >> 4;

    const float* xb = x + (size_t)b * 784;
    for (int i = tid; i < 784; i += TPB){
        float v = xb[i];
        float q = rintf(fminf(fmaxf(ZP_X1 + v / S_X1, 0.0f), 255.0f));
        xs[i] = bfbits(q - ZP_X1);
    }

    int offj[8]; bool vj[8];
    #pragma unroll
    for (int j = 0; j < 8; ++j){
        int k = quad*8 + j;
        vj[j] = (k < 25);
        int kh = k / 5, kw = k - 5*kh;
        offj[j] = vj[j] ? (kh*28 + kw) : 0;
    }

    ushort8 bw0 = *(const ushort8*)(w1bf + ln*32 + quad*8);
    ushort8 bw1 = *(const ushort8*)(w1bf + (16 + ln)*32 + quad*8);
    bf16x8 bf0 = __builtin_bit_cast(bf16x8, bw0);
    bf16x8 bf1 = __builtin_bit_cast(bf16x8, bw1);

    float K1 = ws[2];
    float B1_0 = ws[OFF_B1 + ln];
    float B1_1 = (ln < 4) ? ws[OFF_B1 + 16 + ln] : 0.0f;
    __syncthreads();

    for (int i = 0; i < 9; ++i){
        int mt = 9*wv + i;
        int m = mt*16 + ln;
        int oh = m / 24, ow = m - 24*oh;
        int base = oh*28 + ow;
        ushort8 aw;
        #pragma unroll
        for (int j = 0; j < 8; ++j)
            aw[j] = vj[j] ? xs[base + offj[j]] : (ushort_t)0;
        bf16x8 af = __builtin_bit_cast(bf16x8, aw);
        floatx4 z = (floatx4){0.f,0.f,0.f,0.f};
        floatx4 a0 = __builtin_amdgcn_mfma_f32_16x16x32_bf16(af, bf0, z, 0, 0, 0);
        floatx4 a1 = __builtin_amdgcn_mfma_f32_16x16x32_bf16(af, bf1, z, 0, 0, 0);

        int m0 = mt*16 + quad*4;
        int oh0 = m0 / 24, owp = (m0 - 24*oh0) >> 1;
        int hbase = (oh0*12 + owp)*20;
        {
            float q[4];
            #pragma unroll
            for (int r = 0; r < 4; ++r){
                float y = fmaxf(fmaf(a0[r], K1, B1_0), 0.0f);
                q[r] = fmodf(rintf(y), 256.0f);
            }
            hb[hbase + ln]      = (unsigned char)fmaxf(q[0], q[1]);
            hb[hbase + 20 + ln] = (unsigned char)fmaxf(q[2], q[3]);
        }
        if (ln < 4){
            float q[4];
            #pragma unroll
            for (int r = 0; r < 4; ++r){
                float y = fmaxf(fmaf(a1[r], K1, B1_1), 0.0f);
                q[r] = fmodf(rintf(y), 256.0f);
            }
            hb[hbase + 16 + ln]      = (unsigned char)fmaxf(q[0], q[1]);
            hb[hbase + 36 + ln]      = (unsigned char)fmaxf(q[2], q[3]);
        }
    }
    __syncthreads();

    // vertical pool + write channels-last padded [pixel(144)][ci24] (ci 20-23 = 0)
    for (int o = tid; o < 3456; o += TPB){
        int p = o / 24, c = o - 24*p;
        float m_ = 0.0f;
        if (c < 20){
            int ph = p / 12, pw = p - 12*ph;
            unsigned char t_ = hb[((2*ph)*12 + pw)*20 + c];
            unsigned char u_ = hb[((2*ph+1)*12 + pw)*20 + c];
            m_ = (float)(t_ > u_ ? t_ : u_);
        }
        q1cl[(size_t)b*3456 + o] = bfbits(m_);
    }
}

// conv2 v5: NO LDS. A-fragments read directly from padded global q1cl (L1/L2-resident),
// B-fragments from L2-hot w2bt. One image/block, 4 waves, each wave 2mt x 2nt.
// Barrier-free, staging-free. Epilogue = verified round-5 pool/write mapping.
__global__ __launch_bounds__(TPB, 6) void k_conv2(const ushort_t* q1cl, const ushort_t* w2bt,
                                                  const float* ws, ushort_t* q2bf, int B){
    int tid = threadIdx.x;
    int lane = tid & 63, wv = tid >> 6;
    int ln = lane & 15, quad = lane >> 4;
    int b = blockIdx.x;
    if (b >= B) return;
    int mt0 = (wv & 1) * 2;        // this wave: m-tiles mt0, mt0+1
    int nt0 = (wv >> 1) * 2;       // this wave: n-tiles nt0, nt0+1

    const ushort_t* img = q1cl + (size_t)b * 3456;
    int arow = ((ln>>3)*12 + (ln&7)) * 24;   // lane's pixel row within an m-tile

    int aoff[20];
    #pragma unroll
    for (int c = 0; c < 20; ++c){
        int tap, inner;
        if (c < 13){ tap = 2*c + (quad>>1); inner = (quad&1)*8; }
        else       { tap = 4*(c-13) + quad; inner = 16; }
        int pt = 0;   // invalid taps -> pixel 0 (weights are zero there)
        if (tap < 25){ int kh = tap/5, kw = tap-5*kh; pt = kh*12 + kw; }
        aoff[c] = pt*24 + inner;
    }

    floatx4 acc[2][2];
    #pragma unroll
    for (int mi = 0; mi < 2; ++mi)
        #pragma unroll
        for (int ni = 0; ni < 2; ++ni) acc[mi][ni] = (floatx4){0.f,0.f,0.f,0.f};

    const ushort_t* bsrc = w2bt + (size_t)ln*32 + quad*8;

    #pragma unroll
    for (int c = 0; c < 20; ++c){
        ushort8 a0w = *(const ushort8*)(img + mt0*576       + arow + aoff[c]);
        ushort8 a1w = *(const ushort8*)(img + (mt0+1)*576   + arow + aoff[c]);
        ushort8 b0w = *(const ushort8*)(bsrc + (size_t)(c*64 + nt0*16)*32);
        ushort8 b1w = *(const ushort8*)(bsrc + (size_t)(c*64 + (nt0+1)*16)*32);
        bf16x8 a0 = __builtin_bit_cast(bf16x8, a0w);
        bf16x8 a1 = __builtin_bit_cast(bf16x8, a1w);
        bf16x8 b0 = __builtin_bit_cast(bf16x8, b0w);
        bf16x8 b1 = __builtin_bit_cast(bf16x8, b1w);
        acc[0][0] = __builtin_amdgcn_mfma_f32_16x16x32_bf16(a0, b0, acc[0][0], 0, 0, 0);
        acc[0][1] = __builtin_amdgcn_mfma_f32_16x16x32_bf16(a0, b1, acc[0][1], 0, 0, 0);
        acc[1][0] = __builtin_amdgcn_mfma_f32_16x16x32_bf16(a1, b0, acc[1][0], 0, 0, 0);
        acc[1][1] = __builtin_amdgcn_mfma_f32_16x16x32_bf16(a1, b1, acc[1][1], 0, 0, 0);
    }

    float sc2 = ws[0];
    #pragma unroll
    for (int ni = 0; ni < 2; ++ni){
        int co = (nt0 + ni)*16 + ln;
        float bias = (co < 50) ? ws[OFF_B2 + co] : 0.0f;
        #pragma unroll
        for (int mi = 0; mi < 2; ++mi){
            int mt = mt0 + mi;
            float q[4];
            #pragma unroll
            for (int r = 0; r < 4; ++r){
                float y = fmaxf((acc[mi][ni][r]*sc2 + bias) / S_N2, 0.0f);
                q[r] = fmodf(rintf(y), 256.0f);
            }
            float h0 = fmaxf(q[0], q[1]), h1 = fmaxf(q[2], q[3]);
            float v0 = fmaxf(h0, __shfl_xor(h0, 32));
            float v1 = fmaxf(h1, __shfl_xor(h1, 32));
            if (quad < 2 && co < 50){
                size_t base = (size_t)b*800 + co*16 + mt*4 + quad*2;
                q2bf[base]     = bfbits(v0);
                q2bf[base + 1] = bfbits(v1);
            }
        }
    }
}

// fc1 via bf16 MFMA GEMM: [B,800] x [512,800]^T, tile 64x64, K-chunk 32, dbuf LDS.
__global__ __launch_bounds__(TPB) void k_fc1(const ushort_t* q2bf, const ushort_t* w3bf,
                                             const float* ws, unsigned char* q3, int B){
    __shared__ ushort_t As[2][64*40];
    int tid = threadIdx.x;
    int n0b = blockIdx.x * 64;
    int b0  = blockIdx.y * 64;
    int lane = tid & 63, wv = tid >> 6;
    int ln = lane & 15, quad = lane >> 4;
    int n0 = n0b + wv*16;
    int lrow = tid >> 2, lk = (tid & 3) * 8;
    const ushort_t* asrc = q2bf + (size_t)(b0 + lrow)*800 + lk;
    ushort_t* adst0 = &As[0][0] + lrow*40 + lk;
    ushort_t* adst1 = &As[1][0] + lrow*40 + lk;

    floatx4 acc[4];
    #pragma unroll
    for (int mt = 0; mt < 4; ++mt) acc[mt] = (floatx4){0.f,0.f,0.f,0.f};

    *(ushort8*)adst0 = *(const ushort8*)asrc;
    __syncthreads();

    for (int c = 0; c < 25; ++c){
        const ushort_t* cur = &As[c & 1][0];
        ushort8 tn;
        bool pf = (c + 1 < 25);
        if (pf) tn = *(const ushort8*)(asrc + (c + 1)*32);
        ushort8 bw = *(const ushort8*)(w3bf + (size_t)(n0 + ln)*800 + c*32 + quad*8);
        bf16x8 bfr = __builtin_bit_cast(bf16x8, bw);
        #pragma unroll
        for (int mt = 0; mt < 4; ++mt){
            ushort8 aw = *(const ushort8*)(cur + (16*mt + ln)*40 + quad*8);
            acc[mt] = __builtin_amdgcn_mfma_f32_16x16x32_bf16(
                          __builtin_bit_cast(bf16x8, aw), bfr, acc[mt], 0, 0, 0);
        }
        if (pf) *(ushort8*)(((c + 1) & 1) ? adst1 : adst0) = tn;
        __syncthreads();
    }

    float sc3 = ws[1];
    int n = n0 + ln;
    if (n < 500){
        float bias = ws[OFF_B3 + n];
        #pragma unroll
        for (int mt = 0; mt < 4; ++mt){
            #pragma unroll
            for (int r = 0; r < 4; ++r){
                int m = 16*mt + 4*quad + r;
                float y = fmaxf((acc[mt][r] * sc3 + bias) / S_N3, 0.0f);
                float q = fmodf(rintf(y), 256.0f);
                q3[(size_t)(b0 + m)*500 + n] = (unsigned char)q;
            }
        }
    }
}

// fc2 (dequant + [B,500]x[10,500]^T + bias) + log_softmax. 16 rows/block, w2 in LDS.
__global__ __launch_bounds__(TPB) void k_fc2(const unsigned char* q3, const float* w2,
                                             const float* b2, float* out, int B){
    __shared__ float w2s[5000];
    __shared__ float b2s[10];
    int tid = threadIdx.x;
    for (int i = tid; i < 5000; i += TPB) w2s[i] = w2[i];
    if (tid < 10) b2s[tid] = b2[tid];
    __syncthreads();
    int lane = tid & 63, wv = tid >> 6;
    for (int rr = 0; rr < 4; ++rr){
        int b = blockIdx.x*16 + wv*4 + rr;
        if (b >= B) break;
        float acc[10];
        #pragma unroll
        for (int c = 0; c < 10; ++c) acc[c] = 0.0f;
        for (int k = lane; k < 500; k += 64){
            float xf = S_N3 * (float)q3[(size_t)b*500 + k];
            #pragma unroll
            for (int c = 0; c < 10; ++c)
                acc[c] = fmaf(xf, w2s[c*500 + k], acc[c]);
        }
        #pragma unroll
        for (int off = 32; off > 0; off >>= 1)
            #pragma unroll
            for (int c = 0; c < 10; ++c)
                acc[c] += __shfl_xor(acc[c], off);
        float lg[10], m = -INFINITY;
        #pragma unroll
        for (int c = 0; c < 10; ++c){ lg[c] = acc[c] + b2s[c]; m = fmaxf(m, lg[c]); }
        float sum = 0.0f;
        #pragma unroll
        for (int c = 0; c < 10; ++c) sum += expf(lg[c] - m);
        float ls = logf(sum);
        if (lane < 10) out[(size_t)b*10 + lane] = lg[lane] - m - ls;
    }
}

extern "C" void kernel_launch(void* const* d_in, const int* in_sizes, int n_in,
                              void* d_out, int out_size, void* d_ws, size_t ws_size,
                              hipStream_t stream){
    const float* x   = (const float*)d_in[0];
    const float* c1w = (const float*)d_in[1];
    const float* c1b = (const float*)d_in[2];
    const float* c2w = (const float*)d_in[3];
    const float* c2b = (const float*)d_in[4];
    const float* f1w = (const float*)d_in[5];
    const float* f1b = (const float*)d_in[6];
    const float* f2w = (const float*)d_in[7];
    const float* f2b = (const float*)d_in[8];
    int B = in_sizes[0] / 784;

    float* ws = (float*)d_ws;
    unsigned int* enc = (unsigned int*)d_ws + 4;
    ushort_t* w1bf = (ushort_t*)((char*)d_ws + W1BF_BYTE);
    ushort_t* w2bf = (ushort_t*)((char*)d_ws + W2BF_BYTE);
    ushort_t* w3bf = (ushort_t*)((char*)d_ws + W3BF_BYTE);
    ushort_t* q1cl = (ushort_t*)((char*)d_ws + Q1_BYTE);
    ushort_t* q2bf = (ushort_t*)((char*)d_ws + Q2_BYTE);
    unsigned char* q3 = (unsigned char*)d_ws + Q3_BYTE;
    float* out = (float*)d_out;

    k_init<<<1, 64, 0, stream>>>(enc);
    k_minmax<<<72, TPB, 0, stream>>>(c1w, c1b, c2w, c2b, f1w, f1b, enc);
    k_make_eff<<<(N_EFF + TPB - 1)/TPB, TPB, 0, stream>>>(c1w, c1b, c2w, c2b, f1w, f1b, enc, ws, w1bf, w2bf, w3bf);
    k_conv1<<<B, TPB, 0, stream>>>(x, w1bf, ws, q1cl);
    k_conv2<<<B, TPB, 0, stream>>>(q1cl, w2bf, ws, q2bf, B);
    dim3 g_fc1(8, B/64);
    k_fc1<<<g_fc1, TPB, 0, stream>>>(q2bf, w3bf, ws, q3, B);
    k_fc2<<<(B + 15)/16, TPB, 0, stream>>>(q3, f2w, f2b, out, B);
}

// Round 7
// 211.238 us; speedup vs baseline: 1.0603x; 1.0603x over previous
//
#include <hip/hip_runtime.h>
#include <cmath>

#define TPB 256
typedef float floatx4 __attribute__((ext_vector_type(4)));
typedef __bf16 bf16x8 __attribute__((ext_vector_type(8)));
typedef unsigned short ushort8 __attribute__((ext_vector_type(8)));
typedef unsigned short ushort_t;

// ---------- workspace layout ----------
// float units: [0]=sc2 (S_N1*s_w2), [1]=sc3 (S_N2*s_w3), [2]=K1 (S_X1*s_w1/S_N1)
// uint units 4..15: enc min/max (6 pairs)
#define OFF_B1 520       // 20  f32  (pre-divided by S_N1)
#define OFF_B2 544       // 50  f32
#define OFF_B3 600       // 500 f32
#define W1BF_BYTE 6144       // [32][32] u16 int weights (conv1)
#define W2BF_BYTE 8192       // [20 chunks][64 co][32 k] u16 int weights (conv2), 81920 B
#define W3BF_BYTE 131072     // [512][800]  u16 int weights (fc1)
#define Q1_BYTE  1048576ULL  // [B][pixel(144)][ci24] bf16 channels-last PADDED (28.3 MB)
#define Q2_BYTE  29360128ULL // [B][800] bf16 (6.6 MB)
#define Q3_BYTE  1048576ULL  // [B][500] u8 — overlays q1cl (dead after conv2)

#define S_X1 (3.5f/255.0f)
#define ZP_X1 36.0f
#define S_N1 (6.0f/255.0f)
#define S_N2 (8.0f/255.0f)
#define S_N3 (10.0f/255.0f)

#define CONV2_G 2
// LDS pixel stride for conv2: 40 u16 = 80 B = 20 banks (period-32 -> conflict-free)
#define XSTR 40

__device__ inline unsigned int enc_f(float f){
    unsigned int u = __float_as_uint(f);
    return (u & 0x80000000u) ? ~u : (u | 0x80000000u);
}
__device__ inline float dec_f(unsigned int e){
    unsigned int u = (e & 0x80000000u) ? (e & 0x7fffffffu) : ~e;
    return __uint_as_float(u);
}
__device__ inline void sczp(float mn, float mx, float& s, float& zp){
    s = (mx - mn) / 255.0f;
    zp = truncf(fminf(fmaxf(0.0f - mn / s, 0.0f), 255.0f));
}
__device__ inline float qclip(float x, float s, float zp){
    return rintf(fminf(fmaxf(zp + x / s, 0.0f), 255.0f));
}
// exact bf16 bits for integer-valued floats |v| < 256
__device__ inline ushort_t bfbits(float v){
    return (ushort_t)(__float_as_uint(v) >> 16);
}

__global__ void k_init(unsigned int* enc){
    int i = threadIdx.x;
    if (i < 6){ enc[2*i] = 0xFFFFFFFFu; enc[2*i+1] = 0u; }
}

__global__ __launch_bounds__(TPB) void k_minmax(
        const float* c1w, const float* c1b, const float* c2w, const float* c2b,
        const float* f1w, const float* f1b, unsigned int* enc){
    __shared__ float smn[TPB], smx[TPB];
    int bb = blockIdx.x, tid = threadIdx.x;
    const float* src; int n, t, sub, nsub;
    if      (bb == 0){ src=c1w; n=500;    t=0; sub=0;     nsub=1;  }
    else if (bb == 1){ src=c1b; n=20;     t=1; sub=0;     nsub=1;  }
    else if (bb <  6){ src=c2w; n=25000;  t=2; sub=bb-2;  nsub=4;  }
    else if (bb == 6){ src=c2b; n=50;     t=3; sub=0;     nsub=1;  }
    else if (bb < 71){ src=f1w; n=400000; t=4; sub=bb-7;  nsub=64; }
    else             { src=f1b; n=500;    t=5; sub=0;     nsub=1;  }
    float mn = INFINITY, mx = -INFINITY;
    for (int i = sub*TPB + tid; i < n; i += nsub*TPB){
        float v = src[i]; mn = fminf(mn, v); mx = fmaxf(mx, v);
    }
    smn[tid] = mn; smx[tid] = mx; __syncthreads();
    for (int s = TPB/2; s > 0; s >>= 1){
        if (tid < s){
            smn[tid] = fminf(smn[tid], smn[tid+s]);
            smx[tid] = fmaxf(smx[tid], smx[tid+s]);
        }
        __syncthreads();
    }
    if (tid == 0){
        atomicMin(&enc[2*t],   enc_f(smn[0]));
        atomicMax(&enc[2*t+1], enc_f(smx[0]));
    }
}

// w2bt chunk packing (20 chunks of K=32):
//   main c in 0..12:   oct q -> tap = 2c + (q>>1), ci = (q&1)*8 + jj   (tap 25 -> zero)
//   residue c in 13..19: oct q -> tap = 4(c-13) + q, ci = 16 + jj (jj<4; jj>=4 -> zero)
#define N_EFF 452157
__global__ __launch_bounds__(TPB) void k_make_eff(
        const float* c1w, const float* c1b, const float* c2w, const float* c2b,
        const float* f1w, const float* f1b, const unsigned int* enc,
        float* ws, ushort_t* w1bf, ushort_t* w2bf, ushort_t* w3bf){
    int i = blockIdx.x * TPB + threadIdx.x;
    if (i >= N_EFF) return;
    if (i < 1024){                   // w1bf: [n(32)][k(32)] integer weights
        int n = i >> 5, k = i & 31;
        float v = 0.0f;
        if (n < 20 && k < 25){
            float s, zp; sczp(dec_f(enc[0]), dec_f(enc[1]), s, zp);
            v = qclip(c1w[n*25 + k], s, zp) - zp;
        }
        w1bf[i] = bfbits(v);
    } else if (i < 1044){            // b1 pre-divided by S_N1
        int j = i - 1024;
        float s, zp; sczp(dec_f(enc[2]), dec_f(enc[3]), s, zp);
        ws[OFF_B1 + j] = (s * (qclip(c1b[j], s, zp) + zp)) / S_N1;
    } else if (i < 42004){           // w2bt chunk-packed
        int j = i - 1044;
        int c = j >> 11, r = j & 2047, co = r >> 5, k = r & 31;
        int q = k >> 3, jj = k & 7;
        int tap, ci; bool valid;
        if (c < 13){ tap = 2*c + (q>>1); ci = (q&1)*8 + jj; valid = (tap < 25); }
        else       { tap = 4*(c-13) + q; ci = 16 + jj;      valid = (tap < 25) && (jj < 4); }
        valid = valid && (co < 50);
        float v = 0.0f;
        if (valid){
            float s, zp; sczp(dec_f(enc[4]), dec_f(enc[5]), s, zp);
            v = qclip(c2w[(co*20 + ci)*25 + tap], s, zp) - zp;
        }
        w2bf[j] = bfbits(v);
    } else if (i < 42054){
        int j = i - 42004;
        float s, zp; sczp(dec_f(enc[6]), dec_f(enc[7]), s, zp);
        ws[OFF_B2 + j] = s * (qclip(c2b[j], s, zp) + zp);
    } else if (i < 451654){          // w3bf: [n(512)][k(800)]
        int j = i - 42054;
        int n = j / 800, k = j - 800*n;
        float v = 0.0f;
        if (n < 500){
            float s, zp; sczp(dec_f(enc[8]), dec_f(enc[9]), s, zp);
            v = qclip(f1w[n*800 + k], s, zp) - zp;
        }
        w3bf[j] = bfbits(v);
    } else if (i < 452154){
        int j = i - 451654;
        float s, zp; sczp(dec_f(enc[10]), dec_f(enc[11]), s, zp);
        ws[OFF_B3 + j] = s * (qclip(f1b[j], s, zp) + zp);
    } else if (i == 452154){
        float s, zp; sczp(dec_f(enc[4]), dec_f(enc[5]), s, zp);
        ws[0] = S_N1 * s;            // conv2 combined scale
    } else if (i == 452155){
        float s, zp; sczp(dec_f(enc[8]), dec_f(enc[9]), s, zp);
        ws[1] = S_N2 * s;            // fc1 combined scale
    } else {
        float s, zp; sczp(dec_f(enc[0]), dec_f(enc[1]), s, zp);
        ws[2] = (S_X1 * s) / S_N1;   // conv1 combined scale, pre-divided
    }
}

// conv1 via bf16 MFMA implicit GEMM -> channels-last PADDED q1cl[B][144][24] bf16 ints
__global__ __launch_bounds__(TPB) void k_conv1(const float* x, const ushort_t* w1bf,
                                               const float* ws, ushort_t* q1cl){
    __shared__ ushort_t xs[784];
    __shared__ unsigned char hb[5760];   // [oh(24)*12+pw][ch(20)] horizontal pool maxes
    int b = blockIdx.x, tid = threadIdx.x;
    int lane = tid & 63, wv = tid >> 6;
    int ln = lane & 15, quad = lane >> 4;

    const float* xb = x + (size_t)b * 784;
    for (int i = tid; i < 784; i += TPB){
        float v = xb[i];
        float q = rintf(fminf(fmaxf(ZP_X1 + v / S_X1, 0.0f), 255.0f));
        xs[i] = bfbits(q - ZP_X1);
    }

    int offj[8]; bool vj[8];
    #pragma unroll
    for (int j = 0; j < 8; ++j){
        int k = quad*8 + j;
        vj[j] = (k < 25);
        int kh = k / 5, kw = k - 5*kh;
        offj[j] = vj[j] ? (kh*28 + kw) : 0;
    }

    ushort8 bw0 = *(const ushort8*)(w1bf + ln*32 + quad*8);
    ushort8 bw1 = *(const ushort8*)(w1bf + (16 + ln)*32 + quad*8);
    bf16x8 bf0 = __builtin_bit_cast(bf16x8, bw0);
    bf16x8 bf1 = __builtin_bit_cast(bf16x8, bw1);

    float K1 = ws[2];
    float B1_0 = ws[OFF_B1 + ln];
    float B1_1 = (ln < 4) ? ws[OFF_B1 + 16 + ln] : 0.0f;
    __syncthreads();

    for (int i = 0; i < 9; ++i){
        int mt = 9*wv + i;
        int m = mt*16 + ln;
        int oh = m / 24, ow = m - 24*oh;
        int base = oh*28 + ow;
        ushort8 aw;
        #pragma unroll
        for (int j = 0; j < 8; ++j)
            aw[j] = vj[j] ? xs[base + offj[j]] : (ushort_t)0;
        bf16x8 af = __builtin_bit_cast(bf16x8, aw);
        floatx4 z = (floatx4){0.f,0.f,0.f,0.f};
        floatx4 a0 = __builtin_amdgcn_mfma_f32_16x16x32_bf16(af, bf0, z, 0, 0, 0);
        floatx4 a1 = __builtin_amdgcn_mfma_f32_16x16x32_bf16(af, bf1, z, 0, 0, 0);

        int m0 = mt*16 + quad*4;
        int oh0 = m0 / 24, owp = (m0 - 24*oh0) >> 1;
        int hbase = (oh0*12 + owp)*20;
        {
            float q[4];
            #pragma unroll
            for (int r = 0; r < 4; ++r){
                float y = fmaxf(fmaf(a0[r], K1, B1_0), 0.0f);
                q[r] = fmodf(rintf(y), 256.0f);
            }
            hb[hbase + ln]      = (unsigned char)fmaxf(q[0], q[1]);
            hb[hbase + 20 + ln] = (unsigned char)fmaxf(q[2], q[3]);
        }
        if (ln < 4){
            float q[4];
            #pragma unroll
            for (int r = 0; r < 4; ++r){
                float y = fmaxf(fmaf(a1[r], K1, B1_1), 0.0f);
                q[r] = fmodf(rintf(y), 256.0f);
            }
            hb[hbase + 16 + ln]      = (unsigned char)fmaxf(q[0], q[1]);
            hb[hbase + 36 + ln]      = (unsigned char)fmaxf(q[2], q[3]);
        }
    }
    __syncthreads();

    // vertical pool + write channels-last padded [pixel(144)][ci24] (ci 20-23 = 0)
    for (int o = tid; o < 3456; o += TPB){
        int p = o / 24, c = o - 24*p;
        float m_ = 0.0f;
        if (c < 20){
            int ph = p / 12, pw = p - 12*ph;
            unsigned char t_ = hb[((2*ph)*12 + pw)*20 + c];
            unsigned char u_ = hb[((2*ph+1)*12 + pw)*20 + c];
            m_ = (float)(t_ > u_ ? t_ : u_);
        }
        q1cl[(size_t)b*3456 + o] = bfbits(m_);
    }
}

// conv2 v7: round-5 structure with CONFLICT-FREE LDS stride 40 u16 (80 B = 20 banks,
// full period-32 bank rotation). Wave owns one nt (16 co), 4 m-tiles, acc = 16 VGPRs.
// B-frags stream from L2-hot w2bt. Barrier-free K-loop, dbuf image staging, G=2.
__global__ __launch_bounds__(TPB) void k_conv2(const ushort_t* q1cl, const ushort_t* w2bt,
                                               const float* ws, ushort_t* q2bf, int B){
    __shared__ __align__(16) ushort_t xs[2][144*XSTR];
    int tid = threadIdx.x;
    int lane = tid & 63, wv = tid >> 6;
    int ln = lane & 15, quad = lane >> 4;

    // per-lane A addressing (u16 units): addr = abase[mt] + aoff[c]
    int abase[4];
    #pragma unroll
    for (int mt = 0; mt < 4; ++mt)
        abase[mt] = (24*mt + (ln>>3)*12 + (ln&7)) * XSTR;
    int aoff[20];
    #pragma unroll
    for (int c = 0; c < 20; ++c){
        int tap, inner;
        if (c < 13){ tap = 2*c + (quad>>1); inner = (quad&1)*8; }
        else       { tap = 4*(c-13) + quad; inner = 16; }
        int pt = 0;   // invalid taps -> pixel 0 (weights are zero there)
        if (tap < 25){ int kh = tap/5, kw = tap-5*kh; pt = kh*12 + kw; }
        aoff[c] = pt*XSTR + inner;
    }

    float sc2 = ws[0];
    int co = wv*16 + ln;
    float bias = (co < 50) ? ws[OFF_B2 + co] : 0.0f;
    const ushort_t* bsrc = w2bt + (size_t)co*32 + quad*8;

    int b0 = blockIdx.x * CONV2_G;
    // stage image 0 (source rows are padded: 12 dwords incl. zeroed ci 20-23)
    {
        const unsigned int* src = (const unsigned int*)(q1cl + (size_t)b0*3456);
        unsigned int* dst = (unsigned int*)xs[0];
        for (int i = tid; i < 1728; i += TPB){
            int p = i / 12, d = i - 12*p;
            dst[p*(XSTR/2) + d] = src[i];
        }
    }
    __syncthreads();

    for (int g = 0; g < CONV2_G; ++g){
        int b = b0 + g;
        if (b >= B) break;

        // stage next image into the other buffer (overlaps with compute)
        if (g + 1 < CONV2_G && b + 1 < B){
            const unsigned int* src = (const unsigned int*)(q1cl + (size_t)(b+1)*3456);
            unsigned int* dst = (unsigned int*)xs[(g+1)&1];
            for (int i = tid; i < 1728; i += TPB){
                int p = i / 12, d = i - 12*p;
                dst[p*(XSTR/2) + d] = src[i];
            }
        }

        const ushort_t* cur = xs[g & 1];
        floatx4 acc[4];
        #pragma unroll
        for (int mt = 0; mt < 4; ++mt) acc[mt] = (floatx4){0.f,0.f,0.f,0.f};

        // barrier-free K-loop: 20 chunks x (1 global B-load + 4 LDS A-reads + 4 MFMAs)
        #pragma unroll
        for (int c = 0; c < 20; ++c){
            ushort8 bw = *(const ushort8*)(bsrc + c*2048);
            bf16x8 bfr = __builtin_bit_cast(bf16x8, bw);
            #pragma unroll
            for (int mt = 0; mt < 4; ++mt){
                ushort8 aw = *(const ushort8*)(cur + abase[mt] + aoff[c]);
                acc[mt] = __builtin_amdgcn_mfma_f32_16x16x32_bf16(
                              __builtin_bit_cast(bf16x8, aw), bfr, acc[mt], 0, 0, 0);
            }
        }

        // epilogue: quantize, 2x2 pool (in-reg horizontal, shfl_xor(32) vertical)
        #pragma unroll
        for (int mt = 0; mt < 4; ++mt){
            float q[4];
            #pragma unroll
            for (int r = 0; r < 4; ++r){
                float y = fmaxf((acc[mt][r]*sc2 + bias) / S_N2, 0.0f);
                q[r] = fmodf(rintf(y), 256.0f);
            }
            float h0 = fmaxf(q[0], q[1]), h1 = fmaxf(q[2], q[3]);
            float v0 = fmaxf(h0, __shfl_xor(h0, 32));
            float v1 = fmaxf(h1, __shfl_xor(h1, 32));
            if (quad < 2 && co < 50){
                size_t base = (size_t)b*800 + co*16 + mt*4 + quad*2;
                q2bf[base]     = bfbits(v0);
                q2bf[base + 1] = bfbits(v1);
            }
        }
        __syncthreads();   // staged next buffer ready; current buffer free
    }
}

// fc1 via bf16 MFMA GEMM: [B,800] x [512,800]^T, tile 64x64, K-chunk 32, dbuf LDS.
__global__ __launch_bounds__(TPB) void k_fc1(const ushort_t* q2bf, const ushort_t* w3bf,
                                             const float* ws, unsigned char* q3, int B){
    __shared__ ushort_t As[2][64*40];
    int tid = threadIdx.x;
    int n0b = blockIdx.x * 64;
    int b0  = blockIdx.y * 64;
    int lane = tid & 63, wv = tid >> 6;
    int ln = lane & 15, quad = lane >> 4;
    int n0 = n0b + wv*16;
    int lrow = tid >> 2, lk = (tid & 3) * 8;
    const ushort_t* asrc = q2bf + (size_t)(b0 + lrow)*800 + lk;
    ushort_t* adst0 = &As[0][0] + lrow*40 + lk;
    ushort_t* adst1 = &As[1][0] + lrow*40 + lk;

    floatx4 acc[4];
    #pragma unroll
    for (int mt = 0; mt < 4; ++mt) acc[mt] = (floatx4){0.f,0.f,0.f,0.f};

    *(ushort8*)adst0 = *(const ushort8*)asrc;
    __syncthreads();

    for (int c = 0; c < 25; ++c){
        const ushort_t* cur = &As[c & 1][0];
        ushort8 tn;
        bool pf = (c + 1 < 25);
        if (pf) tn = *(const ushort8*)(asrc + (c + 1)*32);
        ushort8 bw = *(const ushort8*)(w3bf + (size_t)(n0 + ln)*800 + c*32 + quad*8);
        bf16x8 bfr = __builtin_bit_cast(bf16x8, bw);
        #pragma unroll
        for (int mt = 0; mt < 4; ++mt){
            ushort8 aw = *(const ushort8*)(cur + (16*mt + ln)*40 + quad*8);
            acc[mt] = __builtin_amdgcn_mfma_f32_16x16x32_bf16(
                          __builtin_bit_cast(bf16x8, aw), bfr, acc[mt], 0, 0, 0);
        }
        if (pf) *(ushort8*)(((c + 1) & 1) ? adst1 : adst0) = tn;
        __syncthreads();
    }

    float sc3 = ws[1];
    int n = n0 + ln;
    if (n < 500){
        float bias = ws[OFF_B3 + n];
        #pragma unroll
        for (int mt = 0; mt < 4; ++mt){
            #pragma unroll
            for (int r = 0; r < 4; ++r){
                int m = 16*mt + 4*quad + r;
                float y = fmaxf((acc[mt][r] * sc3 + bias) / S_N3, 0.0f);
                float q = fmodf(rintf(y), 256.0f);
                q3[(size_t)(b0 + m)*500 + n] = (unsigned char)q;
            }
        }
    }
}

// fc2 (dequant + [B,500]x[10,500]^T + bias) + log_softmax. 16 rows/block, w2 in LDS.
__global__ __launch_bounds__(TPB) void k_fc2(const unsigned char* q3, const float* w2,
                                             const float* b2, float* out, int B){
    __shared__ float w2s[5000];
    __shared__ float b2s[10];
    int tid = threadIdx.x;
    for (int i = tid; i < 5000; i += TPB) w2s[i] = w2[i];
    if (tid < 10) b2s[tid] = b2[tid];
    __syncthreads();
    int lane = tid & 63, wv = tid >> 6;
    for (int rr = 0; rr < 4; ++rr){
        int b = blockIdx.x*16 + wv*4 + rr;
        if (b >= B) break;
        float acc[10];
        #pragma unroll
        for (int c = 0; c < 10; ++c) acc[c] = 0.0f;
        for (int k = lane; k < 500; k += 64){
            float xf = S_N3 * (float)q3[(size_t)b*500 + k];
            #pragma unroll
            for (int c = 0; c < 10; ++c)
                acc[c] = fmaf(xf, w2s[c*500 + k], acc[c]);
        }
        #pragma unroll
        for (int off = 32; off > 0; off >>= 1)
            #pragma unroll
            for (int c = 0; c < 10; ++c)
                acc[c] += __shfl_xor(acc[c], off);
        float lg[10], m = -INFINITY;
        #pragma unroll
        for (int c = 0; c < 10; ++c){ lg[c] = acc[c] + b2s[c]; m = fmaxf(m, lg[c]); }
        float sum = 0.0f;
        #pragma unroll
        for (int c = 0; c < 10; ++c) sum += expf(lg[c] - m);
        float ls = logf(sum);
        if (lane < 10) out[(size_t)b*10 + lane] = lg[lane] - m - ls;
    }
}

extern "C" void kernel_launch(void* const* d_in, const int* in_sizes, int n_in,
                              void* d_out, int out_size, void* d_ws, size_t ws_size,
                              hipStream_t stream){
    const float* x   = (const float*)d_in[0];
    const float* c1w = (const float*)d_in[1];
    const float* c1b = (const float*)d_in[2];
    const float* c2w = (const float*)d_in[3];
    const float* c2b = (const float*)d_in[4];
    const float* f1w = (const float*)d_in[5];
    const float* f1b = (const float*)d_in[6];
    const float* f2w = (const float*)d_in[7];
    const float* f2b = (const float*)d_in[8];
    int B = in_sizes[0] / 784;

    float* ws = (float*)d_ws;
    unsigned int* enc = (unsigned int*)d_ws + 4;
    ushort_t* w1bf = (ushort_t*)((char*)d_ws + W1BF_BYTE);
    ushort_t* w2bf = (ushort_t*)((char*)d_ws + W2BF_BYTE);
    ushort_t* w3bf = (ushort_t*)((char*)d_ws + W3BF_BYTE);
    ushort_t* q1cl = (ushort_t*)((char*)d_ws + Q1_BYTE);
    ushort_t* q2bf = (ushort_t*)((char*)d_ws + Q2_BYTE);
    unsigned char* q3 = (unsigned char*)d_ws + Q3_BYTE;
    float* out = (float*)d_out;

    k_init<<<1, 64, 0, stream>>>(enc);
    k_minmax<<<72, TPB, 0, stream>>>(c1w, c1b, c2w, c2b, f1w, f1b, enc);
    k_make_eff<<<(N_EFF + TPB - 1)/TPB, TPB, 0, stream>>>(c1w, c1b, c2w, c2b, f1w, f1b, enc, ws, w1bf, w2bf, w3bf);
    k_conv1<<<B, TPB, 0, stream>>>(x, w1bf, ws, q1cl);
    k_conv2<<<(B + CONV2_G - 1)/CONV2_G, TPB, 0, stream>>>(q1cl, w2bf, ws, q2bf, B);
    dim3 g_fc1(8, B/64);
    k_fc1<<<g_fc1, TPB, 0, stream>>>(q2bf, w3bf, ws, q3, B);
    k_fc2<<<(B + 15)/16, TPB, 0, stream>>>(q3, f2w, f2b, out, B);
}

// Round 8
// 177.778 us; speedup vs baseline: 1.2598x; 1.1882x over previous
//
#include <hip/hip_runtime.h>
#include <cmath>

#define TPB 256
typedef float floatx4 __attribute__((ext_vector_type(4)));
typedef __bf16 bf16x8 __attribute__((ext_vector_type(8)));
typedef unsigned short ushort8 __attribute__((ext_vector_type(8)));
typedef unsigned short ushort_t;

// ---------- workspace layout ----------
// float units: [0]=sc2 (S_N1*s_w2), [1]=sc3 (S_N2*s_w3), [2]=K1 (S_X1*s_w1/S_N1)
// uint units 4..15: enc min/max (6 pairs)
#define OFF_B1 520       // 20  f32  (pre-divided by S_N1)
#define OFF_B2 544       // 50  f32
#define OFF_B3 600       // 500 f32
#define W1BF_BYTE 6144       // [32][32] u16 int weights (conv1)
#define W2BF_BYTE 8192       // [20 chunks][64 co][32 k] u16 int weights (conv2), 81920 B
#define W3BF_BYTE 131072     // [512][800]  u16 int weights (fc1)
#define Q2_BYTE  29360128ULL // [B][800] bf16 (6.6 MB)
#define Q3_BYTE  1048576ULL  // [B][500] u8

#define S_X1 (3.5f/255.0f)
#define ZP_X1 36.0f
#define S_N1 (6.0f/255.0f)
#define S_N2 (8.0f/255.0f)
#define S_N3 (10.0f/255.0f)

// LDS pixel stride for conv2 A-reads: 40 u16 = 80 B = 20 banks (period-32 -> conflict-free)
#define XSTR 40

__device__ inline unsigned int enc_f(float f){
    unsigned int u = __float_as_uint(f);
    return (u & 0x80000000u) ? ~u : (u | 0x80000000u);
}
__device__ inline float dec_f(unsigned int e){
    unsigned int u = (e & 0x80000000u) ? (e & 0x7fffffffu) : ~e;
    return __uint_as_float(u);
}
__device__ inline void sczp(float mn, float mx, float& s, float& zp){
    s = (mx - mn) / 255.0f;
    zp = truncf(fminf(fmaxf(0.0f - mn / s, 0.0f), 255.0f));
}
__device__ inline float qclip(float x, float s, float zp){
    return rintf(fminf(fmaxf(zp + x / s, 0.0f), 255.0f));
}
// exact bf16 bits for integer-valued floats |v| < 256
__device__ inline ushort_t bfbits(float v){
    return (ushort_t)(__float_as_uint(v) >> 16);
}

__global__ void k_init(unsigned int* enc){
    int i = threadIdx.x;
    if (i < 6){ enc[2*i] = 0xFFFFFFFFu; enc[2*i+1] = 0u; }
}

__global__ __launch_bounds__(TPB) void k_minmax(
        const float* c1w, const float* c1b, const float* c2w, const float* c2b,
        const float* f1w, const float* f1b, unsigned int* enc){
    __shared__ float smn[TPB], smx[TPB];
    int bb = blockIdx.x, tid = threadIdx.x;
    const float* src; int n, t, sub, nsub;
    if      (bb == 0){ src=c1w; n=500;    t=0; sub=0;     nsub=1;  }
    else if (bb == 1){ src=c1b; n=20;     t=1; sub=0;     nsub=1;  }
    else if (bb <  6){ src=c2w; n=25000;  t=2; sub=bb-2;  nsub=4;  }
    else if (bb == 6){ src=c2b; n=50;     t=3; sub=0;     nsub=1;  }
    else if (bb < 71){ src=f1w; n=400000; t=4; sub=bb-7;  nsub=64; }
    else             { src=f1b; n=500;    t=5; sub=0;     nsub=1;  }
    float mn = INFINITY, mx = -INFINITY;
    for (int i = sub*TPB + tid; i < n; i += nsub*TPB){
        float v = src[i]; mn = fminf(mn, v); mx = fmaxf(mx, v);
    }
    smn[tid] = mn; smx[tid] = mx; __syncthreads();
    for (int s = TPB/2; s > 0; s >>= 1){
        if (tid < s){
            smn[tid] = fminf(smn[tid], smn[tid+s]);
            smx[tid] = fmaxf(smx[tid], smx[tid+s]);
        }
        __syncthreads();
    }
    if (tid == 0){
        atomicMin(&enc[2*t],   enc_f(smn[0]));
        atomicMax(&enc[2*t+1], enc_f(smx[0]));
    }
}

// w2bt chunk packing (20 chunks of K=32):
//   main c in 0..12:   oct q -> tap = 2c + (q>>1), ci = (q&1)*8 + jj   (tap 25 -> zero)
//   residue c in 13..19: oct q -> tap = 4(c-13) + q, ci = 16 + jj (jj<4; jj>=4 -> zero)
#define N_EFF 452157
__global__ __launch_bounds__(TPB) void k_make_eff(
        const float* c1w, const float* c1b, const float* c2w, const float* c2b,
        const float* f1w, const float* f1b, const unsigned int* enc,
        float* ws, ushort_t* w1bf, ushort_t* w2bf, ushort_t* w3bf){
    int i = blockIdx.x * TPB + threadIdx.x;
    if (i >= N_EFF) return;
    if (i < 1024){                   // w1bf: [n(32)][k(32)] integer weights
        int n = i >> 5, k = i & 31;
        float v = 0.0f;
        if (n < 20 && k < 25){
            float s, zp; sczp(dec_f(enc[0]), dec_f(enc[1]), s, zp);
            v = qclip(c1w[n*25 + k], s, zp) - zp;
        }
        w1bf[i] = bfbits(v);
    } else if (i < 1044){            // b1 pre-divided by S_N1
        int j = i - 1024;
        float s, zp; sczp(dec_f(enc[2]), dec_f(enc[3]), s, zp);
        ws[OFF_B1 + j] = (s * (qclip(c1b[j], s, zp) + zp)) / S_N1;
    } else if (i < 42004){           // w2bt chunk-packed
        int j = i - 1044;
        int c = j >> 11, r = j & 2047, co = r >> 5, k = r & 31;
        int q = k >> 3, jj = k & 7;
        int tap, ci; bool valid;
        if (c < 13){ tap = 2*c + (q>>1); ci = (q&1)*8 + jj; valid = (tap < 25); }
        else       { tap = 4*(c-13) + q; ci = 16 + jj;      valid = (tap < 25) && (jj < 4); }
        valid = valid && (co < 50);
        float v = 0.0f;
        if (valid){
            float s, zp; sczp(dec_f(enc[4]), dec_f(enc[5]), s, zp);
            v = qclip(c2w[(co*20 + ci)*25 + tap], s, zp) - zp;
        }
        w2bf[j] = bfbits(v);
    } else if (i < 42054){
        int j = i - 42004;
        float s, zp; sczp(dec_f(enc[6]), dec_f(enc[7]), s, zp);
        ws[OFF_B2 + j] = s * (qclip(c2b[j], s, zp) + zp);
    } else if (i < 451654){          // w3bf: [n(512)][k(800)]
        int j = i - 42054;
        int n = j / 800, k = j - 800*n;
        float v = 0.0f;
        if (n < 500){
            float s, zp; sczp(dec_f(enc[8]), dec_f(enc[9]), s, zp);
            v = qclip(f1w[n*800 + k], s, zp) - zp;
        }
        w3bf[j] = bfbits(v);
    } else if (i < 452154){
        int j = i - 451654;
        float s, zp; sczp(dec_f(enc[10]), dec_f(enc[11]), s, zp);
        ws[OFF_B3 + j] = s * (qclip(f1b[j], s, zp) + zp);
    } else if (i == 452154){
        float s, zp; sczp(dec_f(enc[4]), dec_f(enc[5]), s, zp);
        ws[0] = S_N1 * s;            // conv2 combined scale
    } else if (i == 452155){
        float s, zp; sczp(dec_f(enc[8]), dec_f(enc[9]), s, zp);
        ws[1] = S_N2 * s;            // fc1 combined scale
    } else {
        float s, zp; sczp(dec_f(enc[0]), dec_f(enc[1]), s, zp);
        ws[2] = (S_X1 * s) / S_N1;   // conv1 combined scale, pre-divided
    }
}

// Fused conv1+conv2, one image per block. conv1 (MFMA, integer epilogue) pools into
// LDS xs[pixel][XSTR] channels-last; conv2 (round-7 verified K-loop) consumes it.
// q1 never touches HBM.
__global__ __launch_bounds__(TPB) void k_conv12(const float* x, const ushort_t* w1bf,
                                                const ushort_t* w2bt, const float* ws,
                                                ushort_t* q2bf, int B){
    __shared__ __align__(16) ushort_t xs[144*XSTR];   // conv2 input; first 784 alias conv1 input
    __shared__ unsigned char hb[5760];                // [oh(24)*12+pw][ch(20)] h-pool maxes
    ushort_t* x1 = xs;   // conv1 quantized input (lifetime ends before xs written; barriers separate)
    int b = blockIdx.x, tid = threadIdx.x;
    int lane = tid & 63, wv = tid >> 6;
    int ln = lane & 15, quad = lane >> 4;

    // ---------------- conv1 phase ----------------
    const float* xb = x + (size_t)b * 784;
    for (int i = tid; i < 784; i += TPB){
        float v = xb[i];
        float q = rintf(fminf(fmaxf(ZP_X1 + v / S_X1, 0.0f), 255.0f));
        x1[i] = bfbits(q - ZP_X1);
    }

    int offj[8]; bool vj[8];
    #pragma unroll
    for (int j = 0; j < 8; ++j){
        int k = quad*8 + j;
        vj[j] = (k < 25);
        int kh = k / 5, kw = k - 5*kh;
        offj[j] = vj[j] ? (kh*28 + kw) : 0;
    }

    ushort8 bw0 = *(const ushort8*)(w1bf + ln*32 + quad*8);
    ushort8 bw1 = *(const ushort8*)(w1bf + (16 + ln)*32 + quad*8);
    bf16x8 bf0 = __builtin_bit_cast(bf16x8, bw0);
    bf16x8 bf1 = __builtin_bit_cast(bf16x8, bw1);

    float K1 = ws[2];
    float B1_0 = ws[OFF_B1 + ln];
    float B1_1 = (ln < 4) ? ws[OFF_B1 + 16 + ln] : 0.0f;
    __syncthreads();

    for (int i = 0; i < 9; ++i){
        int mt = 9*wv + i;
        int m = mt*16 + ln;
        int oh = m / 24, ow = m - 24*oh;
        int base = oh*28 + ow;
        ushort8 aw;
        #pragma unroll
        for (int j = 0; j < 8; ++j)
            aw[j] = vj[j] ? x1[base + offj[j]] : (ushort_t)0;
        bf16x8 af = __builtin_bit_cast(bf16x8, aw);
        floatx4 z = (floatx4){0.f,0.f,0.f,0.f};
        floatx4 a0 = __builtin_amdgcn_mfma_f32_16x16x32_bf16(af, bf0, z, 0, 0, 0);
        floatx4 a1 = __builtin_amdgcn_mfma_f32_16x16x32_bf16(af, bf1, z, 0, 0, 0);

        // integer epilogue: for y>=0, (uint)rintf(y) & 255 == fmod(rint(y),256) exactly
        int m0 = mt*16 + quad*4;
        int oh0 = m0 / 24, owp = (m0 - 24*oh0) >> 1;
        int hbase = (oh0*12 + owp)*20;
        {
            unsigned int qv[4];
            #pragma unroll
            for (int r = 0; r < 4; ++r){
                float y = fmaxf(fmaf(a0[r], K1, B1_0), 0.0f);
                qv[r] = ((unsigned int)rintf(y)) & 255u;
            }
            unsigned int h0 = qv[0] > qv[1] ? qv[0] : qv[1];
            unsigned int h1 = qv[2] > qv[3] ? qv[2] : qv[3];
            hb[hbase + ln]      = (unsigned char)h0;
            hb[hbase + 20 + ln] = (unsigned char)h1;
        }
        if (ln < 4){
            unsigned int qv[4];
            #pragma unroll
            for (int r = 0; r < 4; ++r){
                float y = fmaxf(fmaf(a1[r], K1, B1_1), 0.0f);
                qv[r] = ((unsigned int)rintf(y)) & 255u;
            }
            unsigned int h0 = qv[0] > qv[1] ? qv[0] : qv[1];
            unsigned int h1 = qv[2] > qv[3] ? qv[2] : qv[3];
            hb[hbase + 16 + ln]      = (unsigned char)h0;
            hb[hbase + 36 + ln]      = (unsigned char)h1;
        }
    }
    __syncthreads();

    // vertical pool into xs channels-last [pixel(144)][XSTR] (ci 20-23 zeroed; 24-39 unread)
    for (int o = tid; o < 3456; o += TPB){
        int p = o / 24, c = o - 24*p;
        unsigned int m_ = 0;
        if (c < 20){
            int ph = p / 12, pw = p - 12*ph;
            unsigned int t_ = hb[((2*ph)*12 + pw)*20 + c];
            unsigned int u_ = hb[((2*ph+1)*12 + pw)*20 + c];
            m_ = t_ > u_ ? t_ : u_;
        }
        xs[p*XSTR + c] = bfbits((float)m_);
    }
    __syncthreads();

    // ---------------- conv2 phase (round-7 verified K-loop) ----------------
    int abase[4];
    #pragma unroll
    for (int mt = 0; mt < 4; ++mt)
        abase[mt] = (24*mt + (ln>>3)*12 + (ln&7)) * XSTR;
    int aoff[20];
    #pragma unroll
    for (int c = 0; c < 20; ++c){
        int tap, inner;
        if (c < 13){ tap = 2*c + (quad>>1); inner = (quad&1)*8; }
        else       { tap = 4*(c-13) + quad; inner = 16; }
        int pt = 0;   // invalid taps -> pixel 0 (weights are zero there)
        if (tap < 25){ int kh = tap/5, kw = tap-5*kh; pt = kh*12 + kw; }
        aoff[c] = pt*XSTR + inner;
    }

    float sc2 = ws[0];
    int co = wv*16 + ln;
    float bias = (co < 50) ? ws[OFF_B2 + co] : 0.0f;
    const ushort_t* bsrc = w2bt + (size_t)co*32 + quad*8;

    floatx4 acc[4];
    #pragma unroll
    for (int mt = 0; mt < 4; ++mt) acc[mt] = (floatx4){0.f,0.f,0.f,0.f};

    #pragma unroll
    for (int c = 0; c < 20; ++c){
        ushort8 bw = *(const ushort8*)(bsrc + c*2048);
        bf16x8 bfr = __builtin_bit_cast(bf16x8, bw);
        #pragma unroll
        for (int mt = 0; mt < 4; ++mt){
            ushort8 aw = *(const ushort8*)(xs + abase[mt] + aoff[c]);
            acc[mt] = __builtin_amdgcn_mfma_f32_16x16x32_bf16(
                          __builtin_bit_cast(bf16x8, aw), bfr, acc[mt], 0, 0, 0);
        }
    }

    #pragma unroll
    for (int mt = 0; mt < 4; ++mt){
        float q[4];
        #pragma unroll
        for (int r = 0; r < 4; ++r){
            float y = fmaxf((acc[mt][r]*sc2 + bias) / S_N2, 0.0f);
            q[r] = fmodf(rintf(y), 256.0f);
        }
        float h0 = fmaxf(q[0], q[1]), h1 = fmaxf(q[2], q[3]);
        float v0 = fmaxf(h0, __shfl_xor(h0, 32));
        float v1 = fmaxf(h1, __shfl_xor(h1, 32));
        if (quad < 2 && co < 50){
            size_t base = (size_t)b*800 + co*16 + mt*4 + quad*2;
            q2bf[base]     = bfbits(v0);
            q2bf[base + 1] = bfbits(v1);
        }
    }
}

// fc1 via bf16 MFMA GEMM: [B,800] x [512,800]^T, tile 64x64, K-chunk 32, dbuf LDS.
__global__ __launch_bounds__(TPB) void k_fc1(const ushort_t* q2bf, const ushort_t* w3bf,
                                             const float* ws, unsigned char* q3, int B){
    __shared__ ushort_t As[2][64*40];
    int tid = threadIdx.x;
    int n0b = blockIdx.x * 64;
    int b0  = blockIdx.y * 64;
    int lane = tid & 63, wv = tid >> 6;
    int ln = lane & 15, quad = lane >> 4;
    int n0 = n0b + wv*16;
    int lrow = tid >> 2, lk = (tid & 3) * 8;
    const ushort_t* asrc = q2bf + (size_t)(b0 + lrow)*800 + lk;
    ushort_t* adst0 = &As[0][0] + lrow*40 + lk;
    ushort_t* adst1 = &As[1][0] + lrow*40 + lk;

    floatx4 acc[4];
    #pragma unroll
    for (int mt = 0; mt < 4; ++mt) acc[mt] = (floatx4){0.f,0.f,0.f,0.f};

    *(ushort8*)adst0 = *(const ushort8*)asrc;
    __syncthreads();

    for (int c = 0; c < 25; ++c){
        const ushort_t* cur = &As[c & 1][0];
        ushort8 tn;
        bool pf = (c + 1 < 25);
        if (pf) tn = *(const ushort8*)(asrc + (c + 1)*32);
        ushort8 bw = *(const ushort8*)(w3bf + (size_t)(n0 + ln)*800 + c*32 + quad*8);
        bf16x8 bfr = __builtin_bit_cast(bf16x8, bw);
        #pragma unroll
        for (int mt = 0; mt < 4; ++mt){
            ushort8 aw = *(const ushort8*)(cur + (16*mt + ln)*40 + quad*8);
            acc[mt] = __builtin_amdgcn_mfma_f32_16x16x32_bf16(
                          __builtin_bit_cast(bf16x8, aw), bfr, acc[mt], 0, 0, 0);
        }
        if (pf) *(ushort8*)(((c + 1) & 1) ? adst1 : adst0) = tn;
        __syncthreads();
    }

    float sc3 = ws[1];
    int n = n0 + ln;
    if (n < 500){
        float bias = ws[OFF_B3 + n];
        #pragma unroll
        for (int mt = 0; mt < 4; ++mt){
            #pragma unroll
            for (int r = 0; r < 4; ++r){
                int m = 16*mt + 4*quad + r;
                float y = fmaxf((acc[mt][r] * sc3 + bias) / S_N3, 0.0f);
                float q = fmodf(rintf(y), 256.0f);
                q3[(size_t)(b0 + m)*500 + n] = (unsigned char)q;
            }
        }
    }
}

// fc2 (dequant + [B,500]x[10,500]^T + bias) + log_softmax. 16 rows/block, w2 in LDS.
__global__ __launch_bounds__(TPB) void k_fc2(const unsigned char* q3, const float* w2,
                                             const float* b2, float* out, int B){
    __shared__ float w2s[5000];
    __shared__ float b2s[10];
    int tid = threadIdx.x;
    for (int i = tid; i < 5000; i += TPB) w2s[i] = w2[i];
    if (tid < 10) b2s[tid] = b2[tid];
    __syncthreads();
    int lane = tid & 63, wv = tid >> 6;
    for (int rr = 0; rr < 4; ++rr){
        int b = blockIdx.x*16 + wv*4 + rr;
        if (b >= B) break;
        float acc[10];
        #pragma unroll
        for (int c = 0; c < 10; ++c) acc[c] = 0.0f;
        for (int k = lane; k < 500; k += 64){
            float xf = S_N3 * (float)q3[(size_t)b*500 + k];
            #pragma unroll
            for (int c = 0; c < 10; ++c)
                acc[c] = fmaf(xf, w2s[c*500 + k], acc[c]);
        }
        #pragma unroll
        for (int off = 32; off > 0; off >>= 1)
            #pragma unroll
            for (int c = 0; c < 10; ++c)
                acc[c] += __shfl_xor(acc[c], off);
        float lg[10], m = -INFINITY;
        #pragma unroll
        for (int c = 0; c < 10; ++c){ lg[c] = acc[c] + b2s[c]; m = fmaxf(m, lg[c]); }
        float sum = 0.0f;
        #pragma unroll
        for (int c = 0; c < 10; ++c) sum += expf(lg[c] - m);
        float ls = logf(sum);
        if (lane < 10) out[(size_t)b*10 + lane] = lg[lane] - m - ls;
    }
}

extern "C" void kernel_launch(void* const* d_in, const int* in_sizes, int n_in,
                              void* d_out, int out_size, void* d_ws, size_t ws_size,
                              hipStream_t stream){
    const float* x   = (const float*)d_in[0];
    const float* c1w = (const float*)d_in[1];
    const float* c1b = (const float*)d_in[2];
    const float* c2w = (const float*)d_in[3];
    const float* c2b = (const float*)d_in[4];
    const float* f1w = (const float*)d_in[5];
    const float* f1b = (const float*)d_in[6];
    const float* f2w = (const float*)d_in[7];
    const float* f2b = (const float*)d_in[8];
    int B = in_sizes[0] / 784;

    float* ws = (float*)d_ws;
    unsigned int* enc = (unsigned int*)d_ws + 4;
    ushort_t* w1bf = (ushort_t*)((char*)d_ws + W1BF_BYTE);
    ushort_t* w2bf = (ushort_t*)((char*)d_ws + W2BF_BYTE);
    ushort_t* w3bf = (ushort_t*)((char*)d_ws + W3BF_BYTE);
    ushort_t* q2bf = (ushort_t*)((char*)d_ws + Q2_BYTE);
    unsigned char* q3 = (unsigned char*)d_ws + Q3_BYTE;
    float* out = (float*)d_out;

    k_init<<<1, 64, 0, stream>>>(enc);
    k_minmax<<<72, TPB, 0, stream>>>(c1w, c1b, c2w, c2b, f1w, f1b, enc);
    k_make_eff<<<(N_EFF + TPB - 1)/TPB, TPB, 0, stream>>>(c1w, c1b, c2w, c2b, f1w, f1b, enc, ws, w1bf, w2bf, w3bf);
    k_conv12<<<B, TPB, 0, stream>>>(x, w1bf, w2bf, ws, q2bf, B);
    dim3 g_fc1(8, B/64);
    k_fc1<<<g_fc1, TPB, 0, stream>>>(q2bf, w3bf, ws, q3, B);
    k_fc2<<<(B + 15)/16, TPB, 0, stream>>>(q3, f2w, f2b, out, B);
}

// Round 9
// 175.909 us; speedup vs baseline: 1.2732x; 1.0106x over previous
//
#include <hip/hip_runtime.h>
#include <cmath>

#define TPB 256
typedef float floatx4 __attribute__((ext_vector_type(4)));
typedef __bf16 bf16x8 __attribute__((ext_vector_type(8)));
typedef unsigned short ushort8 __attribute__((ext_vector_type(8)));
typedef unsigned short ushort_t;

// ---------- workspace layout (float units) ----------
// [0]=sc2d ((S_N1*s_w2)/S_N2), [1]=sc3d ((S_N2*s_w3)/S_N3), [2]=K1 ((S_X1*s_w1)/S_N1)
// [16..88) = pmn[72] partial mins, [96..168) = pmx[72] partial maxes
#define OFF_PMN 16
#define OFF_PMX 96
#define OFF_B1 520       // 20  f32  (pre-divided by S_N1)
#define OFF_B2 544       // 50  f32  (pre-divided by S_N2)
#define OFF_B3 600       // 500 f32  (pre-divided by S_N3)
#define W1BF_BYTE 6144       // [32][32] u16 int weights (conv1)
#define W2BF_BYTE 8192       // [20 chunks][64 co][32 k] u16 int weights (conv2), 81920 B
#define W3BF_BYTE 131072     // [512][800]  u16 int weights (fc1)
#define Q2_BYTE  29360128ULL // [B][800] bf16 (6.6 MB)
#define Q3_BYTE  1048576ULL  // [B][500] u8

#define S_X1 (3.5f/255.0f)
#define ZP_X1 36.0f
#define S_N1 (6.0f/255.0f)
#define S_N2 (8.0f/255.0f)
#define S_N3 (10.0f/255.0f)

// LDS pixel stride for conv2 A-reads: 40 u16 = 80 B = 20 banks (period-32 -> conflict-free)
#define XSTR 40

__device__ inline float qclip(float x, float s, float zp){
    return rintf(fminf(fmaxf(zp + x / s, 0.0f), 255.0f));
}
// exact bf16 bits for integer-valued floats |v| < 256
__device__ inline ushort_t bfbits(float v){
    return (ushort_t)(__float_as_uint(v) >> 16);
}

// per-block min/max partials; block->tensor map: 0:c1w 1:c1b 2-5:c2w 6:c2b 7-70:f1w 71:f1b
__global__ __launch_bounds__(TPB) void k_minmax(
        const float* c1w, const float* c1b, const float* c2w, const float* c2b,
        const float* f1w, const float* f1b, float* pmn, float* pmx){
    __shared__ float smn[TPB], smx[TPB];
    int bb = blockIdx.x, tid = threadIdx.x;
    const float* src; int n, sub, nsub;
    if      (bb == 0){ src=c1w; n=500;    sub=0;     nsub=1;  }
    else if (bb == 1){ src=c1b; n=20;     sub=0;     nsub=1;  }
    else if (bb <  6){ src=c2w; n=25000;  sub=bb-2;  nsub=4;  }
    else if (bb == 6){ src=c2b; n=50;     sub=0;     nsub=1;  }
    else if (bb < 71){ src=f1w; n=400000; sub=bb-7;  nsub=64; }
    else             { src=f1b; n=500;    sub=0;     nsub=1;  }
    float mn = INFINITY, mx = -INFINITY;
    for (int i = sub*TPB + tid; i < n; i += nsub*TPB){
        float v = src[i]; mn = fminf(mn, v); mx = fmaxf(mx, v);
    }
    smn[tid] = mn; smx[tid] = mx; __syncthreads();
    for (int s = TPB/2; s > 0; s >>= 1){
        if (tid < s){
            smn[tid] = fminf(smn[tid], smn[tid+s]);
            smx[tid] = fmaxf(smx[tid], smx[tid+s]);
        }
        __syncthreads();
    }
    if (tid == 0){ pmn[bb] = smn[0]; pmx[bb] = smx[0]; }
}

// w2bt chunk packing (20 chunks of K=32):
//   main c in 0..12:   oct q -> tap = 2c + (q>>1), ci = (q&1)*8 + jj   (tap 25 -> zero)
//   residue c in 13..19: oct q -> tap = 4(c-13) + q, ci = 16 + jj (jj<4; jj>=4 -> zero)
#define N_EFF 452157
__global__ __launch_bounds__(TPB) void k_make_eff(
        const float* c1w, const float* c1b, const float* c2w, const float* c2b,
        const float* f1w, const float* f1b, const float* pmn, const float* pmx,
        float* ws, ushort_t* w1bf, ushort_t* w2bf, ushort_t* w3bf){
    __shared__ float sS[6], sZ[6];
    int tid = threadIdx.x;
    int wv = tid >> 6, lane = tid & 63;
    // wave-parallel reduce of partials -> per-tensor s, zp (once per block)
    const int starts[6] = {0,1,2,6,7,71};
    const int counts[6] = {1,1,4,1,64,1};
    #pragma unroll
    for (int rep = 0; rep < 2; ++rep){
        int t = wv + rep*4;
        if (t < 6){
            float mn = INFINITY, mx = -INFINITY;
            if (lane < counts[t]){ mn = pmn[starts[t]+lane]; mx = pmx[starts[t]+lane]; }
            #pragma unroll
            for (int off = 32; off > 0; off >>= 1){
                mn = fminf(mn, __shfl_xor(mn, off));
                mx = fmaxf(mx, __shfl_xor(mx, off));
            }
            if (lane == 0){
                float s = (mx - mn) / 255.0f;
                sS[t] = s;
                sZ[t] = truncf(fminf(fmaxf(0.0f - mn / s, 0.0f), 255.0f));
            }
        }
    }
    __syncthreads();

    int i = blockIdx.x * TPB + tid;
    if (i >= N_EFF) return;
    if (i < 1024){                   // w1bf: [n(32)][k(32)] integer weights
        int n = i >> 5, k = i & 31;
        float v = 0.0f;
        if (n < 20 && k < 25) v = qclip(c1w[n*25 + k], sS[0], sZ[0]) - sZ[0];
        w1bf[i] = bfbits(v);
    } else if (i < 1044){            // b1 pre-divided by S_N1
        int j = i - 1024;
        ws[OFF_B1 + j] = (sS[1] * (qclip(c1b[j], sS[1], sZ[1]) + sZ[1])) / S_N1;
    } else if (i < 42004){           // w2bt chunk-packed
        int j = i - 1044;
        int c = j >> 11, r = j & 2047, co = r >> 5, k = r & 31;
        int q = k >> 3, jj = k & 7;
        int tap, ci; bool valid;
        if (c < 13){ tap = 2*c + (q>>1); ci = (q&1)*8 + jj; valid = (tap < 25); }
        else       { tap = 4*(c-13) + q; ci = 16 + jj;      valid = (tap < 25) && (jj < 4); }
        valid = valid && (co < 50);
        float v = 0.0f;
        if (valid) v = qclip(c2w[(co*20 + ci)*25 + tap], sS[2], sZ[2]) - sZ[2];
        w2bf[j] = bfbits(v);
    } else if (i < 42054){           // b2 pre-divided by S_N2
        int j = i - 42004;
        ws[OFF_B2 + j] = (sS[3] * (qclip(c2b[j], sS[3], sZ[3]) + sZ[3])) / S_N2;
    } else if (i < 451654){          // w3bf: [n(512)][k(800)]
        int j = i - 42054;
        int n = j / 800, k = j - 800*n;
        float v = 0.0f;
        if (n < 500) v = qclip(f1w[n*800 + k], sS[4], sZ[4]) - sZ[4];
        w3bf[j] = bfbits(v);
    } else if (i < 452154){          // b3 pre-divided by S_N3
        int j = i - 451654;
        ws[OFF_B3 + j] = (sS[5] * (qclip(f1b[j], sS[5], sZ[5]) + sZ[5])) / S_N3;
    } else if (i == 452154){
        ws[0] = (S_N1 * sS[2]) / S_N2;   // conv2 combined scale, pre-divided
    } else if (i == 452155){
        ws[1] = (S_N2 * sS[4]) / S_N3;   // fc1 combined scale, pre-divided
    } else {
        ws[2] = (S_X1 * sS[0]) / S_N1;   // conv1 combined scale, pre-divided
    }
}

// Fused conv1+conv2, one image per block. conv1 (MFMA, integer epilogue) pools via
// u16 hb (2 lanes/dword = conflict-free) into LDS xs[pixel][XSTR] channels-last;
// conv2 (round-7 verified K-loop) consumes it. q1 never touches HBM.
__global__ __launch_bounds__(TPB) void k_conv12(const float* x, const ushort_t* w1bf,
                                                const ushort_t* w2bt, const float* ws,
                                                ushort_t* q2bf, int B){
    __shared__ __align__(16) ushort_t xs[144*XSTR];   // conv2 input; first 784 alias conv1 input
    __shared__ ushort_t hbu[5760];                    // [oh(24)*12+owp][ch(20)] h-pool maxes (u16)
    ushort_t* x1 = xs;   // conv1 quantized input (lifetime ends before xs written; barriers separate)
    int b = blockIdx.x, tid = threadIdx.x;
    int lane = tid & 63, wv = tid >> 6;
    int ln = lane & 15, quad = lane >> 4;

    // ---------------- conv1 phase ----------------
    const float* xb = x + (size_t)b * 784;
    for (int i = tid; i < 784; i += TPB){
        float v = xb[i];
        float q = rintf(fminf(fmaxf(ZP_X1 + v / S_X1, 0.0f), 255.0f));
        x1[i] = bfbits(q - ZP_X1);
    }

    int offj[8]; bool vj[8];
    #pragma unroll
    for (int j = 0; j < 8; ++j){
        int k = quad*8 + j;
        vj[j] = (k < 25);
        int kh = k / 5, kw = k - 5*kh;
        offj[j] = vj[j] ? (kh*28 + kw) : 0;
    }

    ushort8 bw0 = *(const ushort8*)(w1bf + ln*32 + quad*8);
    ushort8 bw1 = *(const ushort8*)(w1bf + (16 + ln)*32 + quad*8);
    bf16x8 bf0 = __builtin_bit_cast(bf16x8, bw0);
    bf16x8 bf1 = __builtin_bit_cast(bf16x8, bw1);

    float K1 = ws[2];
    float B1_0 = ws[OFF_B1 + ln];
    float B1_1 = (ln < 4) ? ws[OFF_B1 + 16 + ln] : 0.0f;
    __syncthreads();

    for (int i = 0; i < 9; ++i){
        int mt = 9*wv + i;
        int m = mt*16 + ln;
        int oh = m / 24, ow = m - 24*oh;
        int base = oh*28 + ow;
        ushort8 aw;
        #pragma unroll
        for (int j = 0; j < 8; ++j)
            aw[j] = vj[j] ? x1[base + offj[j]] : (ushort_t)0;
        bf16x8 af = __builtin_bit_cast(bf16x8, aw);
        floatx4 z = (floatx4){0.f,0.f,0.f,0.f};
        floatx4 a0 = __builtin_amdgcn_mfma_f32_16x16x32_bf16(af, bf0, z, 0, 0, 0);
        floatx4 a1 = __builtin_amdgcn_mfma_f32_16x16x32_bf16(af, bf1, z, 0, 0, 0);

        // integer epilogue: for y>=0, (uint)rintf(y) & 255 == fmod(rint(y),256) exactly.
        // D layout: row=position m0+r, col=channel ln. h-pool pairs (r0,r1),(r2,r3).
        int m0 = mt*16 + quad*4;
        int oh0 = m0 / 24, owp = (m0 - 24*oh0) >> 1;
        int hbase = (oh0*12 + owp)*20;
        {
            unsigned int qv[4];
            #pragma unroll
            for (int r = 0; r < 4; ++r){
                float y = fmaxf(fmaf(a0[r], K1, B1_0), 0.0f);
                qv[r] = ((unsigned int)rintf(y)) & 255u;
            }
            unsigned int h0 = qv[0] > qv[1] ? qv[0] : qv[1];
            unsigned int h1 = qv[2] > qv[3] ? qv[2] : qv[3];
            hbu[hbase + ln]      = (ushort_t)h0;
            hbu[hbase + 20 + ln] = (ushort_t)h1;
        }
        if (ln < 4){
            unsigned int qv[4];
            #pragma unroll
            for (int r = 0; r < 4; ++r){
                float y = fmaxf(fmaf(a1[r], K1, B1_1), 0.0f);
                qv[r] = ((unsigned int)rintf(y)) & 255u;
            }
            unsigned int h0 = qv[0] > qv[1] ? qv[0] : qv[1];
            unsigned int h1 = qv[2] > qv[3] ? qv[2] : qv[3];
            hbu[hbase + 16 + ln]      = (ushort_t)h0;
            hbu[hbase + 36 + ln]      = (ushort_t)h1;
        }
    }
    __syncthreads();

    // vertical pool into xs channels-last [pixel(144)][XSTR] (ci 20-23 zeroed; 24-39 unread)
    for (int o = tid; o < 3456; o += TPB){
        int p = o / 24, c = o - 24*p;
        unsigned int m_ = 0;
        if (c < 20){
            int ph = p / 12, pw = p - 12*ph;
            unsigned int t_ = hbu[((2*ph)*12 + pw)*20 + c];
            unsigned int u_ = hbu[((2*ph+1)*12 + pw)*20 + c];
            m_ = t_ > u_ ? t_ : u_;
        }
        xs[p*XSTR + c] = bfbits((float)m_);
    }
    __syncthreads();

    // ---------------- conv2 phase (round-7 verified K-loop) ----------------
    int abase[4];
    #pragma unroll
    for (int mt = 0; mt < 4; ++mt)
        abase[mt] = (24*mt + (ln>>3)*12 + (ln&7)) * XSTR;
    int aoff[20];
    #pragma unroll
    for (int c = 0; c < 20; ++c){
        int tap, inner;
        if (c < 13){ tap = 2*c + (quad>>1); inner = (quad&1)*8; }
        else       { tap = 4*(c-13) + quad; inner = 16; }
        int pt = 0;   // invalid taps -> pixel 0 (weights are zero there)
        if (tap < 25){ int kh = tap/5, kw = tap-5*kh; pt = kh*12 + kw; }
        aoff[c] = pt*XSTR + inner;
    }

    float sc2d = ws[0];                                  // pre-divided by S_N2
    int co = wv*16 + ln;
    float bias2d = (co < 50) ? ws[OFF_B2 + co] : 0.0f;   // pre-divided by S_N2
    const ushort_t* bsrc = w2bt + (size_t)co*32 + quad*8;

    floatx4 acc[4];
    #pragma unroll
    for (int mt = 0; mt < 4; ++mt) acc[mt] = (floatx4){0.f,0.f,0.f,0.f};

    #pragma unroll
    for (int c = 0; c < 20; ++c){
        ushort8 bw = *(const ushort8*)(bsrc + c*2048);
        bf16x8 bfr = __builtin_bit_cast(bf16x8, bw);
        #pragma unroll
        for (int mt = 0; mt < 4; ++mt){
            ushort8 aw = *(const ushort8*)(xs + abase[mt] + aoff[c]);
            acc[mt] = __builtin_amdgcn_mfma_f32_16x16x32_bf16(
                          __builtin_bit_cast(bf16x8, aw), bfr, acc[mt], 0, 0, 0);
        }
    }

    #pragma unroll
    for (int mt = 0; mt < 4; ++mt){
        unsigned int qv[4];
        #pragma unroll
        for (int r = 0; r < 4; ++r){
            float y = fmaxf(fmaf(acc[mt][r], sc2d, bias2d), 0.0f);
            qv[r] = ((unsigned int)rintf(y)) & 255u;
        }
        unsigned int h0 = qv[0] > qv[1] ? qv[0] : qv[1];
        unsigned int h1 = qv[2] > qv[3] ? qv[2] : qv[3];
        unsigned int p0 = (unsigned int)__shfl_xor((int)h0, 32);
        unsigned int p1 = (unsigned int)__shfl_xor((int)h1, 32);
        unsigned int v0 = h0 > p0 ? h0 : p0;
        unsigned int v1 = h1 > p1 ? h1 : p1;
        if (quad < 2 && co < 50){
            size_t base = (size_t)b*800 + co*16 + mt*4 + quad*2;
            q2bf[base]     = bfbits((float)v0);
            q2bf[base + 1] = bfbits((float)v1);
        }
    }
}

// fc1 via bf16 MFMA GEMM: [B,800] x [512,800]^T, tile 64x64, K-chunk 32, dbuf LDS.
__global__ __launch_bounds__(TPB) void k_fc1(const ushort_t* q2bf, const ushort_t* w3bf,
                                             const float* ws, unsigned char* q3, int B){
    __shared__ ushort_t As[2][64*40];
    int tid = threadIdx.x;
    int n0b = blockIdx.x * 64;
    int b0  = blockIdx.y * 64;
    int lane = tid & 63, wv = tid >> 6;
    int ln = lane & 15, quad = lane >> 4;
    int n0 = n0b + wv*16;
    int lrow = tid >> 2, lk = (tid & 3) * 8;
    const ushort_t* asrc = q2bf + (size_t)(b0 + lrow)*800 + lk;
    ushort_t* adst0 = &As[0][0] + lrow*40 + lk;
    ushort_t* adst1 = &As[1][0] + lrow*40 + lk;

    floatx4 acc[4];
    #pragma unroll
    for (int mt = 0; mt < 4; ++mt) acc[mt] = (floatx4){0.f,0.f,0.f,0.f};

    *(ushort8*)adst0 = *(const ushort8*)asrc;
    __syncthreads();

    for (int c = 0; c < 25; ++c){
        const ushort_t* cur = &As[c & 1][0];
        ushort8 tn;
        bool pf = (c + 1 < 25);
        if (pf) tn = *(const ushort8*)(asrc + (c + 1)*32);
        ushort8 bw = *(const ushort8*)(w3bf + (size_t)(n0 + ln)*800 + c*32 + quad*8);
        bf16x8 bfr = __builtin_bit_cast(bf16x8, bw);
        #pragma unroll
        for (int mt = 0; mt < 4; ++mt){
            ushort8 aw = *(const ushort8*)(cur + (16*mt + ln)*40 + quad*8);
            acc[mt] = __builtin_amdgcn_mfma_f32_16x16x32_bf16(
                          __builtin_bit_cast(bf16x8, aw), bfr, acc[mt], 0, 0, 0);
        }
        if (pf) *(ushort8*)(((c + 1) & 1) ? adst1 : adst0) = tn;
        __syncthreads();
    }

    float sc3d = ws[1];                       // pre-divided by S_N3
    int n = n0 + ln;
    if (n < 500){
        float bias = ws[OFF_B3 + n];          // pre-divided by S_N3
        #pragma unroll
        for (int mt = 0; mt < 4; ++mt){
            #pragma unroll
            for (int r = 0; r < 4; ++r){
                int m = 16*mt + 4*quad + r;
                float y = fmaxf(fmaf(acc[mt][r], sc3d, bias), 0.0f);
                q3[(size_t)(b0 + m)*500 + n] = (unsigned char)(((unsigned int)rintf(y)) & 255u);
            }
        }
    }
}

// fc2 (dequant + [B,500]x[10,500]^T + bias) + log_softmax. 16 rows/block, w2 in LDS.
__global__ __launch_bounds__(TPB) void k_fc2(const unsigned char* q3, const float* w2,
                                             const float* b2, float* out, int B){
    __shared__ float w2s[5000];
    __shared__ float b2s[10];
    int tid = threadIdx.x;
    for (int i = tid; i < 5000; i += TPB) w2s[i] = w2[i];
    if (tid < 10) b2s[tid] = b2[tid];
    __syncthreads();
    int lane = tid & 63, wv = tid >> 6;
    for (int rr = 0; rr < 4; ++rr){
        int b = blockIdx.x*16 + wv*4 + rr;
        if (b >= B) break;
        float acc[10];
        #pragma unroll
        for (int c = 0; c < 10; ++c) acc[c] = 0.0f;
        for (int k = lane; k < 500; k += 64){
            float xf = S_N3 * (float)q3[(size_t)b*500 + k];
            #pragma unroll
            for (int c = 0; c < 10; ++c)
                acc[c] = fmaf(xf, w2s[c*500 + k], acc[c]);
        }
        #pragma unroll
        for (int off = 32; off > 0; off >>= 1)
            #pragma unroll
            for (int c = 0; c < 10; ++c)
                acc[c] += __shfl_xor(acc[c], off);
        float lg[10], m = -INFINITY;
        #pragma unroll
        for (int c = 0; c < 10; ++c){ lg[c] = acc[c] + b2s[c]; m = fmaxf(m, lg[c]); }
        float sum = 0.0f;
        #pragma unroll
        for (int c = 0; c < 10; ++c) sum += expf(lg[c] - m);
        float ls = logf(sum);
        if (lane < 10) out[(size_t)b*10 + lane] = lg[lane] - m - ls;
    }
}

extern "C" void kernel_launch(void* const* d_in, const int* in_sizes, int n_in,
                              void* d_out, int out_size, void* d_ws, size_t ws_size,
                              hipStream_t stream){
    const float* x   = (const float*)d_in[0];
    const float* c1w = (const float*)d_in[1];
    const float* c1b = (const float*)d_in[2];
    const float* c2w = (const float*)d_in[3];
    const float* c2b = (const float*)d_in[4];
    const float* f1w = (const float*)d_in[5];
    const float* f1b = (const float*)d_in[6];
    const float* f2w = (const float*)d_in[7];
    const float* f2b = (const float*)d_in[8];
    int B = in_sizes[0] / 784;

    float* ws = (float*)d_ws;
    float* pmn = ws + OFF_PMN;
    float* pmx = ws + OFF_PMX;
    ushort_t* w1bf = (ushort_t*)((char*)d_ws + W1BF_BYTE);
    ushort_t* w2bf = (ushort_t*)((char*)d_ws + W2BF_BYTE);
    ushort_t* w3bf = (ushort_t*)((char*)d_ws + W3BF_BYTE);
    ushort_t* q2bf = (ushort_t*)((char*)d_ws + Q2_BYTE);
    unsigned char* q3 = (unsigned char*)d_ws + Q3_BYTE;
    float* out = (float*)d_out;

    k_minmax<<<72, TPB, 0, stream>>>(c1w, c1b, c2w, c2b, f1w, f1b, pmn, pmx);
    k_make_eff<<<(N_EFF + TPB - 1)/TPB, TPB, 0, stream>>>(c1w, c1b, c2w, c2b, f1w, f1b, pmn, pmx, ws, w1bf, w2bf, w3bf);
    k_conv12<<<B, TPB, 0, stream>>>(x, w1bf, w2bf, ws, q2bf, B);
    dim3 g_fc1(8, B/64);
    k_fc1<<<g_fc1, TPB, 0, stream>>>(q2bf, w3bf, ws, q3, B);
    k_fc2<<<(B + 15)/16, TPB, 0, stream>>>(q3, f2w, f2b, out, B);
}

// Round 11
// 174.149 us; speedup vs baseline: 1.2861x; 1.0101x over previous
//
#include <hip/hip_runtime.h>
#include <cmath>

#define TPB 256
typedef float floatx4 __attribute__((ext_vector_type(4)));
typedef __bf16 bf16x8 __attribute__((ext_vector_type(8)));
typedef unsigned short ushort8 __attribute__((ext_vector_type(8)));
typedef unsigned short ushort_t;

// ---------- workspace layout (float units) ----------
// [0]=sc2d ((S_N1*s_w2)/S_N2), [1]=sc3d ((S_N2*s_w3)/S_N3), [2]=K1 ((S_X1*s_w1)/S_N1)
// [16..88) = pmn[72] partial mins, [96..168) = pmx[72] partial maxes
#define OFF_PMN 16
#define OFF_PMX 96
#define OFF_B1 520       // 20  f32  (pre-divided by S_N1)
#define OFF_B2 544       // 50  f32  (pre-divided by S_N2)
#define OFF_B3 600       // 500 f32  (pre-divided by S_N3)
#define W1BF_BYTE 6144       // [32][32] u16 int weights (conv1)
#define W2BF_BYTE 8192       // [20 chunks][64 co][32 k] u16 int weights (conv2), 81920 B
#define W3BF_BYTE 131072     // [512][800]  u16 int weights (fc1)
#define Q2_BYTE  29360128ULL // [B][800] bf16 (6.6 MB)
#define Q3_BYTE  1048576ULL  // [B][500] u8

#define S_X1 (3.5f/255.0f)
#define ZP_X1 36.0f
#define S_N1 (6.0f/255.0f)
#define S_N2 (8.0f/255.0f)
#define S_N3 (10.0f/255.0f)

// LDS pixel stride for conv2 A-reads: 40 u16 = 80 B = 20 banks (period-32 -> conflict-free)
#define XSTR 40

__device__ inline float qclip(float x, float s, float zp){
    return rintf(fminf(fmaxf(zp + x / s, 0.0f), 255.0f));
}
// exact bf16 bits for integer-valued floats |v| < 256
__device__ inline ushort_t bfbits(float v){
    return (ushort_t)(__float_as_uint(v) >> 16);
}

// per-block min/max partials; block->tensor map: 0:c1w 1:c1b 2-5:c2w 6:c2b 7-70:f1w 71:f1b
__global__ __launch_bounds__(TPB) void k_minmax(
        const float* c1w, const float* c1b, const float* c2w, const float* c2b,
        const float* f1w, const float* f1b, float* pmn, float* pmx){
    __shared__ float smn[TPB], smx[TPB];
    int bb = blockIdx.x, tid = threadIdx.x;
    const float* src; int n, sub, nsub;
    if      (bb == 0){ src=c1w; n=500;    sub=0;     nsub=1;  }
    else if (bb == 1){ src=c1b; n=20;     sub=0;     nsub=1;  }
    else if (bb <  6){ src=c2w; n=25000;  sub=bb-2;  nsub=4;  }
    else if (bb == 6){ src=c2b; n=50;     sub=0;     nsub=1;  }
    else if (bb < 71){ src=f1w; n=400000; sub=bb-7;  nsub=64; }
    else             { src=f1b; n=500;    sub=0;     nsub=1;  }
    float mn = INFINITY, mx = -INFINITY;
    for (int i = sub*TPB + tid; i < n; i += nsub*TPB){
        float v = src[i]; mn = fminf(mn, v); mx = fmaxf(mx, v);
    }
    smn[tid] = mn; smx[tid] = mx; __syncthreads();
    for (int s = TPB/2; s > 0; s >>= 1){
        if (tid < s){
            smn[tid] = fminf(smn[tid], smn[tid+s]);
            smx[tid] = fmaxf(smx[tid], smx[tid+s]);
        }
        __syncthreads();
    }
    if (tid == 0){ pmn[bb] = smn[0]; pmx[bb] = smx[0]; }
}

// w2bt chunk packing (20 chunks of K=32):
//   main c in 0..12:   oct q -> tap = 2c + (q>>1), ci = (q&1)*8 + jj   (tap 25 -> zero)
//   residue c in 13..19: oct q -> tap = 4(c-13) + q, ci = 16 + jj (jj<4; jj>=4 -> zero)
#define N_EFF 452157
__global__ __launch_bounds__(TPB) void k_make_eff(
        const float* c1w, const float* c1b, const float* c2w, const float* c2b,
        const float* f1w, const float* f1b, const float* pmn, const float* pmx,
        float* ws, ushort_t* w1bf, ushort_t* w2bf, ushort_t* w3bf){
    __shared__ float sS[6], sZ[6];
    int tid = threadIdx.x;
    int wv = tid >> 6, lane = tid & 63;
    const int starts[6] = {0,1,2,6,7,71};
    const int counts[6] = {1,1,4,1,64,1};
    #pragma unroll
    for (int rep = 0; rep < 2; ++rep){
        int t = wv + rep*4;
        if (t < 6){
            float mn = INFINITY, mx = -INFINITY;
            if (lane < counts[t]){ mn = pmn[starts[t]+lane]; mx = pmx[starts[t]+lane]; }
            #pragma unroll
            for (int off = 32; off > 0; off >>= 1){
                mn = fminf(mn, __shfl_xor(mn, off));
                mx = fmaxf(mx, __shfl_xor(mx, off));
            }
            if (lane == 0){
                float s = (mx - mn) / 255.0f;
                sS[t] = s;
                sZ[t] = truncf(fminf(fmaxf(0.0f - mn / s, 0.0f), 255.0f));
            }
        }
    }
    __syncthreads();

    int i = blockIdx.x * TPB + tid;
    if (i >= N_EFF) return;
    if (i < 1024){                   // w1bf: [n(32)][k(32)] integer weights
        int n = i >> 5, k = i & 31;
        float v = 0.0f;
        if (n < 20 && k < 25) v = qclip(c1w[n*25 + k], sS[0], sZ[0]) - sZ[0];
        w1bf[i] = bfbits(v);
    } else if (i < 1044){            // b1 pre-divided by S_N1
        int j = i - 1024;
        ws[OFF_B1 + j] = (sS[1] * (qclip(c1b[j], sS[1], sZ[1]) + sZ[1])) / S_N1;
    } else if (i < 42004){           // w2bt chunk-packed
        int j = i - 1044;
        int c = j >> 11, r = j & 2047, co = r >> 5, k = r & 31;
        int q = k >> 3, jj = k & 7;
        int tap, ci; bool valid;
        if (c < 13){ tap = 2*c + (q>>1); ci = (q&1)*8 + jj; valid = (tap < 25); }
        else       { tap = 4*(c-13) + q; ci = 16 + jj;      valid = (tap < 25) && (jj < 4); }
        valid = valid && (co < 50);
        float v = 0.0f;
        if (valid) v = qclip(c2w[(co*20 + ci)*25 + tap], sS[2], sZ[2]) - sZ[2];
        w2bf[j] = bfbits(v);
    } else if (i < 42054){           // b2 pre-divided by S_N2
        int j = i - 42004;
        ws[OFF_B2 + j] = (sS[3] * (qclip(c2b[j], sS[3], sZ[3]) + sZ[3])) / S_N2;
    } else if (i < 451654){          // w3bf: [n(512)][k(800)]
        int j = i - 42054;
        int n = j / 800, k = j - 800*n;
        float v = 0.0f;
        if (n < 500) v = qclip(f1w[n*800 + k], sS[4], sZ[4]) - sZ[4];
        w3bf[j] = bfbits(v);
    } else if (i < 452154){          // b3 pre-divided by S_N3
        int j = i - 451654;
        ws[OFF_B3 + j] = (sS[5] * (qclip(f1b[j], sS[5], sZ[5]) + sZ[5])) / S_N3;
    } else if (i == 452154){
        ws[0] = (S_N1 * sS[2]) / S_N2;   // conv2 combined scale, pre-divided
    } else if (i == 452155){
        ws[1] = (S_N2 * sS[4]) / S_N3;   // fc1 combined scale, pre-divided
    } else {
        ws[2] = (S_X1 * sS[0]) / S_N1;   // conv1 combined scale, pre-divided
    }
}

// Fused conv1+conv2, one image per block.
// conv1: 4 per-quad image copies (784 u16 = 392 dwords = +8 banks apart -> quads in
// separate bank windows, kills the gather conflicts). Integer epilogue, u16 hb.
// conv2: 2mt x 2nt per wave (A LDS reads halved vs 4mt x 1nt; B from L2) — round-6-verified map.
__global__ __launch_bounds__(TPB) void k_conv12(const float* x, const ushort_t* w1bf,
                                                const ushort_t* w2bt, const float* ws,
                                                ushort_t* q2bf, int B){
    __shared__ __align__(16) ushort_t xs[144*XSTR];   // conv2 input; first 3136 alias xim
    __shared__ ushort_t hbu[5760];                    // [oh(24)*12+owp][ch(20)] h-pool maxes
    ushort_t* xim = xs;   // 4 copies of quantized 784-u16 image (dead before xs written)
    int b = blockIdx.x, tid = threadIdx.x;
    int lane = tid & 63, wv = tid >> 6;
    int ln = lane & 15, quad = lane >> 4;

    // ---------------- conv1 phase ----------------
    const float* xb = x + (size_t)b * 784;
    for (int i = tid; i < 784; i += TPB){
        float v = xb[i];
        float q = rintf(fminf(fmaxf(ZP_X1 + v / S_X1, 0.0f), 255.0f));
        ushort_t bits = bfbits(q - ZP_X1);
        xim[i] = bits; xim[784 + i] = bits; xim[1568 + i] = bits; xim[2352 + i] = bits;
    }

    int offj[8]; bool vj[8];
    #pragma unroll
    for (int j = 0; j < 8; ++j){
        int k = quad*8 + j;
        vj[j] = (k < 25);
        int kh = k / 5, kw = k - 5*kh;
        offj[j] = vj[j] ? (kh*28 + kw) : 0;
    }
    const ushort_t* xq = xim + quad*784;   // this quad's private copy

    ushort8 bw0 = *(const ushort8*)(w1bf + ln*32 + quad*8);
    ushort8 bw1 = *(const ushort8*)(w1bf + (16 + ln)*32 + quad*8);
    bf16x8 bf0 = __builtin_bit_cast(bf16x8, bw0);
    bf16x8 bf1 = __builtin_bit_cast(bf16x8, bw1);

    float K1 = ws[2];
    float B1_0 = ws[OFF_B1 + ln];
    float B1_1 = (ln < 4) ? ws[OFF_B1 + 16 + ln] : 0.0f;
    __syncthreads();

    for (int i = 0; i < 9; ++i){
        int mt = 9*wv + i;
        int m = mt*16 + ln;
        int oh = m / 24, ow = m - 24*oh;
        int base = oh*28 + ow;
        ushort8 aw;
        #pragma unroll
        for (int j = 0; j < 8; ++j)
            aw[j] = vj[j] ? xq[base + offj[j]] : (ushort_t)0;
        bf16x8 af = __builtin_bit_cast(bf16x8, aw);
        floatx4 z = (floatx4){0.f,0.f,0.f,0.f};
        floatx4 a0 = __builtin_amdgcn_mfma_f32_16x16x32_bf16(af, bf0, z, 0, 0, 0);
        floatx4 a1 = __builtin_amdgcn_mfma_f32_16x16x32_bf16(af, bf1, z, 0, 0, 0);

        // integer epilogue: for y>=0, (uint)rintf(y) & 255 == fmod(rint(y),256) exactly
        int m0 = mt*16 + quad*4;
        int oh0 = m0 / 24, owp = (m0 - 24*oh0) >> 1;
        int hbase = (oh0*12 + owp)*20;
        {
            unsigned int qv[4];
            #pragma unroll
            for (int r = 0; r < 4; ++r){
                float y = fmaxf(fmaf(a0[r], K1, B1_0), 0.0f);
                qv[r] = ((unsigned int)rintf(y)) & 255u;
            }
            unsigned int h0 = qv[0] > qv[1] ? qv[0] : qv[1];
            unsigned int h1 = qv[2] > qv[3] ? qv[2] : qv[3];
            hbu[hbase + ln]      = (ushort_t)h0;
            hbu[hbase + 20 + ln] = (ushort_t)h1;
        }
        if (ln < 4){
            unsigned int qv[4];
            #pragma unroll
            for (int r = 0; r < 4; ++r){
                float y = fmaxf(fmaf(a1[r], K1, B1_1), 0.0f);
                qv[r] = ((unsigned int)rintf(y)) & 255u;
            }
            unsigned int h0 = qv[0] > qv[1] ? qv[0] : qv[1];
            unsigned int h1 = qv[2] > qv[3] ? qv[2] : qv[3];
            hbu[hbase + 16 + ln]      = (ushort_t)h0;
            hbu[hbase + 36 + ln]      = (ushort_t)h1;
        }
    }
    __syncthreads();   // xim reads done; xs may now be overwritten

    // vertical pool into xs channels-last [pixel(144)][XSTR] (ci 20-23 zeroed; 24-39 unread)
    for (int o = tid; o < 3456; o += TPB){
        int p = o / 24, c = o - 24*p;
        unsigned int m_ = 0;
        if (c < 20){
            int ph = p / 12, pw = p - 12*ph;
            unsigned int t_ = hbu[((2*ph)*12 + pw)*20 + c];
            unsigned int u_ = hbu[((2*ph+1)*12 + pw)*20 + c];
            m_ = t_ > u_ ? t_ : u_;
        }
        xs[p*XSTR + c] = bfbits((float)m_);
    }
    __syncthreads();

    // ---------------- conv2 phase: wave owns 2mt x 2nt ----------------
    int mt0 = (wv & 1) * 2;
    int nt0 = (wv >> 1) * 2;
    int abase[2];
    #pragma unroll
    for (int mi = 0; mi < 2; ++mi)
        abase[mi] = (24*(mt0+mi) + (ln>>3)*12 + (ln&7)) * XSTR;
    int aoff[20];
    #pragma unroll
    for (int c = 0; c < 20; ++c){
        int tap, inner;
        if (c < 13){ tap = 2*c + (quad>>1); inner = (quad&1)*8; }
        else       { tap = 4*(c-13) + quad; inner = 16; }
        int pt = 0;   // invalid taps -> pixel 0 (weights are zero there)
        if (tap < 25){ int kh = tap/5, kw = tap-5*kh; pt = kh*12 + kw; }
        aoff[c] = pt*XSTR + inner;
    }

    float sc2d = ws[0];
    const ushort_t* bsrc0 = w2bt + (size_t)(nt0*16 + ln)*32 + quad*8;
    const ushort_t* bsrc1 = bsrc0 + 16*32;

    floatx4 acc[2][2];
    #pragma unroll
    for (int mi = 0; mi < 2; ++mi)
        #pragma unroll
        for (int ni = 0; ni < 2; ++ni) acc[mi][ni] = (floatx4){0.f,0.f,0.f,0.f};

    #pragma unroll
    for (int c = 0; c < 20; ++c){
        ushort8 b0w = *(const ushort8*)(bsrc0 + c*2048);
        ushort8 b1w = *(const ushort8*)(bsrc1 + c*2048);
        ushort8 a0w = *(const ushort8*)(xs + abase[0] + aoff[c]);
        ushort8 a1w = *(const ushort8*)(xs + abase[1] + aoff[c]);
        bf16x8 a0 = __builtin_bit_cast(bf16x8, a0w);
        bf16x8 a1 = __builtin_bit_cast(bf16x8, a1w);
        bf16x8 b0 = __builtin_bit_cast(bf16x8, b0w);
        bf16x8 b1 = __builtin_bit_cast(bf16x8, b1w);
        acc[0][0] = __builtin_amdgcn_mfma_f32_16x16x32_bf16(a0, b0, acc[0][0], 0, 0, 0);
        acc[0][1] = __builtin_amdgcn_mfma_f32_16x16x32_bf16(a0, b1, acc[0][1], 0, 0, 0);
        acc[1][0] = __builtin_amdgcn_mfma_f32_16x16x32_bf16(a1, b0, acc[1][0], 0, 0, 0);
        acc[1][1] = __builtin_amdgcn_mfma_f32_16x16x32_bf16(a1, b1, acc[1][1], 0, 0, 0);
    }

    #pragma unroll
    for (int ni = 0; ni < 2; ++ni){
        int co = (nt0 + ni)*16 + ln;
        float bias2d = (co < 50) ? ws[OFF_B2 + co] : 0.0f;
        #pragma unroll
        for (int mi = 0; mi < 2; ++mi){
            int mt = mt0 + mi;
            unsigned int qv[4];
            #pragma unroll
            for (int r = 0; r < 4; ++r){
                float y = fmaxf(fmaf(acc[mi][ni][r], sc2d, bias2d), 0.0f);
                qv[r] = ((unsigned int)rintf(y)) & 255u;
            }
            unsigned int h0 = qv[0] > qv[1] ? qv[0] : qv[1];
            unsigned int h1 = qv[2] > qv[3] ? qv[2] : qv[3];
            unsigned int p0 = (unsigned int)__shfl_xor((int)h0, 32);
            unsigned int p1 = (unsigned int)__shfl_xor((int)h1, 32);
            unsigned int v0 = h0 > p0 ? h0 : p0;
            unsigned int v1 = h1 > p1 ? h1 : p1;
            if (quad < 2 && co < 50){
                size_t base = (size_t)b*800 + co*16 + mt*4 + quad*2;
                q2bf[base]     = bfbits((float)v0);
                q2bf[base + 1] = bfbits((float)v1);
            }
        }
    }
}

// fc1 via bf16 MFMA GEMM: [B,800] x [512,800]^T, tile 64x64, K-chunk 32, dbuf LDS.
// (exact round-9 passing version)
__global__ __launch_bounds__(TPB) void k_fc1(const ushort_t* q2bf, const ushort_t* w3bf,
                                             const float* ws, unsigned char* q3, int B){
    __shared__ ushort_t As[2][64*40];
    int tid = threadIdx.x;
    int n0b = blockIdx.x * 64;
    int b0  = blockIdx.y * 64;
    int lane = tid & 63, wv = tid >> 6;
    int ln = lane & 15, quad = lane >> 4;
    int n0 = n0b + wv*16;
    int lrow = tid >> 2, lk = (tid & 3) * 8;
    const ushort_t* asrc = q2bf + (size_t)(b0 + lrow)*800 + lk;
    ushort_t* adst0 = &As[0][0] + lrow*40 + lk;
    ushort_t* adst1 = &As[1][0] + lrow*40 + lk;

    floatx4 acc[4];
    #pragma unroll
    for (int mt = 0; mt < 4; ++mt) acc[mt] = (floatx4){0.f,0.f,0.f,0.f};

    *(ushort8*)adst0 = *(const ushort8*)asrc;
    __syncthreads();

    for (int c = 0; c < 25; ++c){
        const ushort_t* cur = &As[c & 1][0];
        ushort8 tn;
        bool pf = (c + 1 < 25);
        if (pf) tn = *(const ushort8*)(asrc + (c + 1)*32);
        ushort8 bw = *(const ushort8*)(w3bf + (size_t)(n0 + ln)*800 + c*32 + quad*8);
        bf16x8 bfr = __builtin_bit_cast(bf16x8, bw);
        #pragma unroll
        for (int mt = 0; mt < 4; ++mt){
            ushort8 aw = *(const ushort8*)(cur + (16*mt + ln)*40 + quad*8);
            acc[mt] = __builtin_amdgcn_mfma_f32_16x16x32_bf16(
                          __builtin_bit_cast(bf16x8, aw), bfr, acc[mt], 0, 0, 0);
        }
        if (pf) *(ushort8*)(((c + 1) & 1) ? adst1 : adst0) = tn;
        __syncthreads();
    }

    float sc3d = ws[1];                       // pre-divided by S_N3
    int n = n0 + ln;
    if (n < 500){
        float bias = ws[OFF_B3 + n];          // pre-divided by S_N3
        #pragma unroll
        for (int mt = 0; mt < 4; ++mt){
            #pragma unroll
            for (int r = 0; r < 4; ++r){
                int m = 16*mt + 4*quad + r;
                float y = fmaxf(fmaf(acc[mt][r], sc3d, bias), 0.0f);
                q3[(size_t)(b0 + m)*500 + n] = (unsigned char)(((unsigned int)rintf(y)) & 255u);
            }
        }
    }
}

// fc2 (dequant + [B,500]x[10,500]^T + bias) + log_softmax. 16 rows/block, w2 in LDS.
// (exact round-9 passing version)
__global__ __launch_bounds__(TPB) void k_fc2(const unsigned char* q3, const float* w2,
                                             const float* b2, float* out, int B){
    __shared__ float w2s[5000];
    __shared__ float b2s[10];
    int tid = threadIdx.x;
    for (int i = tid; i < 5000; i += TPB) w2s[i] = w2[i];
    if (tid < 10) b2s[tid] = b2[tid];
    __syncthreads();
    int lane = tid & 63, wv = tid >> 6;
    for (int rr = 0; rr < 4; ++rr){
        int b = blockIdx.x*16 + wv*4 + rr;
        if (b >= B) break;
        float acc[10];
        #pragma unroll
        for (int c = 0; c < 10; ++c) acc[c] = 0.0f;
        for (int k = lane; k < 500; k += 64){
            float xf = S_N3 * (float)q3[(size_t)b*500 + k];
            #pragma unroll
            for (int c = 0; c < 10; ++c)
                acc[c] = fmaf(xf, w2s[c*500 + k], acc[c]);
        }
        #pragma unroll
        for (int off = 32; off > 0; off >>= 1)
            #pragma unroll
            for (int c = 0; c < 10; ++c)
                acc[c] += __shfl_xor(acc[c], off);
        float lg[10], m = -INFINITY;
        #pragma unroll
        for (int c = 0; c < 10; ++c){ lg[c] = acc[c] + b2s[c]; m = fmaxf(m, lg[c]); }
        float sum = 0.0f;
        #pragma unroll
        for (int c = 0; c < 10; ++c) sum += expf(lg[c] - m);
        float ls = logf(sum);
        if (lane < 10) out[(size_t)b*10 + lane] = lg[lane] - m - ls;
    }
}

extern "C" void kernel_launch(void* const* d_in, const int* in_sizes, int n_in,
                              void* d_out, int out_size, void* d_ws, size_t ws_size,
                              hipStream_t stream){
    const float* x   = (const float*)d_in[0];
    const float* c1w = (const float*)d_in[1];
    const float* c1b = (const float*)d_in[2];
    const float* c2w = (const float*)d_in[3];
    const float* c2b = (const float*)d_in[4];
    const float* f1w = (const float*)d_in[5];
    const float* f1b = (const float*)d_in[6];
    const float* f2w = (const float*)d_in[7];
    const float* f2b = (const float*)d_in[8];
    int B = in_sizes[0] / 784;

    float* ws = (float*)d_ws;
    float* pmn = ws + OFF_PMN;
    float* pmx = ws + OFF_PMX;
    ushort_t* w1bf = (ushort_t*)((char*)d_ws + W1BF_BYTE);
    ushort_t* w2bf = (ushort_t*)((char*)d_ws + W2BF_BYTE);
    ushort_t* w3bf = (ushort_t*)((char*)d_ws + W3BF_BYTE);
    ushort_t* q2bf = (ushort_t*)((char*)d_ws + Q2_BYTE);
    unsigned char* q3 = (unsigned char*)d_ws + Q3_BYTE;
    float* out = (float*)d_out;

    k_minmax<<<72, TPB, 0, stream>>>(c1w, c1b, c2w, c2b, f1w, f1b, pmn, pmx);
    k_make_eff<<<(N_EFF + TPB - 1)/TPB, TPB, 0, stream>>>(c1w, c1b, c2w, c2b, f1w, f1b, pmn, pmx, ws, w1bf, w2bf, w3bf);
    k_conv12<<<B, TPB, 0, stream>>>(x, w1bf, w2bf, ws, q2bf, B);
    dim3 g_fc1(8, B/64);
    k_fc1<<<g_fc1, TPB, 0, stream>>>(q2bf, w3bf, ws, q3, B);
    k_fc2<<<(B + 15)/16, TPB, 0, stream>>>(q3, f2w, f2b, out, B);
}

// Round 12
// 173.301 us; speedup vs baseline: 1.2923x; 1.0049x over previous
//
#include <hip/hip_runtime.h>
#include <cmath>

#define TPB 256
typedef float floatx4 __attribute__((ext_vector_type(4)));
typedef __bf16 bf16x8 __attribute__((ext_vector_type(8)));
typedef unsigned short ushort8 __attribute__((ext_vector_type(8)));
typedef unsigned short ushort_t;

// ---------- workspace layout (float units) ----------
// [0]=sc2d ((S_N1*s_w2)/S_N2), [1]=sc3d ((S_N2*s_w3)/S_N3), [2]=K1 ((S_X1*s_w1)/S_N1)
// [16..88) = pmn[72] partial mins, [96..168) = pmx[72] partial maxes
#define OFF_PMN 16
#define OFF_PMX 96
#define OFF_B1 520       // 20  f32  (pre-divided by S_N1)
#define OFF_B2 544       // 50  f32  (pre-divided by S_N2)
#define OFF_B3 600       // 500 f32  (pre-divided by S_N3)
#define W1BF_BYTE 6144       // [32][32] u16 int weights (conv1)
#define W2BF_BYTE 8192       // [20 chunks][64 co][32 k] u16 int weights (conv2), 81920 B
#define W3BF_BYTE 131072     // [512][800]  u16 int weights (fc1)
#define Q2_BYTE  29360128ULL // [B][800] bf16 (6.6 MB)
#define Q3_BYTE  1048576ULL  // [B][500] u8

#define S_X1 (3.5f/255.0f)
#define ZP_X1 36.0f
#define S_N1 (6.0f/255.0f)
#define S_N2 (8.0f/255.0f)
#define S_N3 (10.0f/255.0f)

// LDS pixel stride for conv2 A-reads: 40 u16 = 80 B = 20 banks (period-32 -> conflict-free)
#define XSTR 40

__device__ inline float qclip(float x, float s, float zp){
    return rintf(fminf(fmaxf(zp + x / s, 0.0f), 255.0f));
}
// exact bf16 bits for integer-valued floats |v| < 256
__device__ inline ushort_t bfbits(float v){
    return (ushort_t)(__float_as_uint(v) >> 16);
}

// per-block min/max partials; block->tensor map: 0:c1w 1:c1b 2-5:c2w 6:c2b 7-70:f1w 71:f1b
__global__ __launch_bounds__(TPB) void k_minmax(
        const float* c1w, const float* c1b, const float* c2w, const float* c2b,
        const float* f1w, const float* f1b, float* pmn, float* pmx){
    __shared__ float smn[TPB], smx[TPB];
    int bb = blockIdx.x, tid = threadIdx.x;
    const float* src; int n, sub, nsub;
    if      (bb == 0){ src=c1w; n=500;    sub=0;     nsub=1;  }
    else if (bb == 1){ src=c1b; n=20;     sub=0;     nsub=1;  }
    else if (bb <  6){ src=c2w; n=25000;  sub=bb-2;  nsub=4;  }
    else if (bb == 6){ src=c2b; n=50;     sub=0;     nsub=1;  }
    else if (bb < 71){ src=f1w; n=400000; sub=bb-7;  nsub=64; }
    else             { src=f1b; n=500;    sub=0;     nsub=1;  }
    float mn = INFINITY, mx = -INFINITY;
    for (int i = sub*TPB + tid; i < n; i += nsub*TPB){
        float v = src[i]; mn = fminf(mn, v); mx = fmaxf(mx, v);
    }
    smn[tid] = mn; smx[tid] = mx; __syncthreads();
    for (int s = TPB/2; s > 0; s >>= 1){
        if (tid < s){
            smn[tid] = fminf(smn[tid], smn[tid+s]);
            smx[tid] = fmaxf(smx[tid], smx[tid+s]);
        }
        __syncthreads();
    }
    if (tid == 0){ pmn[bb] = smn[0]; pmx[bb] = smx[0]; }
}

// w2bt chunk packing (20 chunks of K=32):
//   main c in 0..12:   oct q -> tap = 2c + (q>>1), ci = (q&1)*8 + jj   (tap 25 -> zero)
//   residue c in 13..19: oct q -> tap = 4(c-13) + q, ci = 16 + jj (jj<4; jj>=4 -> zero)
#define N_EFF 452157
__global__ __launch_bounds__(TPB) void k_make_eff(
        const float* c1w, const float* c1b, const float* c2w, const float* c2b,
        const float* f1w, const float* f1b, const float* pmn, const float* pmx,
        float* ws, ushort_t* w1bf, ushort_t* w2bf, ushort_t* w3bf){
    __shared__ float sS[6], sZ[6];
    int tid = threadIdx.x;
    int wv = tid >> 6, lane = tid & 63;
    const int starts[6] = {0,1,2,6,7,71};
    const int counts[6] = {1,1,4,1,64,1};
    #pragma unroll
    for (int rep = 0; rep < 2; ++rep){
        int t = wv + rep*4;
        if (t < 6){
            float mn = INFINITY, mx = -INFINITY;
            if (lane < counts[t]){ mn = pmn[starts[t]+lane]; mx = pmx[starts[t]+lane]; }
            #pragma unroll
            for (int off = 32; off > 0; off >>= 1){
                mn = fminf(mn, __shfl_xor(mn, off));
                mx = fmaxf(mx, __shfl_xor(mx, off));
            }
            if (lane == 0){
                float s = (mx - mn) / 255.0f;
                sS[t] = s;
                sZ[t] = truncf(fminf(fmaxf(0.0f - mn / s, 0.0f), 255.0f));
            }
        }
    }
    __syncthreads();

    int i = blockIdx.x * TPB + tid;
    if (i >= N_EFF) return;
    if (i < 1024){                   // w1bf: [n(32)][k(32)] integer weights
        int n = i >> 5, k = i & 31;
        float v = 0.0f;
        if (n < 20 && k < 25) v = qclip(c1w[n*25 + k], sS[0], sZ[0]) - sZ[0];
        w1bf[i] = bfbits(v);
    } else if (i < 1044){            // b1 pre-divided by S_N1
        int j = i - 1024;
        ws[OFF_B1 + j] = (sS[1] * (qclip(c1b[j], sS[1], sZ[1]) + sZ[1])) / S_N1;
    } else if (i < 42004){           // w2bt chunk-packed
        int j = i - 1044;
        int c = j >> 11, r = j & 2047, co = r >> 5, k = r & 31;
        int q = k >> 3, jj = k & 7;
        int tap, ci; bool valid;
        if (c < 13){ tap = 2*c + (q>>1); ci = (q&1)*8 + jj; valid = (tap < 25); }
        else       { tap = 4*(c-13) + q; ci = 16 + jj;      valid = (tap < 25) && (jj < 4); }
        valid = valid && (co < 50);
        float v = 0.0f;
        if (valid) v = qclip(c2w[(co*20 + ci)*25 + tap], sS[2], sZ[2]) - sZ[2];
        w2bf[j] = bfbits(v);
    } else if (i < 42054){           // b2 pre-divided by S_N2
        int j = i - 42004;
        ws[OFF_B2 + j] = (sS[3] * (qclip(c2b[j], sS[3], sZ[3]) + sZ[3])) / S_N2;
    } else if (i < 451654){          // w3bf: [n(512)][k(800)]
        int j = i - 42054;
        int n = j / 800, k = j - 800*n;
        float v = 0.0f;
        if (n < 500) v = qclip(f1w[n*800 + k], sS[4], sZ[4]) - sZ[4];
        w3bf[j] = bfbits(v);
    } else if (i < 452154){          // b3 pre-divided by S_N3
        int j = i - 451654;
        ws[OFF_B3 + j] = (sS[5] * (qclip(f1b[j], sS[5], sZ[5]) + sZ[5])) / S_N3;
    } else if (i == 452154){
        ws[0] = (S_N1 * sS[2]) / S_N2;   // conv2 combined scale, pre-divided
    } else if (i == 452155){
        ws[1] = (S_N2 * sS[4]) / S_N3;   // fc1 combined scale, pre-divided
    } else {
        ws[2] = (S_X1 * sS[0]) / S_N1;   // conv1 combined scale, pre-divided
    }
}

// Fused conv1+conv2, one image per block. (exact round-11 passing version)
__global__ __launch_bounds__(TPB) void k_conv12(const float* x, const ushort_t* w1bf,
                                                const ushort_t* w2bt, const float* ws,
                                                ushort_t* q2bf, int B){
    __shared__ __align__(16) ushort_t xs[144*XSTR];   // conv2 input; first 3136 alias xim
    __shared__ ushort_t hbu[5760];                    // [oh(24)*12+owp][ch(20)] h-pool maxes
    ushort_t* xim = xs;   // 4 copies of quantized 784-u16 image (dead before xs written)
    int b = blockIdx.x, tid = threadIdx.x;
    int lane = tid & 63, wv = tid >> 6;
    int ln = lane & 15, quad = lane >> 4;

    // ---------------- conv1 phase ----------------
    const float* xb = x + (size_t)b * 784;
    for (int i = tid; i < 784; i += TPB){
        float v = xb[i];
        float q = rintf(fminf(fmaxf(ZP_X1 + v / S_X1, 0.0f), 255.0f));
        ushort_t bits = bfbits(q - ZP_X1);
        xim[i] = bits; xim[784 + i] = bits; xim[1568 + i] = bits; xim[2352 + i] = bits;
    }

    int offj[8]; bool vj[8];
    #pragma unroll
    for (int j = 0; j < 8; ++j){
        int k = quad*8 + j;
        vj[j] = (k < 25);
        int kh = k / 5, kw = k - 5*kh;
        offj[j] = vj[j] ? (kh*28 + kw) : 0;
    }
    const ushort_t* xq = xim + quad*784;   // this quad's private copy

    ushort8 bw0 = *(const ushort8*)(w1bf + ln*32 + quad*8);
    ushort8 bw1 = *(const ushort8*)(w1bf + (16 + ln)*32 + quad*8);
    bf16x8 bf0 = __builtin_bit_cast(bf16x8, bw0);
    bf16x8 bf1 = __builtin_bit_cast(bf16x8, bw1);

    float K1 = ws[2];
    float B1_0 = ws[OFF_B1 + ln];
    float B1_1 = (ln < 4) ? ws[OFF_B1 + 16 + ln] : 0.0f;
    __syncthreads();

    for (int i = 0; i < 9; ++i){
        int mt = 9*wv + i;
        int m = mt*16 + ln;
        int oh = m / 24, ow = m - 24*oh;
        int base = oh*28 + ow;
        ushort8 aw;
        #pragma unroll
        for (int j = 0; j < 8; ++j)
            aw[j] = vj[j] ? xq[base + offj[j]] : (ushort_t)0;
        bf16x8 af = __builtin_bit_cast(bf16x8, aw);
        floatx4 z = (floatx4){0.f,0.f,0.f,0.f};
        floatx4 a0 = __builtin_amdgcn_mfma_f32_16x16x32_bf16(af, bf0, z, 0, 0, 0);
        floatx4 a1 = __builtin_amdgcn_mfma_f32_16x16x32_bf16(af, bf1, z, 0, 0, 0);

        // integer epilogue: for y>=0, (uint)rintf(y) & 255 == fmod(rint(y),256) exactly
        int m0 = mt*16 + quad*4;
        int oh0 = m0 / 24, owp = (m0 - 24*oh0) >> 1;
        int hbase = (oh0*12 + owp)*20;
        {
            unsigned int qv[4];
            #pragma unroll
            for (int r = 0; r < 4; ++r){
                float y = fmaxf(fmaf(a0[r], K1, B1_0), 0.0f);
                qv[r] = ((unsigned int)rintf(y)) & 255u;
            }
            unsigned int h0 = qv[0] > qv[1] ? qv[0] : qv[1];
            unsigned int h1 = qv[2] > qv[3] ? qv[2] : qv[3];
            hbu[hbase + ln]      = (ushort_t)h0;
            hbu[hbase + 20 + ln] = (ushort_t)h1;
        }
        if (ln < 4){
            unsigned int qv[4];
            #pragma unroll
            for (int r = 0; r < 4; ++r){
                float y = fmaxf(fmaf(a1[r], K1, B1_1), 0.0f);
                qv[r] = ((unsigned int)rintf(y)) & 255u;
            }
            unsigned int h0 = qv[0] > qv[1] ? qv[0] : qv[1];
            unsigned int h1 = qv[2] > qv[3] ? qv[2] : qv[3];
            hbu[hbase + 16 + ln]      = (ushort_t)h0;
            hbu[hbase + 36 + ln]      = (ushort_t)h1;
        }
    }
    __syncthreads();   // xim reads done; xs may now be overwritten

    // vertical pool into xs channels-last [pixel(144)][XSTR] (ci 20-23 zeroed; 24-39 unread)
    for (int o = tid; o < 3456; o += TPB){
        int p = o / 24, c = o - 24*p;
        unsigned int m_ = 0;
        if (c < 20){
            int ph = p / 12, pw = p - 12*ph;
            unsigned int t_ = hbu[((2*ph)*12 + pw)*20 + c];
            unsigned int u_ = hbu[((2*ph+1)*12 + pw)*20 + c];
            m_ = t_ > u_ ? t_ : u_;
        }
        xs[p*XSTR + c] = bfbits((float)m_);
    }
    __syncthreads();

    // ---------------- conv2 phase: wave owns 2mt x 2nt ----------------
    int mt0 = (wv & 1) * 2;
    int nt0 = (wv >> 1) * 2;
    int abase[2];
    #pragma unroll
    for (int mi = 0; mi < 2; ++mi)
        abase[mi] = (24*(mt0+mi) + (ln>>3)*12 + (ln&7)) * XSTR;
    int aoff[20];
    #pragma unroll
    for (int c = 0; c < 20; ++c){
        int tap, inner;
        if (c < 13){ tap = 2*c + (quad>>1); inner = (quad&1)*8; }
        else       { tap = 4*(c-13) + quad; inner = 16; }
        int pt = 0;   // invalid taps -> pixel 0 (weights are zero there)
        if (tap < 25){ int kh = tap/5, kw = tap-5*kh; pt = kh*12 + kw; }
        aoff[c] = pt*XSTR + inner;
    }

    float sc2d = ws[0];
    const ushort_t* bsrc0 = w2bt + (size_t)(nt0*16 + ln)*32 + quad*8;
    const ushort_t* bsrc1 = bsrc0 + 16*32;

    floatx4 acc[2][2];
    #pragma unroll
    for (int mi = 0; mi < 2; ++mi)
        #pragma unroll
        for (int ni = 0; ni < 2; ++ni) acc[mi][ni] = (floatx4){0.f,0.f,0.f,0.f};

    #pragma unroll
    for (int c = 0; c < 20; ++c){
        ushort8 b0w = *(const ushort8*)(bsrc0 + c*2048);
        ushort8 b1w = *(const ushort8*)(bsrc1 + c*2048);
        ushort8 a0w = *(const ushort8*)(xs + abase[0] + aoff[c]);
        ushort8 a1w = *(const ushort8*)(xs + abase[1] + aoff[c]);
        bf16x8 a0 = __builtin_bit_cast(bf16x8, a0w);
        bf16x8 a1 = __builtin_bit_cast(bf16x8, a1w);
        bf16x8 b0 = __builtin_bit_cast(bf16x8, b0w);
        bf16x8 b1 = __builtin_bit_cast(bf16x8, b1w);
        acc[0][0] = __builtin_amdgcn_mfma_f32_16x16x32_bf16(a0, b0, acc[0][0], 0, 0, 0);
        acc[0][1] = __builtin_amdgcn_mfma_f32_16x16x32_bf16(a0, b1, acc[0][1], 0, 0, 0);
        acc[1][0] = __builtin_amdgcn_mfma_f32_16x16x32_bf16(a1, b0, acc[1][0], 0, 0, 0);
        acc[1][1] = __builtin_amdgcn_mfma_f32_16x16x32_bf16(a1, b1, acc[1][1], 0, 0, 0);
    }

    #pragma unroll
    for (int ni = 0; ni < 2; ++ni){
        int co = (nt0 + ni)*16 + ln;
        float bias2d = (co < 50) ? ws[OFF_B2 + co] : 0.0f;
        #pragma unroll
        for (int mi = 0; mi < 2; ++mi){
            int mt = mt0 + mi;
            unsigned int qv[4];
            #pragma unroll
            for (int r = 0; r < 4; ++r){
                float y = fmaxf(fmaf(acc[mi][ni][r], sc2d, bias2d), 0.0f);
                qv[r] = ((unsigned int)rintf(y)) & 255u;
            }
            unsigned int h0 = qv[0] > qv[1] ? qv[0] : qv[1];
            unsigned int h1 = qv[2] > qv[3] ? qv[2] : qv[3];
            unsigned int p0 = (unsigned int)__shfl_xor((int)h0, 32);
            unsigned int p1 = (unsigned int)__shfl_xor((int)h1, 32);
            unsigned int v0 = h0 > p0 ? h0 : p0;
            unsigned int v1 = h1 > p1 ? h1 : p1;
            if (quad < 2 && co < 50){
                size_t base = (size_t)b*800 + co*16 + mt*4 + quad*2;
                q2bf[base]     = bfbits((float)v0);
                q2bf[base + 1] = bfbits((float)v1);
            }
        }
    }
}

// fc1 v2: barrier-free, LDS-free MFMA GEMM (conv2-v5 pattern, HW-verified round 6).
// Block = 32 rows x 64 cols, grid (8, B/32) = 1024 blocks (4/CU). Wave: 2mt x 16n,
// acc = 8 VGPRs. A and B both stream from L2-resident global (q2bf 6.6 MB, w3bf 800 KB).
__global__ __launch_bounds__(TPB) void k_fc1(const ushort_t* q2bf, const ushort_t* w3bf,
                                             const float* ws, unsigned char* q3, int B){
    int tid = threadIdx.x;
    int lane = tid & 63, wv = tid >> 6;
    int ln = lane & 15, quad = lane >> 4;
    int n0 = blockIdx.x * 64 + wv*16;
    int b0 = blockIdx.y * 32;

    const ushort_t* bsrc = w3bf + (size_t)(n0 + ln)*800 + quad*8;
    const ushort_t* asrc0 = q2bf + (size_t)(b0 + ln)*800 + quad*8;
    const ushort_t* asrc1 = q2bf + (size_t)(b0 + 16 + ln)*800 + quad*8;

    floatx4 acc[2];
    #pragma unroll
    for (int mt = 0; mt < 2; ++mt) acc[mt] = (floatx4){0.f,0.f,0.f,0.f};

    #pragma unroll
    for (int c = 0; c < 25; ++c){
        ushort8 bw  = *(const ushort8*)(bsrc  + c*32);
        ushort8 a0w = *(const ushort8*)(asrc0 + c*32);
        ushort8 a1w = *(const ushort8*)(asrc1 + c*32);
        bf16x8 bfr = __builtin_bit_cast(bf16x8, bw);
        acc[0] = __builtin_amdgcn_mfma_f32_16x16x32_bf16(
                     __builtin_bit_cast(bf16x8, a0w), bfr, acc[0], 0, 0, 0);
        acc[1] = __builtin_amdgcn_mfma_f32_16x16x32_bf16(
                     __builtin_bit_cast(bf16x8, a1w), bfr, acc[1], 0, 0, 0);
    }

    float sc3d = ws[1];                       // pre-divided by S_N3
    int n = n0 + ln;
    if (n < 500){
        float bias = ws[OFF_B3 + n];          // pre-divided by S_N3
        #pragma unroll
        for (int mt = 0; mt < 2; ++mt){
            #pragma unroll
            for (int r = 0; r < 4; ++r){
                int m = 16*mt + 4*quad + r;
                float y = fmaxf(fmaf(acc[mt][r], sc3d, bias), 0.0f);
                q3[(size_t)(b0 + m)*500 + n] = (unsigned char)(((unsigned int)rintf(y)) & 255u);
            }
        }
    }
}

// fc2 (dequant + [B,500]x[10,500]^T + bias) + log_softmax. 16 rows/block, w2 in LDS.
// (exact round-9 passing version)
__global__ __launch_bounds__(TPB) void k_fc2(const unsigned char* q3, const float* w2,
                                             const float* b2, float* out, int B){
    __shared__ float w2s[5000];
    __shared__ float b2s[10];
    int tid = threadIdx.x;
    for (int i = tid; i < 5000; i += TPB) w2s[i] = w2[i];
    if (tid < 10) b2s[tid] = b2[tid];
    __syncthreads();
    int lane = tid & 63, wv = tid >> 6;
    for (int rr = 0; rr < 4; ++rr){
        int b = blockIdx.x*16 + wv*4 + rr;
        if (b >= B) break;
        float acc[10];
        #pragma unroll
        for (int c = 0; c < 10; ++c) acc[c] = 0.0f;
        for (int k = lane; k < 500; k += 64){
            float xf = S_N3 * (float)q3[(size_t)b*500 + k];
            #pragma unroll
            for (int c = 0; c < 10; ++c)
                acc[c] = fmaf(xf, w2s[c*500 + k], acc[c]);
        }
        #pragma unroll
        for (int off = 32; off > 0; off >>= 1)
            #pragma unroll
            for (int c = 0; c < 10; ++c)
                acc[c] += __shfl_xor(acc[c], off);
        float lg[10], m = -INFINITY;
        #pragma unroll
        for (int c = 0; c < 10; ++c){ lg[c] = acc[c] + b2s[c]; m = fmaxf(m, lg[c]); }
        float sum = 0.0f;
        #pragma unroll
        for (int c = 0; c < 10; ++c) sum += expf(lg[c] - m);
        float ls = logf(sum);
        if (lane < 10) out[(size_t)b*10 + lane] = lg[lane] - m - ls;
    }
}

extern "C" void kernel_launch(void* const* d_in, const int* in_sizes, int n_in,
                              void* d_out, int out_size, void* d_ws, size_t ws_size,
                              hipStream_t stream){
    const float* x   = (const float*)d_in[0];
    const float* c1w = (const float*)d_in[1];
    const float* c1b = (const float*)d_in[2];
    const float* c2w = (const float*)d_in[3];
    const float* c2b = (const float*)d_in[4];
    const float* f1w = (const float*)d_in[5];
    const float* f1b = (const float*)d_in[6];
    const float* f2w = (const float*)d_in[7];
    const float* f2b = (const float*)d_in[8];
    int B = in_sizes[0] / 784;

    float* ws = (float*)d_ws;
    float* pmn = ws + OFF_PMN;
    float* pmx = ws + OFF_PMX;
    ushort_t* w1bf = (ushort_t*)((char*)d_ws + W1BF_BYTE);
    ushort_t* w2bf = (ushort_t*)((char*)d_ws + W2BF_BYTE);
    ushort_t* w3bf = (ushort_t*)((char*)d_ws + W3BF_BYTE);
    ushort_t* q2bf = (ushort_t*)((char*)d_ws + Q2_BYTE);
    unsigned char* q3 = (unsigned char*)d_ws + Q3_BYTE;
    float* out = (float*)d_out;

    k_minmax<<<72, TPB, 0, stream>>>(c1w, c1b, c2w, c2b, f1w, f1b, pmn, pmx);
    k_make_eff<<<(N_EFF + TPB - 1)/TPB, TPB, 0, stream>>>(c1w, c1b, c2w, c2b, f1w, f1b, pmn, pmx, ws, w1bf, w2bf, w3bf);
    k_conv12<<<B, TPB, 0, stream>>>(x, w1bf, w2bf, ws, q2bf, B);
    dim3 g_fc1(8, (B + 31)/32);
    k_fc1<<<g_fc1, TPB, 0, stream>>>(q2bf, w3bf, ws, q3, B);
    k_fc2<<<(B + 15)/16, TPB, 0, stream>>>(q3, f2w, f2b, out, B);
}

// Round 13
// 164.053 us; speedup vs baseline: 1.3652x; 1.0564x over previous
//
#include <hip/hip_runtime.h>
#include <cmath>

#define TPB 256
typedef float floatx4 __attribute__((ext_vector_type(4)));
typedef __bf16 bf16x8 __attribute__((ext_vector_type(8)));
typedef unsigned short ushort8 __attribute__((ext_vector_type(8)));
typedef unsigned short ushort_t;

// ---------- workspace layout (float units) ----------
// [0]=sc2d ((S_N1*s_w2)/S_N2), [1]=sc3d ((S_N2*s_w3)/S_N3), [2]=K1 ((S_X1*s_w1)/S_N1)
// [16..88) = pmn[72] partial mins, [96..168) = pmx[72] partial maxes
#define OFF_PMN 16
#define OFF_PMX 96
#define OFF_B1 520       // 20  f32  (pre-divided by S_N1)
#define OFF_B2 544       // 50  f32  (pre-divided by S_N2)
#define OFF_B3 600       // 500 f32  (pre-divided by S_N3)
#define W1BF_BYTE 6144       // [32][32] u16 int weights (conv1)
#define W2BF_BYTE 8192       // [20 chunks][64 co][32 k] u16 int weights (conv2), 81920 B
#define W3BF_BYTE 131072     // [512][800]  u16 int weights (fc1)
#define Q2_BYTE  29360128ULL // [B][800] bf16 (6.6 MB)
#define Q3_BYTE  1048576ULL  // [B][500] u8

#define S_X1 (3.5f/255.0f)
#define ZP_X1 36.0f
#define S_N1 (6.0f/255.0f)
#define S_N2 (8.0f/255.0f)
#define S_N3 (10.0f/255.0f)

// LDS pixel stride for conv2 A-reads: 40 u16 = 80 B = 20 banks (period-32 -> conflict-free)
#define XSTR 40

__device__ inline float qclip(float x, float s, float zp){
    return rintf(fminf(fmaxf(zp + x / s, 0.0f), 255.0f));
}
// exact bf16 bits for integer-valued floats |v| < 256
__device__ inline ushort_t bfbits(float v){
    return (ushort_t)(__float_as_uint(v) >> 16);
}

// per-block min/max partials; block->tensor map: 0:c1w 1:c1b 2-5:c2w 6:c2b 7-70:f1w 71:f1b
__global__ __launch_bounds__(TPB) void k_minmax(
        const float* c1w, const float* c1b, const float* c2w, const float* c2b,
        const float* f1w, const float* f1b, float* pmn, float* pmx){
    __shared__ float smn[TPB], smx[TPB];
    int bb = blockIdx.x, tid = threadIdx.x;
    const float* src; int n, sub, nsub;
    if      (bb == 0){ src=c1w; n=500;    sub=0;     nsub=1;  }
    else if (bb == 1){ src=c1b; n=20;     sub=0;     nsub=1;  }
    else if (bb <  6){ src=c2w; n=25000;  sub=bb-2;  nsub=4;  }
    else if (bb == 6){ src=c2b; n=50;     sub=0;     nsub=1;  }
    else if (bb < 71){ src=f1w; n=400000; sub=bb-7;  nsub=64; }
    else             { src=f1b; n=500;    sub=0;     nsub=1;  }
    float mn = INFINITY, mx = -INFINITY;
    for (int i = sub*TPB + tid; i < n; i += nsub*TPB){
        float v = src[i]; mn = fminf(mn, v); mx = fmaxf(mx, v);
    }
    smn[tid] = mn; smx[tid] = mx; __syncthreads();
    for (int s = TPB/2; s > 0; s >>= 1){
        if (tid < s){
            smn[tid] = fminf(smn[tid], smn[tid+s]);
            smx[tid] = fmaxf(smx[tid], smx[tid+s]);
        }
        __syncthreads();
    }
    if (tid == 0){ pmn[bb] = smn[0]; pmx[bb] = smx[0]; }
}

// w2bt chunk packing (20 chunks of K=32):
//   main c in 0..12:   oct q -> tap = 2c + (q>>1), ci = (q&1)*8 + jj   (tap 25 -> zero)
//   residue c in 13..19: oct q -> tap = 4(c-13) + q, ci = 16 + jj (jj<4; jj>=4 -> zero)
#define N_EFF 452157
__global__ __launch_bounds__(TPB) void k_make_eff(
        const float* c1w, const float* c1b, const float* c2w, const float* c2b,
        const float* f1w, const float* f1b, const float* pmn, const float* pmx,
        float* ws, ushort_t* w1bf, ushort_t* w2bf, ushort_t* w3bf){
    __shared__ float sS[6], sZ[6];
    int tid = threadIdx.x;
    int wv = tid >> 6, lane = tid & 63;
    const int starts[6] = {0,1,2,6,7,71};
    const int counts[6] = {1,1,4,1,64,1};
    #pragma unroll
    for (int rep = 0; rep < 2; ++rep){
        int t = wv + rep*4;
        if (t < 6){
            float mn = INFINITY, mx = -INFINITY;
            if (lane < counts[t]){ mn = pmn[starts[t]+lane]; mx = pmx[starts[t]+lane]; }
            #pragma unroll
            for (int off = 32; off > 0; off >>= 1){
                mn = fminf(mn, __shfl_xor(mn, off));
                mx = fmaxf(mx, __shfl_xor(mx, off));
            }
            if (lane == 0){
                float s = (mx - mn) / 255.0f;
                sS[t] = s;
                sZ[t] = truncf(fminf(fmaxf(0.0f - mn / s, 0.0f), 255.0f));
            }
        }
    }
    __syncthreads();

    int i = blockIdx.x * TPB + tid;
    if (i >= N_EFF) return;
    if (i < 1024){                   // w1bf: [n(32)][k(32)] integer weights
        int n = i >> 5, k = i & 31;
        float v = 0.0f;
        if (n < 20 && k < 25) v = qclip(c1w[n*25 + k], sS[0], sZ[0]) - sZ[0];
        w1bf[i] = bfbits(v);
    } else if (i < 1044){            // b1 pre-divided by S_N1
        int j = i - 1024;
        ws[OFF_B1 + j] = (sS[1] * (qclip(c1b[j], sS[1], sZ[1]) + sZ[1])) / S_N1;
    } else if (i < 42004){           // w2bt chunk-packed
        int j = i - 1044;
        int c = j >> 11, r = j & 2047, co = r >> 5, k = r & 31;
        int q = k >> 3, jj = k & 7;
        int tap, ci; bool valid;
        if (c < 13){ tap = 2*c + (q>>1); ci = (q&1)*8 + jj; valid = (tap < 25); }
        else       { tap = 4*(c-13) + q; ci = 16 + jj;      valid = (tap < 25) && (jj < 4); }
        valid = valid && (co < 50);
        float v = 0.0f;
        if (valid) v = qclip(c2w[(co*20 + ci)*25 + tap], sS[2], sZ[2]) - sZ[2];
        w2bf[j] = bfbits(v);
    } else if (i < 42054){           // b2 pre-divided by S_N2
        int j = i - 42004;
        ws[OFF_B2 + j] = (sS[3] * (qclip(c2b[j], sS[3], sZ[3]) + sZ[3])) / S_N2;
    } else if (i < 451654){          // w3bf: [n(512)][k(800)]
        int j = i - 42054;
        int n = j / 800, k = j - 800*n;
        float v = 0.0f;
        if (n < 500) v = qclip(f1w[n*800 + k], sS[4], sZ[4]) - sZ[4];
        w3bf[j] = bfbits(v);
    } else if (i < 452154){          // b3 pre-divided by S_N3
        int j = i - 451654;
        ws[OFF_B3 + j] = (sS[5] * (qclip(f1b[j], sS[5], sZ[5]) + sZ[5])) / S_N3;
    } else if (i == 452154){
        ws[0] = (S_N1 * sS[2]) / S_N2;   // conv2 combined scale, pre-divided
    } else if (i == 452155){
        ws[1] = (S_N2 * sS[4]) / S_N3;   // fc1 combined scale, pre-divided
    } else {
        ws[2] = (S_X1 * sS[0]) / S_N1;   // conv1 combined scale, pre-divided
    }
}

// Fused conv1+conv2, one image per block. (exact round-11 passing version)
__global__ __launch_bounds__(TPB) void k_conv12(const float* x, const ushort_t* w1bf,
                                                const ushort_t* w2bt, const float* ws,
                                                ushort_t* q2bf, int B){
    __shared__ __align__(16) ushort_t xs[144*XSTR];   // conv2 input; first 3136 alias xim
    __shared__ ushort_t hbu[5760];                    // [oh(24)*12+owp][ch(20)] h-pool maxes
    ushort_t* xim = xs;   // 4 copies of quantized 784-u16 image (dead before xs written)
    int b = blockIdx.x, tid = threadIdx.x;
    int lane = tid & 63, wv = tid >> 6;
    int ln = lane & 15, quad = lane >> 4;

    // ---------------- conv1 phase ----------------
    const float* xb = x + (size_t)b * 784;
    for (int i = tid; i < 784; i += TPB){
        float v = xb[i];
        float q = rintf(fminf(fmaxf(ZP_X1 + v / S_X1, 0.0f), 255.0f));
        ushort_t bits = bfbits(q - ZP_X1);
        xim[i] = bits; xim[784 + i] = bits; xim[1568 + i] = bits; xim[2352 + i] = bits;
    }

    int offj[8]; bool vj[8];
    #pragma unroll
    for (int j = 0; j < 8; ++j){
        int k = quad*8 + j;
        vj[j] = (k < 25);
        int kh = k / 5, kw = k - 5*kh;
        offj[j] = vj[j] ? (kh*28 + kw) : 0;
    }
    const ushort_t* xq = xim + quad*784;   // this quad's private copy

    ushort8 bw0 = *(const ushort8*)(w1bf + ln*32 + quad*8);
    ushort8 bw1 = *(const ushort8*)(w1bf + (16 + ln)*32 + quad*8);
    bf16x8 bf0 = __builtin_bit_cast(bf16x8, bw0);
    bf16x8 bf1 = __builtin_bit_cast(bf16x8, bw1);

    float K1 = ws[2];
    float B1_0 = ws[OFF_B1 + ln];
    float B1_1 = (ln < 4) ? ws[OFF_B1 + 16 + ln] : 0.0f;
    __syncthreads();

    for (int i = 0; i < 9; ++i){
        int mt = 9*wv + i;
        int m = mt*16 + ln;
        int oh = m / 24, ow = m - 24*oh;
        int base = oh*28 + ow;
        ushort8 aw;
        #pragma unroll
        for (int j = 0; j < 8; ++j)
            aw[j] = vj[j] ? xq[base + offj[j]] : (ushort_t)0;
        bf16x8 af = __builtin_bit_cast(bf16x8, aw);
        floatx4 z = (floatx4){0.f,0.f,0.f,0.f};
        floatx4 a0 = __builtin_amdgcn_mfma_f32_16x16x32_bf16(af, bf0, z, 0, 0, 0);
        floatx4 a1 = __builtin_amdgcn_mfma_f32_16x16x32_bf16(af, bf1, z, 0, 0, 0);

        // integer epilogue: for y>=0, (uint)rintf(y) & 255 == fmod(rint(y),256) exactly
        int m0 = mt*16 + quad*4;
        int oh0 = m0 / 24, owp = (m0 - 24*oh0) >> 1;
        int hbase = (oh0*12 + owp)*20;
        {
            unsigned int qv[4];
            #pragma unroll
            for (int r = 0; r < 4; ++r){
                float y = fmaxf(fmaf(a0[r], K1, B1_0), 0.0f);
                qv[r] = ((unsigned int)rintf(y)) & 255u;
            }
            unsigned int h0 = qv[0] > qv[1] ? qv[0] : qv[1];
            unsigned int h1 = qv[2] > qv[3] ? qv[2] : qv[3];
            hbu[hbase + ln]      = (ushort_t)h0;
            hbu[hbase + 20 + ln] = (ushort_t)h1;
        }
        if (ln < 4){
            unsigned int qv[4];
            #pragma unroll
            for (int r = 0; r < 4; ++r){
                float y = fmaxf(fmaf(a1[r], K1, B1_1), 0.0f);
                qv[r] = ((unsigned int)rintf(y)) & 255u;
            }
            unsigned int h0 = qv[0] > qv[1] ? qv[0] : qv[1];
            unsigned int h1 = qv[2] > qv[3] ? qv[2] : qv[3];
            hbu[hbase + 16 + ln]      = (ushort_t)h0;
            hbu[hbase + 36 + ln]      = (ushort_t)h1;
        }
    }
    __syncthreads();   // xim reads done; xs may now be overwritten

    // vertical pool into xs channels-last [pixel(144)][XSTR] (ci 20-23 zeroed; 24-39 unread)
    for (int o = tid; o < 3456; o += TPB){
        int p = o / 24, c = o - 24*p;
        unsigned int m_ = 0;
        if (c < 20){
            int ph = p / 12, pw = p - 12*ph;
            unsigned int t_ = hbu[((2*ph)*12 + pw)*20 + c];
            unsigned int u_ = hbu[((2*ph+1)*12 + pw)*20 + c];
            m_ = t_ > u_ ? t_ : u_;
        }
        xs[p*XSTR + c] = bfbits((float)m_);
    }
    __syncthreads();

    // ---------------- conv2 phase: wave owns 2mt x 2nt ----------------
    int mt0 = (wv & 1) * 2;
    int nt0 = (wv >> 1) * 2;
    int abase[2];
    #pragma unroll
    for (int mi = 0; mi < 2; ++mi)
        abase[mi] = (24*(mt0+mi) + (ln>>3)*12 + (ln&7)) * XSTR;
    int aoff[20];
    #pragma unroll
    for (int c = 0; c < 20; ++c){
        int tap, inner;
        if (c < 13){ tap = 2*c + (quad>>1); inner = (quad&1)*8; }
        else       { tap = 4*(c-13) + quad; inner = 16; }
        int pt = 0;   // invalid taps -> pixel 0 (weights are zero there)
        if (tap < 25){ int kh = tap/5, kw = tap-5*kh; pt = kh*12 + kw; }
        aoff[c] = pt*XSTR + inner;
    }

    float sc2d = ws[0];
    const ushort_t* bsrc0 = w2bt + (size_t)(nt0*16 + ln)*32 + quad*8;
    const ushort_t* bsrc1 = bsrc0 + 16*32;

    floatx4 acc[2][2];
    #pragma unroll
    for (int mi = 0; mi < 2; ++mi)
        #pragma unroll
        for (int ni = 0; ni < 2; ++ni) acc[mi][ni] = (floatx4){0.f,0.f,0.f,0.f};

    #pragma unroll
    for (int c = 0; c < 20; ++c){
        ushort8 b0w = *(const ushort8*)(bsrc0 + c*2048);
        ushort8 b1w = *(const ushort8*)(bsrc1 + c*2048);
        ushort8 a0w = *(const ushort8*)(xs + abase[0] + aoff[c]);
        ushort8 a1w = *(const ushort8*)(xs + abase[1] + aoff[c]);
        bf16x8 a0 = __builtin_bit_cast(bf16x8, a0w);
        bf16x8 a1 = __builtin_bit_cast(bf16x8, a1w);
        bf16x8 b0 = __builtin_bit_cast(bf16x8, b0w);
        bf16x8 b1 = __builtin_bit_cast(bf16x8, b1w);
        acc[0][0] = __builtin_amdgcn_mfma_f32_16x16x32_bf16(a0, b0, acc[0][0], 0, 0, 0);
        acc[0][1] = __builtin_amdgcn_mfma_f32_16x16x32_bf16(a0, b1, acc[0][1], 0, 0, 0);
        acc[1][0] = __builtin_amdgcn_mfma_f32_16x16x32_bf16(a1, b0, acc[1][0], 0, 0, 0);
        acc[1][1] = __builtin_amdgcn_mfma_f32_16x16x32_bf16(a1, b1, acc[1][1], 0, 0, 0);
    }

    #pragma unroll
    for (int ni = 0; ni < 2; ++ni){
        int co = (nt0 + ni)*16 + ln;
        float bias2d = (co < 50) ? ws[OFF_B2 + co] : 0.0f;
        #pragma unroll
        for (int mi = 0; mi < 2; ++mi){
            int mt = mt0 + mi;
            unsigned int qv[4];
            #pragma unroll
            for (int r = 0; r < 4; ++r){
                float y = fmaxf(fmaf(acc[mi][ni][r], sc2d, bias2d), 0.0f);
                qv[r] = ((unsigned int)rintf(y)) & 255u;
            }
            unsigned int h0 = qv[0] > qv[1] ? qv[0] : qv[1];
            unsigned int h1 = qv[2] > qv[3] ? qv[2] : qv[3];
            unsigned int p0 = (unsigned int)__shfl_xor((int)h0, 32);
            unsigned int p1 = (unsigned int)__shfl_xor((int)h1, 32);
            unsigned int v0 = h0 > p0 ? h0 : p0;
            unsigned int v1 = h1 > p1 ? h1 : p1;
            if (quad < 2 && co < 50){
                size_t base = (size_t)b*800 + co*16 + mt*4 + quad*2;
                q2bf[base]     = bfbits((float)v0);
                q2bf[base + 1] = bfbits((float)v1);
            }
        }
    }
}

// fc1 v2: barrier-free, LDS-free MFMA GEMM. (exact round-12 passing version)
__global__ __launch_bounds__(TPB) void k_fc1(const ushort_t* q2bf, const ushort_t* w3bf,
                                             const float* ws, unsigned char* q3, int B){
    int tid = threadIdx.x;
    int lane = tid & 63, wv = tid >> 6;
    int ln = lane & 15, quad = lane >> 4;
    int n0 = blockIdx.x * 64 + wv*16;
    int b0 = blockIdx.y * 32;

    const ushort_t* bsrc = w3bf + (size_t)(n0 + ln)*800 + quad*8;
    const ushort_t* asrc0 = q2bf + (size_t)(b0 + ln)*800 + quad*8;
    const ushort_t* asrc1 = q2bf + (size_t)(b0 + 16 + ln)*800 + quad*8;

    floatx4 acc[2];
    #pragma unroll
    for (int mt = 0; mt < 2; ++mt) acc[mt] = (floatx4){0.f,0.f,0.f,0.f};

    #pragma unroll
    for (int c = 0; c < 25; ++c){
        ushort8 bw  = *(const ushort8*)(bsrc  + c*32);
        ushort8 a0w = *(const ushort8*)(asrc0 + c*32);
        ushort8 a1w = *(const ushort8*)(asrc1 + c*32);
        bf16x8 bfr = __builtin_bit_cast(bf16x8, bw);
        acc[0] = __builtin_amdgcn_mfma_f32_16x16x32_bf16(
                     __builtin_bit_cast(bf16x8, a0w), bfr, acc[0], 0, 0, 0);
        acc[1] = __builtin_amdgcn_mfma_f32_16x16x32_bf16(
                     __builtin_bit_cast(bf16x8, a1w), bfr, acc[1], 0, 0, 0);
    }

    float sc3d = ws[1];                       // pre-divided by S_N3
    int n = n0 + ln;
    if (n < 500){
        float bias = ws[OFF_B3 + n];          // pre-divided by S_N3
        #pragma unroll
        for (int mt = 0; mt < 2; ++mt){
            #pragma unroll
            for (int r = 0; r < 4; ++r){
                int m = 16*mt + 4*quad + r;
                float y = fmaxf(fmaf(acc[mt][r], sc3d, bias), 0.0f);
                q3[(size_t)(b0 + m)*500 + n] = (unsigned char)(((unsigned int)rintf(y)) & 255u);
            }
        }
    }
}

// fc2 v2: LDS-free, barrier-free. One wave per row, 4 rows/block, grid B/4 = 1024.
// w2 (20 KB) fits in L1 -> all w2 loads are L1 hits after warm-up; q3 row from L2.
// Accumulation order & operand bits identical to v1 (same k-lane map, same butterfly).
__global__ __launch_bounds__(TPB) void k_fc2(const unsigned char* q3, const float* w2,
                                             const float* b2, float* out, int B){
    int tid = threadIdx.x;
    int lane = tid & 63, wv = tid >> 6;
    int b = blockIdx.x*4 + wv;
    if (b >= B) return;
    float acc[10];
    #pragma unroll
    for (int c = 0; c < 10; ++c) acc[c] = 0.0f;
    #pragma unroll
    for (int it = 0; it < 8; ++it){
        int k = lane + it*64;
        if (k < 500){
            float xf = S_N3 * (float)q3[(size_t)b*500 + k];
            #pragma unroll
            for (int c = 0; c < 10; ++c)
                acc[c] = fmaf(xf, w2[c*500 + k], acc[c]);
        }
    }
    #pragma unroll
    for (int off = 32; off > 0; off >>= 1)
        #pragma unroll
        for (int c = 0; c < 10; ++c)
            acc[c] += __shfl_xor(acc[c], off);
    float lg[10], m = -INFINITY;
    #pragma unroll
    for (int c = 0; c < 10; ++c){ lg[c] = acc[c] + b2[c]; m = fmaxf(m, lg[c]); }
    float sum = 0.0f;
    #pragma unroll
    for (int c = 0; c < 10; ++c) sum += expf(lg[c] - m);
    float ls = logf(sum);
    if (lane < 10) out[(size_t)b*10 + lane] = lg[lane] - m - ls;
}

extern "C" void kernel_launch(void* const* d_in, const int* in_sizes, int n_in,
                              void* d_out, int out_size, void* d_ws, size_t ws_size,
                              hipStream_t stream){
    const float* x   = (const float*)d_in[0];
    const float* c1w = (const float*)d_in[1];
    const float* c1b = (const float*)d_in[2];
    const float* c2w = (const float*)d_in[3];
    const float* c2b = (const float*)d_in[4];
    const float* f1w = (const float*)d_in[5];
    const float* f1b = (const float*)d_in[6];
    const float* f2w = (const float*)d_in[7];
    const float* f2b = (const float*)d_in[8];
    int B = in_sizes[0] / 784;

    float* ws = (float*)d_ws;
    float* pmn = ws + OFF_PMN;
    float* pmx = ws + OFF_PMX;
    ushort_t* w1bf = (ushort_t*)((char*)d_ws + W1BF_BYTE);
    ushort_t* w2bf = (ushort_t*)((char*)d_ws + W2BF_BYTE);
    ushort_t* w3bf = (ushort_t*)((char*)d_ws + W3BF_BYTE);
    ushort_t* q2bf = (ushort_t*)((char*)d_ws + Q2_BYTE);
    unsigned char* q3 = (unsigned char*)d_ws + Q3_BYTE;
    float* out = (float*)d_out;

    k_minmax<<<72, TPB, 0, stream>>>(c1w, c1b, c2w, c2b, f1w, f1b, pmn, pmx);
    k_make_eff<<<(N_EFF + TPB - 1)/TPB, TPB, 0, stream>>>(c1w, c1b, c2w, c2b, f1w, f1b, pmn, pmx, ws, w1bf, w2bf, w3bf);
    k_conv12<<<B, TPB, 0, stream>>>(x, w1bf, w2bf, ws, q2bf, B);
    dim3 g_fc1(8, (B + 31)/32);
    k_fc1<<<g_fc1, TPB, 0, stream>>>(q2bf, w3bf, ws, q3, B);
    k_fc2<<<(B + 3)/4, TPB, 0, stream>>>(q3, f2w, f2b, out, B);
}

// Round 15
// 161.638 us; speedup vs baseline: 1.3856x; 1.0149x over previous
//
#include <hip/hip_runtime.h>
#include <cmath>

#define TPB 256
typedef float floatx4 __attribute__((ext_vector_type(4)));
typedef __bf16 bf16x8 __attribute__((ext_vector_type(8)));
typedef unsigned short ushort8 __attribute__((ext_vector_type(8)));
typedef unsigned short ushort_t;

// ---------- workspace layout (float units) ----------
// [0]=sc2d ((S_N1*s_w2)/S_N2), [1]=sc3d ((S_N2*s_w3)/S_N3), [2]=K1 ((S_X1*s_w1)/S_N1)
// [16..88) = pmn[72] partial mins, [96..168) = pmx[72] partial maxes
#define OFF_PMN 16
#define OFF_PMX 96
#define OFF_B1 520       // 20  f32  (pre-divided by S_N1)
#define OFF_B2 544       // 50  f32  (pre-divided by S_N2)
#define OFF_B3 600       // 500 f32  (pre-divided by S_N3)
#define W1BF_BYTE 6144       // [32][32] u16 int weights (conv1)
#define W2BF_BYTE 8192       // [20 chunks][64 co][32 k] u16 int weights (conv2), 81920 B
#define W3BF_BYTE 131072     // [512][800]  u16 int weights (fc1)
#define Q2_BYTE  29360128ULL // [B][800] bf16 (6.6 MB)
#define Q3_BYTE  1048576ULL  // [B][500] u8

#define S_X1 (3.5f/255.0f)
#define ZP_X1 36.0f
#define S_N1 (6.0f/255.0f)
#define S_N2 (8.0f/255.0f)
#define S_N3 (10.0f/255.0f)

// LDS pixel stride for conv2 A-reads: 40 u16 = 80 B = 20 banks (period-32 -> conflict-free)
#define XSTR 40

__device__ inline float qclip(float x, float s, float zp){
    return rintf(fminf(fmaxf(zp + x / s, 0.0f), 255.0f));
}
// exact bf16 bits for integer-valued floats |v| < 256
__device__ inline ushort_t bfbits(float v){
    return (ushort_t)(__float_as_uint(v) >> 16);
}

// per-block min/max partials; block->tensor map: 0:c1w 1:c1b 2-5:c2w 6:c2b 7-70:f1w 71:f1b
__global__ __launch_bounds__(TPB) void k_minmax(
        const float* c1w, const float* c1b, const float* c2w, const float* c2b,
        const float* f1w, const float* f1b, float* pmn, float* pmx){
    __shared__ float smn[TPB], smx[TPB];
    int bb = blockIdx.x, tid = threadIdx.x;
    const float* src; int n, sub, nsub;
    if      (bb == 0){ src=c1w; n=500;    sub=0;     nsub=1;  }
    else if (bb == 1){ src=c1b; n=20;     sub=0;     nsub=1;  }
    else if (bb <  6){ src=c2w; n=25000;  sub=bb-2;  nsub=4;  }
    else if (bb == 6){ src=c2b; n=50;     sub=0;     nsub=1;  }
    else if (bb < 71){ src=f1w; n=400000; sub=bb-7;  nsub=64; }
    else             { src=f1b; n=500;    sub=0;     nsub=1;  }
    float mn = INFINITY, mx = -INFINITY;
    for (int i = sub*TPB + tid; i < n; i += nsub*TPB){
        float v = src[i]; mn = fminf(mn, v); mx = fmaxf(mx, v);
    }
    smn[tid] = mn; smx[tid] = mx; __syncthreads();
    for (int s = TPB/2; s > 0; s >>= 1){
        if (tid < s){
            smn[tid] = fminf(smn[tid], smn[tid+s]);
            smx[tid] = fmaxf(smx[tid], smx[tid+s]);
        }
        __syncthreads();
    }
    if (tid == 0){ pmn[bb] = smn[0]; pmx[bb] = smx[0]; }
}

// w2bt chunk packing (20 chunks of K=32):
//   main c in 0..12:   oct q -> tap = 2c + (q>>1), ci = (q&1)*8 + jj   (tap 25 -> zero)
//   residue c in 13..19: oct q -> tap = 4(c-13) + q, ci = 16 + jj (jj<4; jj>=4 -> zero)
#define N_EFF 452157
__global__ __launch_bounds__(TPB) void k_make_eff(
        const float* c1w, const float* c1b, const float* c2w, const float* c2b,
        const float* f1w, const float* f1b, const float* pmn, const float* pmx,
        float* ws, ushort_t* w1bf, ushort_t* w2bf, ushort_t* w3bf){
    __shared__ float sS[6], sZ[6];
    int tid = threadIdx.x;
    int wv = tid >> 6, lane = tid & 63;
    const int starts[6] = {0,1,2,6,7,71};
    const int counts[6] = {1,1,4,1,64,1};
    #pragma unroll
    for (int rep = 0; rep < 2; ++rep){
        int t = wv + rep*4;
        if (t < 6){
            float mn = INFINITY, mx = -INFINITY;
            if (lane < counts[t]){ mn = pmn[starts[t]+lane]; mx = pmx[starts[t]+lane]; }
            #pragma unroll
            for (int off = 32; off > 0; off >>= 1){
                mn = fminf(mn, __shfl_xor(mn, off));
                mx = fmaxf(mx, __shfl_xor(mx, off));
            }
            if (lane == 0){
                float s = (mx - mn) / 255.0f;
                sS[t] = s;
                sZ[t] = truncf(fminf(fmaxf(0.0f - mn / s, 0.0f), 255.0f));
            }
        }
    }
    __syncthreads();

    int i = blockIdx.x * TPB + tid;
    if (i >= N_EFF) return;
    if (i < 1024){                   // w1bf: [n(32)][k(32)] integer weights
        int n = i >> 5, k = i & 31;
        float v = 0.0f;
        if (n < 20 && k < 25) v = qclip(c1w[n*25 + k], sS[0], sZ[0]) - sZ[0];
        w1bf[i] = bfbits(v);
    } else if (i < 1044){            // b1 pre-divided by S_N1
        int j = i - 1024;
        ws[OFF_B1 + j] = (sS[1] * (qclip(c1b[j], sS[1], sZ[1]) + sZ[1])) / S_N1;
    } else if (i < 42004){           // w2bt chunk-packed
        int j = i - 1044;
        int c = j >> 11, r = j & 2047, co = r >> 5, k = r & 31;
        int q = k >> 3, jj = k & 7;
        int tap, ci; bool valid;
        if (c < 13){ tap = 2*c + (q>>1); ci = (q&1)*8 + jj; valid = (tap < 25); }
        else       { tap = 4*(c-13) + q; ci = 16 + jj;      valid = (tap < 25) && (jj < 4); }
        valid = valid && (co < 50);
        float v = 0.0f;
        if (valid) v = qclip(c2w[(co*20 + ci)*25 + tap], sS[2], sZ[2]) - sZ[2];
        w2bf[j] = bfbits(v);
    } else if (i < 42054){           // b2 pre-divided by S_N2
        int j = i - 42004;
        ws[OFF_B2 + j] = (sS[3] * (qclip(c2b[j], sS[3], sZ[3]) + sZ[3])) / S_N2;
    } else if (i < 451654){          // w3bf: [n(512)][k(800)]
        int j = i - 42054;
        int n = j / 800, k = j - 800*n;
        float v = 0.0f;
        if (n < 500) v = qclip(f1w[n*800 + k], sS[4], sZ[4]) - sZ[4];
        w3bf[j] = bfbits(v);
    } else if (i < 452154){          // b3 pre-divided by S_N3
        int j = i - 451654;
        ws[OFF_B3 + j] = (sS[5] * (qclip(f1b[j], sS[5], sZ[5]) + sZ[5])) / S_N3;
    } else if (i == 452154){
        ws[0] = (S_N1 * sS[2]) / S_N2;   // conv2 combined scale, pre-divided
    } else if (i == 452155){
        ws[1] = (S_N2 * sS[4]) / S_N3;   // fc1 combined scale, pre-divided
    } else {
        ws[2] = (S_X1 * sS[0]) / S_N1;   // conv1 combined scale, pre-divided
    }
}

// Fused conv1+conv2, one image per block.
// conv1 CORNER-MAJOR m-map: m -> (pool window p=m>>2, corner=m&3), so each lane's 4
// C-regs are the 4 corners of one 2x2 pool window: quant + in-register max4 + direct
// write of the pooled value to xs[p*XSTR+ch]. No hb buffer, no pool pass, 2 barriers.
// conv2: 2mt x 2nt per wave (round-11 verified, unchanged).
// [A/A resubmit of round-14: testing crash-flake hypothesis; statically bounds-clean]
__global__ __launch_bounds__(TPB) void k_conv12(const float* x, const ushort_t* w1bf,
                                                const ushort_t* w2bt, const float* ws,
                                                ushort_t* q2bf, int B){
    __shared__ __align__(16) ushort_t xs[144*XSTR];   // conv2 input, [pool pixel][ci(XSTR)]
    __shared__ __align__(16) ushort_t xim[3136];      // 4 per-quad copies of quantized image
    int b = blockIdx.x, tid = threadIdx.x;
    int lane = tid & 63, wv = tid >> 6;
    int ln = lane & 15, quad = lane >> 4;

    // zero xs pad columns 20-23 once (ci 24-39 are never read)
    for (int i = tid; i < 144; i += TPB){
        *(unsigned int*)(xs + i*XSTR + 20) = 0u;
        *(unsigned int*)(xs + i*XSTR + 22) = 0u;
    }

    // ---------------- conv1 phase ----------------
    const float* xb = x + (size_t)b * 784;
    for (int i = tid; i < 784; i += TPB){
        float v = xb[i];
        float q = rintf(fminf(fmaxf(ZP_X1 + v / S_X1, 0.0f), 255.0f));
        ushort_t bits = bfbits(q - ZP_X1);
        xim[i] = bits; xim[784 + i] = bits; xim[1568 + i] = bits; xim[2352 + i] = bits;
    }

    int offj[8]; bool vj[8];
    #pragma unroll
    for (int j = 0; j < 8; ++j){
        int k = quad*8 + j;
        vj[j] = (k < 25);
        int kh = k / 5, kw = k - 5*kh;
        offj[j] = vj[j] ? (kh*28 + kw) : 0;
    }
    const ushort_t* xq = xim + quad*784;   // this quad's private copy

    ushort8 bw0 = *(const ushort8*)(w1bf + ln*32 + quad*8);
    ushort8 bw1 = *(const ushort8*)(w1bf + (16 + ln)*32 + quad*8);
    bf16x8 bf0 = __builtin_bit_cast(bf16x8, bw0);
    bf16x8 bf1 = __builtin_bit_cast(bf16x8, bw1);

    float K1 = ws[2];
    float B1_0 = ws[OFF_B1 + ln];
    float B1_1 = (ln < 4) ? ws[OFF_B1 + 16 + ln] : 0.0f;
    __syncthreads();

    for (int i = 0; i < 9; ++i){
        int mt = 9*wv + i;
        // corner-major A-row for this lane: m = mt*16 + ln
        int m = mt*16 + ln;
        int p = m >> 2, crn = m & 3;
        int ph_ = p / 12, pw_ = p - 12*ph_;
        int oh = 2*ph_ + (crn >> 1), ow = 2*pw_ + (crn & 1);
        int base = oh*28 + ow;
        ushort8 aw;
        #pragma unroll
        for (int j = 0; j < 8; ++j)
            aw[j] = vj[j] ? xq[base + offj[j]] : (ushort_t)0;
        bf16x8 af = __builtin_bit_cast(bf16x8, aw);
        floatx4 z = (floatx4){0.f,0.f,0.f,0.f};
        floatx4 a0 = __builtin_amdgcn_mfma_f32_16x16x32_bf16(af, bf0, z, 0, 0, 0);
        floatx4 a1 = __builtin_amdgcn_mfma_f32_16x16x32_bf16(af, bf1, z, 0, 0, 0);

        // epilogue: C rows quad*4+r = corners r of pool window pp; quant (integer wrap,
        // exact: (uint)rintf(y)&255 == fmod(rint(y),256) for y>=0), max4, direct store.
        int pp = mt*4 + quad;
        {
            unsigned int qv[4];
            #pragma unroll
            for (int r = 0; r < 4; ++r){
                float y = fmaxf(fmaf(a0[r], K1, B1_0), 0.0f);
                qv[r] = ((unsigned int)rintf(y)) & 255u;
            }
            unsigned int h0 = qv[0] > qv[1] ? qv[0] : qv[1];
            unsigned int h1 = qv[2] > qv[3] ? qv[2] : qv[3];
            unsigned int mx = h0 > h1 ? h0 : h1;
            xs[pp*XSTR + ln] = bfbits((float)mx);
        }
        if (ln < 4){
            unsigned int qv[4];
            #pragma unroll
            for (int r = 0; r < 4; ++r){
                float y = fmaxf(fmaf(a1[r], K1, B1_1), 0.0f);
                qv[r] = ((unsigned int)rintf(y)) & 255u;
            }
            unsigned int h0 = qv[0] > qv[1] ? qv[0] : qv[1];
            unsigned int h1 = qv[2] > qv[3] ? qv[2] : qv[3];
            unsigned int mx = h0 > h1 ? h0 : h1;
            xs[pp*XSTR + 16 + ln] = bfbits((float)mx);
        }
    }
    __syncthreads();

    // ---------------- conv2 phase: wave owns 2mt x 2nt ----------------
    int mt0 = (wv & 1) * 2;
    int nt0 = (wv >> 1) * 2;
    int abase[2];
    #pragma unroll
    for (int mi = 0; mi < 2; ++mi)
        abase[mi] = (24*(mt0+mi) + (ln>>3)*12 + (ln&7)) * XSTR;
    int aoff[20];
    #pragma unroll
    for (int c = 0; c < 20; ++c){
        int tap, inner;
        if (c < 13){ tap = 2*c + (quad>>1); inner = (quad&1)*8; }
        else       { tap = 4*(c-13) + quad; inner = 16; }
        int pt = 0;   // invalid taps -> pixel 0 (weights are zero there)
        if (tap < 25){ int kh = tap/5, kw = tap-5*kh; pt = kh*12 + kw; }
        aoff[c] = pt*XSTR + inner;
    }

    float sc2d = ws[0];
    const ushort_t* bsrc0 = w2bt + (size_t)(nt0*16 + ln)*32 + quad*8;
    const ushort_t* bsrc1 = bsrc0 + 16*32;

    floatx4 acc[2][2];
    #pragma unroll
    for (int mi = 0; mi < 2; ++mi)
        #pragma unroll
        for (int ni = 0; ni < 2; ++ni) acc[mi][ni] = (floatx4){0.f,0.f,0.f,0.f};

    #pragma unroll
    for (int c = 0; c < 20; ++c){
        ushort8 b0w = *(const ushort8*)(bsrc0 + c*2048);
        ushort8 b1w = *(const ushort8*)(bsrc1 + c*2048);
        ushort8 a0w = *(const ushort8*)(xs + abase[0] + aoff[c]);
        ushort8 a1w = *(const ushort8*)(xs + abase[1] + aoff[c]);
        bf16x8 a0 = __builtin_bit_cast(bf16x8, a0w);
        bf16x8 a1 = __builtin_bit_cast(bf16x8, a1w);
        bf16x8 b0 = __builtin_bit_cast(bf16x8, b0w);
        bf16x8 b1 = __builtin_bit_cast(bf16x8, b1w);
        acc[0][0] = __builtin_amdgcn_mfma_f32_16x16x32_bf16(a0, b0, acc[0][0], 0, 0, 0);
        acc[0][1] = __builtin_amdgcn_mfma_f32_16x16x32_bf16(a0, b1, acc[0][1], 0, 0, 0);
        acc[1][0] = __builtin_amdgcn_mfma_f32_16x16x32_bf16(a1, b0, acc[1][0], 0, 0, 0);
        acc[1][1] = __builtin_amdgcn_mfma_f32_16x16x32_bf16(a1, b1, acc[1][1], 0, 0, 0);
    }

    #pragma unroll
    for (int ni = 0; ni < 2; ++ni){
        int co = (nt0 + ni)*16 + ln;
        float bias2d = (co < 50) ? ws[OFF_B2 + co] : 0.0f;
        #pragma unroll
        for (int mi = 0; mi < 2; ++mi){
            int mt = mt0 + mi;
            unsigned int qv[4];
            #pragma unroll
            for (int r = 0; r < 4; ++r){
                float y = fmaxf(fmaf(acc[mi][ni][r], sc2d, bias2d), 0.0f);
                qv[r] = ((unsigned int)rintf(y)) & 255u;
            }
            unsigned int h0 = qv[0] > qv[1] ? qv[0] : qv[1];
            unsigned int h1 = qv[2] > qv[3] ? qv[2] : qv[3];
            unsigned int p0 = (unsigned int)__shfl_xor((int)h0, 32);
            unsigned int p1 = (unsigned int)__shfl_xor((int)h1, 32);
            unsigned int v0 = h0 > p0 ? h0 : p0;
            unsigned int v1 = h1 > p1 ? h1 : p1;
            if (quad < 2 && co < 50){
                size_t base = (size_t)b*800 + co*16 + mt*4 + quad*2;
                q2bf[base]     = bfbits((float)v0);
                q2bf[base + 1] = bfbits((float)v1);
            }
        }
    }
}

// fc1 v2: barrier-free, LDS-free MFMA GEMM. (exact round-12 passing version)
__global__ __launch_bounds__(TPB) void k_fc1(const ushort_t* q2bf, const ushort_t* w3bf,
                                             const float* ws, unsigned char* q3, int B){
    int tid = threadIdx.x;
    int lane = tid & 63, wv = tid >> 6;
    int ln = lane & 15, quad = lane >> 4;
    int n0 = blockIdx.x * 64 + wv*16;
    int b0 = blockIdx.y * 32;

    const ushort_t* bsrc = w3bf + (size_t)(n0 + ln)*800 + quad*8;
    const ushort_t* asrc0 = q2bf + (size_t)(b0 + ln)*800 + quad*8;
    const ushort_t* asrc1 = q2bf + (size_t)(b0 + 16 + ln)*800 + quad*8;

    floatx4 acc[2];
    #pragma unroll
    for (int mt = 0; mt < 2; ++mt) acc[mt] = (floatx4){0.f,0.f,0.f,0.f};

    #pragma unroll
    for (int c = 0; c < 25; ++c){
        ushort8 bw  = *(const ushort8*)(bsrc  + c*32);
        ushort8 a0w = *(const ushort8*)(asrc0 + c*32);
        ushort8 a1w = *(const ushort8*)(asrc1 + c*32);
        bf16x8 bfr = __builtin_bit_cast(bf16x8, bw);
        acc[0] = __builtin_amdgcn_mfma_f32_16x16x32_bf16(
                     __builtin_bit_cast(bf16x8, a0w), bfr, acc[0], 0, 0, 0);
        acc[1] = __builtin_amdgcn_mfma_f32_16x16x32_bf16(
                     __builtin_bit_cast(bf16x8, a1w), bfr, acc[1], 0, 0, 0);
    }

    float sc3d = ws[1];                       // pre-divided by S_N3
    int n = n0 + ln;
    if (n < 500){
        float bias = ws[OFF_B3 + n];          // pre-divided by S_N3
        #pragma unroll
        for (int mt = 0; mt < 2; ++mt){
            #pragma unroll
            for (int r = 0; r < 4; ++r){
                int m = 16*mt + 4*quad + r;
                float y = fmaxf(fmaf(acc[mt][r], sc3d, bias), 0.0f);
                q3[(size_t)(b0 + m)*500 + n] = (unsigned char)(((unsigned int)rintf(y)) & 255u);
            }
        }
    }
}

// fc2 v2: LDS-free, barrier-free. (exact round-13 passing version)
__global__ __launch_bounds__(TPB) void k_fc2(const unsigned char* q3, const float* w2,
                                             const float* b2, float* out, int B){
    int tid = threadIdx.x;
    int lane = tid & 63, wv = tid >> 6;
    int b = blockIdx.x*4 + wv;
    if (b >= B) return;
    float acc[10];
    #pragma unroll
    for (int c = 0; c < 10; ++c) acc[c] = 0.0f;
    #pragma unroll
    for (int it = 0; it < 8; ++it){
        int k = lane + it*64;
        if (k < 500){
            float xf = S_N3 * (float)q3[(size_t)b*500 + k];
            #pragma unroll
            for (int c = 0; c < 10; ++c)
                acc[c] = fmaf(xf, w2[c*500 + k], acc[c]);
        }
    }
    #pragma unroll
    for (int off = 32; off > 0; off >>= 1)
        #pragma unroll
        for (int c = 0; c < 10; ++c)
            acc[c] += __shfl_xor(acc[c], off);
    float lg[10], m = -INFINITY;
    #pragma unroll
    for (int c = 0; c < 10; ++c){ lg[c] = acc[c] + b2[c]; m = fmaxf(m, lg[c]); }
    float sum = 0.0f;
    #pragma unroll
    for (int c = 0; c < 10; ++c) sum += expf(lg[c] - m);
    float ls = logf(sum);
    if (lane < 10) out[(size_t)b*10 + lane] = lg[lane] - m - ls;
}

extern "C" void kernel_launch(void* const* d_in, const int* in_sizes, int n_in,
                              void* d_out, int out_size, void* d_ws, size_t ws_size,
                              hipStream_t stream){
    const float* x   = (const float*)d_in[0];
    const float* c1w = (const float*)d_in[1];
    const float* c1b = (const float*)d_in[2];
    const float* c2w = (const float*)d_in[3];
    const float* c2b = (const float*)d_in[4];
    const float* f1w = (const float*)d_in[5];
    const float* f1b = (const float*)d_in[6];
    const float* f2w = (const float*)d_in[7];
    const float* f2b = (const float*)d_in[8];
    int B = in_sizes[0] / 784;

    float* ws = (float*)d_ws;
    float* pmn = ws + OFF_PMN;
    float* pmx = ws + OFF_PMX;
    ushort_t* w1bf = (ushort_t*)((char*)d_ws + W1BF_BYTE);
    ushort_t* w2bf = (ushort_t*)((char*)d_ws + W2BF_BYTE);
    ushort_t* w3bf = (ushort_t*)((char*)d_ws + W3BF_BYTE);
    ushort_t* q2bf = (ushort_t*)((char*)d_ws + Q2_BYTE);
    unsigned char* q3 = (unsigned char*)d_ws + Q3_BYTE;
    float* out = (float*)d_out;

    k_minmax<<<72, TPB, 0, stream>>>(c1w, c1b, c2w, c2b, f1w, f1b, pmn, pmx);
    k_make_eff<<<(N_EFF + TPB - 1)/TPB, TPB, 0, stream>>>(c1w, c1b, c2w, c2b, f1w, f1b, pmn, pmx, ws, w1bf, w2bf, w3bf);
    k_conv12<<<B, TPB, 0, stream>>>(x, w1bf, w2bf, ws, q2bf, B);
    dim3 g_fc1(8, (B + 31)/32);
    k_fc1<<<g_fc1, TPB, 0, stream>>>(q2bf, w3bf, ws, q3, B);
    k_fc2<<<(B + 3)/4, TPB, 0, stream>>>(q3, f2w, f2b, out, B);
}

// Round 16
// 159.336 us; speedup vs baseline: 1.4056x; 1.0145x over previous
//
#include <hip/hip_runtime.h>
#include <cmath>

#define TPB 256
typedef float floatx4 __attribute__((ext_vector_type(4)));
typedef __bf16 bf16x8 __attribute__((ext_vector_type(8)));
typedef unsigned short ushort8 __attribute__((ext_vector_type(8)));
typedef unsigned short ushort_t;

// ---------- workspace layout (float units) ----------
// [0]=sc2d ((S_N1*s_w2)/S_N2), [1]=sc3d ((S_N2*s_w3)/S_N3), [2]=K1 ((S_X1*s_w1)/S_N1)
// [16..88) = pmn[72] partial mins, [96..168) = pmx[72] partial maxes
#define OFF_PMN 16
#define OFF_PMX 96
#define OFF_B1 520       // 20  f32  (pre-divided by S_N1)
#define OFF_B2 544       // 50  f32  (pre-divided by S_N2)
#define OFF_B3 600       // 500 f32  (pre-divided by S_N3)
#define W1BF_BYTE 6144       // [32][32] u16 int weights (conv1)
#define W2BF_BYTE 8192       // [20 chunks][64 co][32 k] u16 int weights (conv2), 81920 B
#define W3BF_BYTE 131072     // [512][800]  u16 int weights (fc1)
#define Q2_BYTE  29360128ULL // [B][800] bf16 (6.6 MB)

#define S_X1 (3.5f/255.0f)
#define ZP_X1 36.0f
#define S_N1 (6.0f/255.0f)
#define S_N2 (8.0f/255.0f)
#define S_N3 (10.0f/255.0f)

// LDS pixel stride for conv2 A-reads: 40 u16 = 80 B = 20 banks (period-32 -> conflict-free)
#define XSTR 40

__device__ inline float qclip(float x, float s, float zp){
    return rintf(fminf(fmaxf(zp + x / s, 0.0f), 255.0f));
}
// exact bf16 bits for integer-valued floats |v| < 256
__device__ inline ushort_t bfbits(float v){
    return (ushort_t)(__float_as_uint(v) >> 16);
}

// per-block min/max partials; block->tensor map: 0:c1w 1:c1b 2-5:c2w 6:c2b 7-70:f1w 71:f1b
__global__ __launch_bounds__(TPB) void k_minmax(
        const float* c1w, const float* c1b, const float* c2w, const float* c2b,
        const float* f1w, const float* f1b, float* pmn, float* pmx){
    __shared__ float smn[TPB], smx[TPB];
    int bb = blockIdx.x, tid = threadIdx.x;
    const float* src; int n, sub, nsub;
    if      (bb == 0){ src=c1w; n=500;    sub=0;     nsub=1;  }
    else if (bb == 1){ src=c1b; n=20;     sub=0;     nsub=1;  }
    else if (bb <  6){ src=c2w; n=25000;  sub=bb-2;  nsub=4;  }
    else if (bb == 6){ src=c2b; n=50;     sub=0;     nsub=1;  }
    else if (bb < 71){ src=f1w; n=400000; sub=bb-7;  nsub=64; }
    else             { src=f1b; n=500;    sub=0;     nsub=1;  }
    float mn = INFINITY, mx = -INFINITY;
    for (int i = sub*TPB + tid; i < n; i += nsub*TPB){
        float v = src[i]; mn = fminf(mn, v); mx = fmaxf(mx, v);
    }
    smn[tid] = mn; smx[tid] = mx; __syncthreads();
    for (int s = TPB/2; s > 0; s >>= 1){
        if (tid < s){
            smn[tid] = fminf(smn[tid], smn[tid+s]);
            smx[tid] = fmaxf(smx[tid], smx[tid+s]);
        }
        __syncthreads();
    }
    if (tid == 0){ pmn[bb] = smn[0]; pmx[bb] = smx[0]; }
}

// w2bt chunk packing (20 chunks of K=32):
//   main c in 0..12:   oct q -> tap = 2c + (q>>1), ci = (q&1)*8 + jj   (tap 25 -> zero)
//   residue c in 13..19: oct q -> tap = 4(c-13) + q, ci = 16 + jj (jj<4; jj>=4 -> zero)
#define N_EFF 452157
__global__ __launch_bounds__(TPB) void k_make_eff(
        const float* c1w, const float* c1b, const float* c2w, const float* c2b,
        const float* f1w, const float* f1b, const float* pmn, const float* pmx,
        float* ws, ushort_t* w1bf, ushort_t* w2bf, ushort_t* w3bf){
    __shared__ float sS[6], sZ[6];
    int tid = threadIdx.x;
    int wv = tid >> 6, lane = tid & 63;
    const int starts[6] = {0,1,2,6,7,71};
    const int counts[6] = {1,1,4,1,64,1};
    #pragma unroll
    for (int rep = 0; rep < 2; ++rep){
        int t = wv + rep*4;
        if (t < 6){
            float mn = INFINITY, mx = -INFINITY;
            if (lane < counts[t]){ mn = pmn[starts[t]+lane]; mx = pmx[starts[t]+lane]; }
            #pragma unroll
            for (int off = 32; off > 0; off >>= 1){
                mn = fminf(mn, __shfl_xor(mn, off));
                mx = fmaxf(mx, __shfl_xor(mx, off));
            }
            if (lane == 0){
                float s = (mx - mn) / 255.0f;
                sS[t] = s;
                sZ[t] = truncf(fminf(fmaxf(0.0f - mn / s, 0.0f), 255.0f));
            }
        }
    }
    __syncthreads();

    int i = blockIdx.x * TPB + tid;
    if (i >= N_EFF) return;
    if (i < 1024){                   // w1bf: [n(32)][k(32)] integer weights
        int n = i >> 5, k = i & 31;
        float v = 0.0f;
        if (n < 20 && k < 25) v = qclip(c1w[n*25 + k], sS[0], sZ[0]) - sZ[0];
        w1bf[i] = bfbits(v);
    } else if (i < 1044){            // b1 pre-divided by S_N1
        int j = i - 1024;
        ws[OFF_B1 + j] = (sS[1] * (qclip(c1b[j], sS[1], sZ[1]) + sZ[1])) / S_N1;
    } else if (i < 42004){           // w2bt chunk-packed
        int j = i - 1044;
        int c = j >> 11, r = j & 2047, co = r >> 5, k = r & 31;
        int q = k >> 3, jj = k & 7;
        int tap, ci; bool valid;
        if (c < 13){ tap = 2*c + (q>>1); ci = (q&1)*8 + jj; valid = (tap < 25); }
        else       { tap = 4*(c-13) + q; ci = 16 + jj;      valid = (tap < 25) && (jj < 4); }
        valid = valid && (co < 50);
        float v = 0.0f;
        if (valid) v = qclip(c2w[(co*20 + ci)*25 + tap], sS[2], sZ[2]) - sZ[2];
        w2bf[j] = bfbits(v);
    } else if (i < 42054){           // b2 pre-divided by S_N2
        int j = i - 42004;
        ws[OFF_B2 + j] = (sS[3] * (qclip(c2b[j], sS[3], sZ[3]) + sZ[3])) / S_N2;
    } else if (i < 451654){          // w3bf: [n(512)][k(800)]
        int j = i - 42054;
        int n = j / 800, k = j - 800*n;
        float v = 0.0f;
        if (n < 500) v = qclip(f1w[n*800 + k], sS[4], sZ[4]) - sZ[4];
        w3bf[j] = bfbits(v);
    } else if (i < 452154){          // b3 pre-divided by S_N3
        int j = i - 451654;
        ws[OFF_B3 + j] = (sS[5] * (qclip(f1b[j], sS[5], sZ[5]) + sZ[5])) / S_N3;
    } else if (i == 452154){
        ws[0] = (S_N1 * sS[2]) / S_N2;   // conv2 combined scale, pre-divided
    } else if (i == 452155){
        ws[1] = (S_N2 * sS[4]) / S_N3;   // fc1 combined scale, pre-divided
    } else {
        ws[2] = (S_X1 * sS[0]) / S_N1;   // conv1 combined scale, pre-divided
    }
}

// Fused conv1+conv2, one image per block. (exact round-15 passing version)
__global__ __launch_bounds__(TPB) void k_conv12(const float* x, const ushort_t* w1bf,
                                                const ushort_t* w2bt, const float* ws,
                                                ushort_t* q2bf, int B){
    __shared__ __align__(16) ushort_t xs[144*XSTR];   // conv2 input, [pool pixel][ci(XSTR)]
    __shared__ __align__(16) ushort_t xim[3136];      // 4 per-quad copies of quantized image
    int b = blockIdx.x, tid = threadIdx.x;
    int lane = tid & 63, wv = tid >> 6;
    int ln = lane & 15, quad = lane >> 4;

    // zero xs pad columns 20-23 once (ci 24-39 are never read)
    for (int i = tid; i < 144; i += TPB){
        *(unsigned int*)(xs + i*XSTR + 20) = 0u;
        *(unsigned int*)(xs + i*XSTR + 22) = 0u;
    }

    // ---------------- conv1 phase ----------------
    const float* xb = x + (size_t)b * 784;
    for (int i = tid; i < 784; i += TPB){
        float v = xb[i];
        float q = rintf(fminf(fmaxf(ZP_X1 + v / S_X1, 0.0f), 255.0f));
        ushort_t bits = bfbits(q - ZP_X1);
        xim[i] = bits; xim[784 + i] = bits; xim[1568 + i] = bits; xim[2352 + i] = bits;
    }

    int offj[8]; bool vj[8];
    #pragma unroll
    for (int j = 0; j < 8; ++j){
        int k = quad*8 + j;
        vj[j] = (k < 25);
        int kh = k / 5, kw = k - 5*kh;
        offj[j] = vj[j] ? (kh*28 + kw) : 0;
    }
    const ushort_t* xq = xim + quad*784;   // this quad's private copy

    ushort8 bw0 = *(const ushort8*)(w1bf + ln*32 + quad*8);
    ushort8 bw1 = *(const ushort8*)(w1bf + (16 + ln)*32 + quad*8);
    bf16x8 bf0 = __builtin_bit_cast(bf16x8, bw0);
    bf16x8 bf1 = __builtin_bit_cast(bf16x8, bw1);

    float K1 = ws[2];
    float B1_0 = ws[OFF_B1 + ln];
    float B1_1 = (ln < 4) ? ws[OFF_B1 + 16 + ln] : 0.0f;
    __syncthreads();

    for (int i = 0; i < 9; ++i){
        int mt = 9*wv + i;
        int m = mt*16 + ln;
        int p = m >> 2, crn = m & 3;
        int ph_ = p / 12, pw_ = p - 12*ph_;
        int oh = 2*ph_ + (crn >> 1), ow = 2*pw_ + (crn & 1);
        int base = oh*28 + ow;
        ushort8 aw;
        #pragma unroll
        for (int j = 0; j < 8; ++j)
            aw[j] = vj[j] ? xq[base + offj[j]] : (ushort_t)0;
        bf16x8 af = __builtin_bit_cast(bf16x8, aw);
        floatx4 z = (floatx4){0.f,0.f,0.f,0.f};
        floatx4 a0 = __builtin_amdgcn_mfma_f32_16x16x32_bf16(af, bf0, z, 0, 0, 0);
        floatx4 a1 = __builtin_amdgcn_mfma_f32_16x16x32_bf16(af, bf1, z, 0, 0, 0);

        int pp = mt*4 + quad;
        {
            unsigned int qv[4];
            #pragma unroll
            for (int r = 0; r < 4; ++r){
                float y = fmaxf(fmaf(a0[r], K1, B1_0), 0.0f);
                qv[r] = ((unsigned int)rintf(y)) & 255u;
            }
            unsigned int h0 = qv[0] > qv[1] ? qv[0] : qv[1];
            unsigned int h1 = qv[2] > qv[3] ? qv[2] : qv[3];
            unsigned int mx = h0 > h1 ? h0 : h1;
            xs[pp*XSTR + ln] = bfbits((float)mx);
        }
        if (ln < 4){
            unsigned int qv[4];
            #pragma unroll
            for (int r = 0; r < 4; ++r){
                float y = fmaxf(fmaf(a1[r], K1, B1_1), 0.0f);
                qv[r] = ((unsigned int)rintf(y)) & 255u;
            }
            unsigned int h0 = qv[0] > qv[1] ? qv[0] : qv[1];
            unsigned int h1 = qv[2] > qv[3] ? qv[2] : qv[3];
            unsigned int mx = h0 > h1 ? h0 : h1;
            xs[pp*XSTR + 16 + ln] = bfbits((float)mx);
        }
    }
    __syncthreads();

    // ---------------- conv2 phase: wave owns 2mt x 2nt ----------------
    int mt0 = (wv & 1) * 2;
    int nt0 = (wv >> 1) * 2;
    int abase[2];
    #pragma unroll
    for (int mi = 0; mi < 2; ++mi)
        abase[mi] = (24*(mt0+mi) + (ln>>3)*12 + (ln&7)) * XSTR;
    int aoff[20];
    #pragma unroll
    for (int c = 0; c < 20; ++c){
        int tap, inner;
        if (c < 13){ tap = 2*c + (quad>>1); inner = (quad&1)*8; }
        else       { tap = 4*(c-13) + quad; inner = 16; }
        int pt = 0;   // invalid taps -> pixel 0 (weights are zero there)
        if (tap < 25){ int kh = tap/5, kw = tap-5*kh; pt = kh*12 + kw; }
        aoff[c] = pt*XSTR + inner;
    }

    float sc2d = ws[0];
    const ushort_t* bsrc0 = w2bt + (size_t)(nt0*16 + ln)*32 + quad*8;
    const ushort_t* bsrc1 = bsrc0 + 16*32;

    floatx4 acc[2][2];
    #pragma unroll
    for (int mi = 0; mi < 2; ++mi)
        #pragma unroll
        for (int ni = 0; ni < 2; ++ni) acc[mi][ni] = (floatx4){0.f,0.f,0.f,0.f};

    #pragma unroll
    for (int c = 0; c < 20; ++c){
        ushort8 b0w = *(const ushort8*)(bsrc0 + c*2048);
        ushort8 b1w = *(const ushort8*)(bsrc1 + c*2048);
        ushort8 a0w = *(const ushort8*)(xs + abase[0] + aoff[c]);
        ushort8 a1w = *(const ushort8*)(xs + abase[1] + aoff[c]);
        bf16x8 a0 = __builtin_bit_cast(bf16x8, a0w);
        bf16x8 a1 = __builtin_bit_cast(bf16x8, a1w);
        bf16x8 b0 = __builtin_bit_cast(bf16x8, b0w);
        bf16x8 b1 = __builtin_bit_cast(bf16x8, b1w);
        acc[0][0] = __builtin_amdgcn_mfma_f32_16x16x32_bf16(a0, b0, acc[0][0], 0, 0, 0);
        acc[0][1] = __builtin_amdgcn_mfma_f32_16x16x32_bf16(a0, b1, acc[0][1], 0, 0, 0);
        acc[1][0] = __builtin_amdgcn_mfma_f32_16x16x32_bf16(a1, b0, acc[1][0], 0, 0, 0);
        acc[1][1] = __builtin_amdgcn_mfma_f32_16x16x32_bf16(a1, b1, acc[1][1], 0, 0, 0);
    }

    #pragma unroll
    for (int ni = 0; ni < 2; ++ni){
        int co = (nt0 + ni)*16 + ln;
        float bias2d = (co < 50) ? ws[OFF_B2 + co] : 0.0f;
        #pragma unroll
        for (int mi = 0; mi < 2; ++mi){
            int mt = mt0 + mi;
            unsigned int qv[4];
            #pragma unroll
            for (int r = 0; r < 4; ++r){
                float y = fmaxf(fmaf(acc[mi][ni][r], sc2d, bias2d), 0.0f);
                qv[r] = ((unsigned int)rintf(y)) & 255u;
            }
            unsigned int h0 = qv[0] > qv[1] ? qv[0] : qv[1];
            unsigned int h1 = qv[2] > qv[3] ? qv[2] : qv[3];
            unsigned int p0 = (unsigned int)__shfl_xor((int)h0, 32);
            unsigned int p1 = (unsigned int)__shfl_xor((int)h1, 32);
            unsigned int v0 = h0 > p0 ? h0 : p0;
            unsigned int v1 = h1 > p1 ? h1 : p1;
            if (quad < 2 && co < 50){
                size_t base = (size_t)b*800 + co*16 + mt*4 + quad*2;
                q2bf[base]     = bfbits((float)v0);
                q2bf[base + 1] = bfbits((float)v1);
            }
        }
    }
}

// Fused fc1+fc2: block = 16 batch rows x all 512 cols, 512 threads (8 waves x 4 n-tiles),
// grid B/16. Barrier-free MFMA K-loop (round-12-verified pattern); q3 quantized
// IN-REGISTER (bit-identical (uint)rintf&255 then S_N3*q — same bits as the old u8
// round-trip); fc2 dot products via 16-lane butterfly + LDS reduce over 8 waves;
// per-row log_softmax. q3 never touches HBM.
__global__ __launch_bounds__(512) void k_fc12(const ushort_t* q2bf, const ushort_t* w3bf,
                                              const float* ws, const float* w2,
                                              const float* b2, float* out, int B){
    __shared__ float red[8*16*10];    // [wv][row16][c10]
    int tid = threadIdx.x;
    int lane = tid & 63, wv = tid >> 6;    // wv in [0,8)
    int ln = lane & 15, quad = lane >> 4;
    int b0 = blockIdx.x * 16;

    const ushort_t* asrc = q2bf + (size_t)(b0 + ln)*800 + quad*8;

    floatx4 acc[4];
    #pragma unroll
    for (int t = 0; t < 4; ++t) acc[t] = (floatx4){0.f,0.f,0.f,0.f};

    for (int c = 0; c < 25; ++c){
        ushort8 aw = *(const ushort8*)(asrc + c*32);
        bf16x8 af = __builtin_bit_cast(bf16x8, aw);
        #pragma unroll
        for (int t = 0; t < 4; ++t){
            int n = wv*64 + t*16 + ln;
            ushort8 bw = *(const ushort8*)(w3bf + (size_t)n*800 + c*32 + quad*8);
            acc[t] = __builtin_amdgcn_mfma_f32_16x16x32_bf16(
                         af, __builtin_bit_cast(bf16x8, bw), acc[t], 0, 0, 0);
        }
    }

    // quantize q3 in-register: xf[r][t] = S_N3 * ((uint)rintf(relu(acc*sc3d+bias)) & 255)
    float sc3d = ws[1];
    float xf[4][4];
    #pragma unroll
    for (int t = 0; t < 4; ++t){
        int col = wv*64 + t*16 + ln;
        float bias = (col < 500) ? ws[OFF_B3 + col] : 0.0f;
        #pragma unroll
        for (int r = 0; r < 4; ++r){
            float y = fmaxf(fmaf(acc[t][r], sc3d, bias), 0.0f);
            unsigned int q = ((unsigned int)rintf(y)) & 255u;
            xf[r][t] = (col < 500) ? S_N3 * (float)q : 0.0f;
        }
    }

    // fc2: per class c, partial over this lane's 4 cols, butterfly over the 16-lane
    // group (masks 1,2,4,8 stay within quad group), wave-leader writes to LDS.
    #pragma unroll
    for (int c = 0; c < 10; ++c){
        float p[4] = {0.f, 0.f, 0.f, 0.f};
        #pragma unroll
        for (int t = 0; t < 4; ++t){
            int col = wv*64 + t*16 + ln;
            float w = (col < 500) ? w2[c*500 + col] : 0.0f;
            #pragma unroll
            for (int r = 0; r < 4; ++r) p[r] = fmaf(xf[r][t], w, p[r]);
        }
        #pragma unroll
        for (int m = 1; m <= 8; m <<= 1)
            #pragma unroll
            for (int r = 0; r < 4; ++r) p[r] += __shfl_xor(p[r], m);
        if (ln == 0){
            #pragma unroll
            for (int r = 0; r < 4; ++r)
                red[(wv*16 + quad*4 + r)*10 + c] = p[r];
        }
    }
    __syncthreads();

    if (tid < 16){
        int row = tid;
        float lg[10], mx = -INFINITY;
        #pragma unroll
        for (int c = 0; c < 10; ++c){
            float s = b2[c];
            #pragma unroll
            for (int w = 0; w < 8; ++w) s += red[(w*16 + row)*10 + c];
            lg[c] = s; mx = fmaxf(mx, s);
        }
        float sum = 0.0f;
        #pragma unroll
        for (int c = 0; c < 10; ++c) sum += expf(lg[c] - mx);
        float ls = logf(sum);
        #pragma unroll
        for (int c = 0; c < 10; ++c)
            out[(size_t)(b0 + row)*10 + c] = lg[c] - mx - ls;
    }
}

extern "C" void kernel_launch(void* const* d_in, const int* in_sizes, int n_in,
                              void* d_out, int out_size, void* d_ws, size_t ws_size,
                              hipStream_t stream){
    const float* x   = (const float*)d_in[0];
    const float* c1w = (const float*)d_in[1];
    const float* c1b = (const float*)d_in[2];
    const float* c2w = (const float*)d_in[3];
    const float* c2b = (const float*)d_in[4];
    const float* f1w = (const float*)d_in[5];
    const float* f1b = (const float*)d_in[6];
    const float* f2w = (const float*)d_in[7];
    const float* f2b = (const float*)d_in[8];
    int B = in_sizes[0] / 784;

    float* ws = (float*)d_ws;
    float* pmn = ws + OFF_PMN;
    float* pmx = ws + OFF_PMX;
    ushort_t* w1bf = (ushort_t*)((char*)d_ws + W1BF_BYTE);
    ushort_t* w2bf = (ushort_t*)((char*)d_ws + W2BF_BYTE);
    ushort_t* w3bf = (ushort_t*)((char*)d_ws + W3BF_BYTE);
    ushort_t* q2bf = (ushort_t*)((char*)d_ws + Q2_BYTE);
    float* out = (float*)d_out;

    k_minmax<<<72, TPB, 0, stream>>>(c1w, c1b, c2w, c2b, f1w, f1b, pmn, pmx);
    k_make_eff<<<(N_EFF + TPB - 1)/TPB, TPB, 0, stream>>>(c1w, c1b, c2w, c2b, f1w, f1b, pmn, pmx, ws, w1bf, w2bf, w3bf);
    k_conv12<<<B, TPB, 0, stream>>>(x, w1bf, w2bf, ws, q2bf, B);
    k_fc12<<<B/16, 512, 0, stream>>>(q2bf, w3bf, ws, f2w, f2b, out, B);
}